// Round 2
// baseline (563.833 us; speedup 1.0000x reference)
//
#include <hip/hip_runtime.h>
#include <hip/hip_fp16.h>

constexpr int kNodes = 50000;
constexpr int kNE    = 800000;            // edges before self loops
constexpr int kFin   = 256;
constexpr int kC     = 32;
constexpr int kH     = 4;
constexpr int kHC    = 128;               // kH * kC
constexpr int kTN    = 16;                // nodes per k_embed block
constexpr int kWP    = 258;               // padded sWt row (2-way LDS alias = free)
constexpr int kLWP   = 130;               // padded s_lwT row in k_post (float2-aligned, 2-way alias)
constexpr float kEps   = 1e-5f;
constexpr float kSlope = 0.2f;
constexpr float kL2E   = 1.44269504f;     // log2(e): fold into att so exp is 1 instr
constexpr float kShift2 = 8.0f * 1.44269504f; // softmax-invariant shift (exp2 domain)

// ---- zero-fill
__global__ void __launch_bounds__(256) k_fill0(unsigned* __restrict__ p, int n) {
    int i = blockIdx.x * 256 + threadIdx.x;
    if (i < n) p[i] = 0u;
}

// ---- K1: h0 = relu(node_ln(x @ W_emb + b_emb)); jk = h0.
// 16 nodes/block; x read DIRECT from global (32-lane same-address broadcast ->
// 2x16B segments per wave-load, zero staging). W staged TRANSPOSED pad-258.
// Thread t = (c, n2): computes nodes n2 and n2+8. LN via 32-lane shfl.
__global__ void __launch_bounds__(256) k_embed(
    const float* __restrict__ x, const float* __restrict__ W, const float* __restrict__ b,
    const float* __restrict__ lnw, const float* __restrict__ lnb,
    float* __restrict__ h, float* __restrict__ jk) {
    __shared__ float sWt[kC * kWP];       // 33 KB
    int t = threadIdx.x;
    int n0 = blockIdx.x * kTN;            // 50000 = 3125 * 16 exact
    for (int i = t; i < kFin * kC; i += 256) {
        int k = i >> 5, c = i & 31;
        sWt[c * kWP + k] = W[i];
    }
    __syncthreads();
    int c = t & 31, n2 = t >> 5;          // n2 = 0..7
    const float* xa = x + (long)(n0 + n2) * kFin;
    const float* xb = x + (long)(n0 + n2 + 8) * kFin;
    const float* wrow = sWt + c * kWP;
    float acc0 = 0.f, acc1 = 0.f;
    #pragma unroll 8
    for (int k = 0; k < kFin; k += 4) {
        float4 x0 = *(const float4*)(xa + k);
        float4 x1 = *(const float4*)(xb + k);
        float2 w0 = *(const float2*)(wrow + k);
        float2 w1 = *(const float2*)(wrow + k + 2);
        acc0 += x0.x * w0.x + x0.y * w0.y + x0.z * w1.x + x0.w * w1.y;
        acc1 += x1.x * w0.x + x1.y * w0.y + x1.z * w1.x + x1.w * w1.y;
    }
    float bc = b[c], lw = lnw[c], lb = lnb[c];
    // node n2
    {
        float y = acc0 + bc;
        float m = y;
        #pragma unroll
        for (int o = 1; o < 32; o <<= 1) m += __shfl_xor(m, o);
        m *= (1.f / kC);
        float xc = y - m, v = xc * xc;
        #pragma unroll
        for (int o = 1; o < 32; o <<= 1) v += __shfl_xor(v, o);
        v *= (1.f / kC);
        float out = fmaxf(xc * rsqrtf(v + kEps) * lw + lb, 0.f);
        int node = n0 + n2;
        h[node * kC + c] = out;
        jk[node * kC + c] = out;
    }
    // node n2 + 8
    {
        float y = acc1 + bc;
        float m = y;
        #pragma unroll
        for (int o = 1; o < 32; o <<= 1) m += __shfl_xor(m, o);
        m *= (1.f / kC);
        float xc = y - m, v = xc * xc;
        #pragma unroll
        for (int o = 1; o < 32; o <<= 1) v += __shfl_xor(v, o);
        v *= (1.f / kC);
        float out = fmaxf(xc * rsqrtf(v + kEps) * lw + lb, 0.f);
        int node = n0 + n2 + 8;
        h[node * kC + c] = out;
        jk[node * kC + c] = out;
    }
}

// ---- K2: xl = h@Wl + bl (fp16) ; xr = h@Wr + br (fp32).
// 256 threads: feature j x node-half; W columns in registers.
__global__ void __launch_bounds__(256) k_trans(
    const float* __restrict__ h,
    const float* __restrict__ Wl, const float* __restrict__ bl,
    const float* __restrict__ Wr, const float* __restrict__ br,
    __half* __restrict__ xl, float* __restrict__ xr) {
    __shared__ float s_h[32 * kC];
    int t = threadIdx.x;
    int j = t & 127, hf = t >> 7;
    float wl[kC], wr[kC];
    #pragma unroll
    for (int k = 0; k < kC; ++k) { wl[k] = Wl[k * kHC + j]; wr[k] = Wr[k * kHC + j]; }
    float blj = bl[j], brj = br[j];
    int n0 = blockIdx.x * 32;
    int nn = min(32, kNodes - n0);
    for (int i = t; i < nn * kC; i += 256) s_h[i] = h[n0 * kC + i];
    __syncthreads();
    int nend = min(nn, hf * 16 + 16);
    for (int n = hf * 16; n < nend; ++n) {
        const float4* h4 = (const float4*)(s_h + n * kC);
        float al = blj, ar = brj;
        #pragma unroll
        for (int kq = 0; kq < 8; ++kq) {
            float4 hv = h4[kq];
            al += hv.x * wl[kq*4] + hv.y * wl[kq*4+1] + hv.z * wl[kq*4+2] + hv.w * wl[kq*4+3];
            ar += hv.x * wr[kq*4] + hv.y * wr[kq*4+1] + hv.z * wr[kq*4+2] + hv.w * wr[kq*4+3];
        }
        long g = (long)(n0 + n) * kHC + j;
        xl[g] = __float2half(al);
        xr[g] = ar;
    }
}

// ---- CSR build (dst is layer-invariant: built ONCE)
__global__ void __launch_bounds__(256) k_hist(const int* __restrict__ dst, int* __restrict__ deg) {
    int e = blockIdx.x * 256 + threadIdx.x;
    if (e < kNE) atomicAdd(&deg[dst[e]], 1);
}

__global__ void __launch_bounds__(256) k_scan1(const int* __restrict__ deg,
                                               int* __restrict__ excl, int* __restrict__ bsum) {
    __shared__ int s[256];
    int t = threadIdx.x;
    int i = blockIdx.x * 256 + t;
    int v = (i < kNodes) ? deg[i] : 0;
    s[t] = v;
    __syncthreads();
    for (int o = 1; o < 256; o <<= 1) {
        int tv = (t >= o) ? s[t - o] : 0;
        __syncthreads();
        s[t] += tv;
        __syncthreads();
    }
    if (i < kNodes) excl[i] = s[t] - v;
    if (t == 255) bsum[blockIdx.x] = s[255];
}

__global__ void __launch_bounds__(256) k_scan2(int* __restrict__ bsum, int nb) {
    __shared__ int s[256];
    int t = threadIdx.x;
    int v = (t < nb) ? bsum[t] : 0;
    s[t] = v;
    __syncthreads();
    for (int o = 1; o < 256; o <<= 1) {
        int tv = (t >= o) ? s[t - o] : 0;
        __syncthreads();
        s[t] += tv;
        __syncthreads();
    }
    if (t < nb) bsum[t] = s[t];
}

__global__ void __launch_bounds__(256) k_scan3(int* __restrict__ excl, const int* __restrict__ bsum) {
    int i = blockIdx.x * 256 + threadIdx.x;
    if (i >= kNodes) return;
    if (blockIdx.x > 0) excl[i] += bsum[blockIdx.x - 1];
}

__global__ void __launch_bounds__(256) k_reorder(
    const int* __restrict__ src, const int* __restrict__ dst, const float* __restrict__ ea,
    const int* __restrict__ rowptr, int* __restrict__ cur,
    int* __restrict__ esrc, float* __restrict__ eea) {
    int e = blockIdx.x * 256 + threadIdx.x;
    if (e >= kNE) return;
    int d = dst[e];
    int pos = rowptr[d] + atomicAdd(&cur[d], 1);
    esrc[pos] = src[e];
    eea[pos]  = ea[e];
}

// ---- K3: fused edge phase, 2 features/lane, 1 wave/node, 4 nodes/block.
// Lane t owns features (2t, 2t+1); head = t>>4 (16 lanes/head).
// Edge metadata lives in registers: lanes 0-31 hold src (int bits), lanes
// 32-63 hold ea; broadcast per edge via __shfl. No LDS, no __syncthreads.
__global__ void __launch_bounds__(256) k_edge(
    const int* __restrict__ rowptr, const int* __restrict__ deg,
    const int* __restrict__ esrc, const float* __restrict__ eea,
    const __half* __restrict__ xl, float* __restrict__ xrg,
    const float* __restrict__ We, const float* __restrict__ att,
    const float* __restrict__ gat_b, float* __restrict__ ps, float* __restrict__ pq) {
    int t = threadIdx.x & 63;             // lane
    int w = threadIdx.x >> 6;             // wave 0..3
    int d = blockIdx.x * 4 + w;           // node (50000 = 12500 * 4 exact)
    const __half2* xl2 = (const __half2*)xl;
    long rowb = (long)d * 64;             // row offset in half2/float2 units

    float2 xrv = ((const float2*)xrg)[rowb + t];
    float2 Wev = ((const float2*)We)[t];
    float2 av  = ((const float2*)att)[t];
    av.x *= kL2E; av.y *= kL2E;           // fold ln2 into att -> single v_exp

    float2 xself = __half22float2(xl2[rowb + t]);

    // self loop (ea = 0)
    float z0 = xself.x + xrv.x, z1 = xself.y + xrv.y;
    z0 = fmaxf(z0, kSlope * z0); z1 = fmaxf(z1, kSlope * z1);
    float p = z0 * av.x + z1 * av.y;
    #pragma unroll
    for (int mm = 1; mm < 16; mm <<= 1) p += __shfl_xor(p, mm);
    float ee = __builtin_amdgcn_exp2f(p - kShift2);
    float l = ee, o0 = ee * xself.x, o1 = ee * xself.y;

    int base = rowptr[d], cnt = deg[d];
    for (int eoff = 0; eoff < cnt; eoff += 32) {
        int cc = min(32, cnt - eoff);
        float meta = 0.f;
        if (t < 32) {
            if (t < cc) meta = __int_as_float(esrc[base + eoff + t]);
        } else {
            int u = t - 32;
            if (u < cc) meta = eea[base + eoff + u];
        }
        int e = 0;
        for (; e + 8 <= cc; e += 8) {
            float2 xv[8]; float pv[8];
            #pragma unroll
            for (int u = 0; u < 8; ++u) {
                int s = __float_as_int(__shfl(meta, e + u));
                xv[u] = __half22float2(xl2[(long)s * 64 + t]);
            }
            #pragma unroll
            for (int u = 0; u < 8; ++u) {
                float eav = __shfl(meta, 32 + e + u);
                float zz0 = fmaf(eav, Wev.x, xrv.x) + xv[u].x;
                float zz1 = fmaf(eav, Wev.y, xrv.y) + xv[u].y;
                zz0 = fmaxf(zz0, kSlope * zz0);
                zz1 = fmaxf(zz1, kSlope * zz1);
                pv[u] = zz0 * av.x + zz1 * av.y;
            }
            #pragma unroll
            for (int mm = 1; mm < 16; mm <<= 1) {
                #pragma unroll
                for (int u = 0; u < 8; ++u) pv[u] += __shfl_xor(pv[u], mm);
            }
            #pragma unroll
            for (int u = 0; u < 8; ++u) {
                float eeu = __builtin_amdgcn_exp2f(pv[u] - kShift2);
                l += eeu;
                o0 = fmaf(eeu, xv[u].x, o0);
                o1 = fmaf(eeu, xv[u].y, o1);
            }
        }
        for (; e < cc; ++e) {
            int s = __float_as_int(__shfl(meta, e));
            float eav = __shfl(meta, 32 + e);
            float2 xv = __half22float2(xl2[(long)s * 64 + t]);
            float zz0 = fmaf(eav, Wev.x, xrv.x) + xv.x;
            float zz1 = fmaf(eav, Wev.y, xrv.y) + xv.y;
            zz0 = fmaxf(zz0, kSlope * zz0);
            zz1 = fmaxf(zz1, kSlope * zz1);
            float pe = zz0 * av.x + zz1 * av.y;
            #pragma unroll
            for (int mm = 1; mm < 16; mm <<= 1) pe += __shfl_xor(pe, mm);
            float eeu = __builtin_amdgcn_exp2f(pe - kShift2);
            l += eeu;
            o0 = fmaf(eeu, xv.x, o0);
            o1 = fmaf(eeu, xv.y, o1);
        }
    }
    float rl = __builtin_amdgcn_rcpf(l);
    float v0 = o0 * rl, v1 = o1 * rl;
    ((float2*)xrg)[rowb + t] = make_float2(v0, v1);   // g overwrites xr (row-private)
    float2 gb = ((const float2*)gat_b)[t];
    float vb0 = v0 + gb.x, vb1 = v1 + gb.y;
    float s = vb0 + vb1, q = vb0 * vb0 + vb1 * vb1;
    #pragma unroll
    for (int mm = 1; mm < 64; mm <<= 1) { s += __shfl_xor(s, mm); q += __shfl_xor(q, mm); }
    if (t == 0) { ps[d] = s; pq[d] = q; }
}

// ---- K4: reduce per-node partials -> stats[2].
__global__ void __launch_bounds__(1024) k_statsr(
    const float* __restrict__ ps, const float* __restrict__ pq, float* __restrict__ stats) {
    __shared__ float rs[1024], rq[1024];
    int t = threadIdx.x;
    float s = 0.f, q = 0.f;
    for (int i = t; i < kNodes; i += 1024) { s += ps[i]; q += pq[i]; }
    rs[t] = s; rq[t] = q;
    __syncthreads();
    for (int o = 512; o > 0; o >>= 1) {
        if (t < o) { rs[t] += rs[t + o]; rq[t] += rq[t + o]; }
        __syncthreads();
    }
    if (t == 0) { stats[0] = rs[0]; stats[1] = rq[0]; }
}

// ---- K5: h = relu(node_ln(relu(graph_ln(g+gat_b)) @ lin_w + lin_b)); jk_out = max(jk_in, h)
// lin_w staged TRANSPOSED pad-130 -> float4(vb, broadcast) + 2x float2(w) per 4 FMA.
__global__ void __launch_bounds__(256) k_post(
    const float* __restrict__ g, const float* __restrict__ gat_b,
    const float* __restrict__ ln1w, const float* __restrict__ ln1b,
    const float* __restrict__ linw, const float* __restrict__ linb,
    const float* __restrict__ ln2w, const float* __restrict__ ln2b,
    const float* __restrict__ stats, const float* __restrict__ jk_in,
    float* __restrict__ h, float* __restrict__ jk_out) {
    __shared__ float s_lwT[kC * kLWP];    // 16.6 KB, lin_w transposed
    __shared__ float s_vb[8 * kHC];       // 4 KB
    int t = threadIdx.x;
    int n0 = blockIdx.x * 8;
    const float inv = 1.f / ((float)kNodes * kHC);
    float mean = stats[0] * inv;
    float var  = stats[1] * inv - mean * mean;
    float rstd = rsqrtf(var + kEps);
    for (int i = t; i < kHC * kC; i += 256) {
        int k = i >> 5, c = i & 31;
        s_lwT[c * kLWP + k] = linw[i];
    }
    for (int i = t; i < 8 * kHC; i += 256) {
        int node = n0 + (i >> 7), f = i & 127;
        float a = (g[(long)node * kHC + f] + gat_b[f] - mean) * rstd * ln1w[f] + ln1b[f];
        s_vb[i] = fmaxf(a, 0.f);
    }
    __syncthreads();
    int n = t >> 5, c = t & 31;
    int node = n0 + n;
    float acc = linb[c];
    const float* vb = s_vb + n * kHC;
    const float* wr = s_lwT + c * kLWP;
    #pragma unroll 8
    for (int k = 0; k < kHC; k += 4) {
        float4 v4 = *(const float4*)(vb + k);
        float2 w0 = *(const float2*)(wr + k);
        float2 w1 = *(const float2*)(wr + k + 2);
        acc += v4.x * w0.x + v4.y * w0.y + v4.z * w1.x + v4.w * w1.y;
    }
    float m = acc;
    #pragma unroll
    for (int mm = 1; mm < 32; mm <<= 1) m += __shfl_xor(m, mm);
    m *= (1.f / kC);
    float dd = acc - m;
    float q = dd * dd;
    #pragma unroll
    for (int mm = 1; mm < 32; mm <<= 1) q += __shfl_xor(q, mm);
    q *= (1.f / kC);
    float out = dd * rsqrtf(q + kEps) * ln2w[c] + ln2b[c];
    out = fmaxf(out, 0.f);
    h[node * kC + c] = out;
    jk_out[node * kC + c] = fmaxf(jk_in[node * kC + c], out);
}

extern "C" void kernel_launch(void* const* d_in, const int* in_sizes, int n_in,
                              void* d_out, int out_size, void* d_ws, size_t ws_size,
                              hipStream_t stream) {
    (void)in_sizes; (void)n_in; (void)out_size; (void)ws_size;
    const float* x     = (const float*)d_in[0];
    const int*   ei    = (const int*)d_in[1];
    const int*   src   = ei;
    const int*   dst   = ei + kNE;
    const float* ea    = (const float*)d_in[2];
    const float* W_emb = (const float*)d_in[3];
    const float* b_emb = (const float*)d_in[4];
    const float* ln0w  = (const float*)d_in[5];
    const float* ln0b  = (const float*)d_in[6];
    const float* Wl    = (const float*)d_in[7];
    const float* bl    = (const float*)d_in[8];
    const float* Wr    = (const float*)d_in[9];
    const float* br    = (const float*)d_in[10];
    const float* We    = (const float*)d_in[11];
    const float* att   = (const float*)d_in[12];
    const float* gat_b = (const float*)d_in[13];
    const float* ln1w  = (const float*)d_in[14];
    const float* ln1b  = (const float*)d_in[15];
    const float* linw  = (const float*)d_in[16];
    const float* linb  = (const float*)d_in[17];
    const float* ln2w  = (const float*)d_in[18];
    const float* ln2b  = (const float*)d_in[19];

    char* wsb = (char*)d_ws;
    float*  h      = (float*)(wsb);                 // 6.4e6 B
    float*  jk     = (float*)(wsb +  6400000);      // 6.4e6 B
    float*  xrg    = (float*)(wsb + 12800000);      // 25.6e6 B (xr, later g)
    __half* xl     = (__half*)(wsb + 38400000);     // 12.8e6 B
    int*    esrc   = (int*)(wsb + 51200000);        // 3.2e6 B
    float*  eea    = (float*)(wsb + 54400000);      // 3.2e6 B
    int*    deg    = (int*)(wsb + 57600000);        // 0.2e6 B
    int*    cur    = (int*)(wsb + 57800000);        // 0.2e6 B
    int*    rowptr = (int*)(wsb + 58000000);        // 0.2e6 B
    int*    bsum   = (int*)(wsb + 58200000);        // 1 KB
    float*  stats  = (float*)(wsb + 58201024);      // 8 B
    float*  ps     = (float*)(wsb + 58300000);      // 0.2e6 B
    float*  pq     = (float*)(wsb + 58500000);      // 0.2e6 B

    const int scanBlocks  = (kNodes + 255) / 256;        // 196
    const int embedBlocks = kNodes / kTN;                // 3125 exact
    const int transBlocks = (kNodes + 31) / 32;          // 1563
    const int eBlocks     = (kNE + 255) / 256;
    const int edgeBlocks  = kNodes / 4;                  // 12500 exact, 4 nodes/block
    const int postBlocks  = kNodes / 8;                  // 6250 exact

    hipLaunchKernelGGL(k_embed, dim3(embedBlocks), dim3(256), 0, stream,
                       x, W_emb, b_emb, ln0w, ln0b, h, jk);
    // CSR build (once; dst is layer-invariant)
    hipLaunchKernelGGL(k_fill0, dim3((2 * kNodes + 255) / 256), dim3(256), 0, stream,
                       (unsigned*)deg, 2 * kNodes);      // deg + cur
    hipLaunchKernelGGL(k_hist, dim3(eBlocks), dim3(256), 0, stream, dst, deg);
    hipLaunchKernelGGL(k_scan1, dim3(scanBlocks), dim3(256), 0, stream, deg, rowptr, bsum);
    hipLaunchKernelGGL(k_scan2, dim3(1), dim3(256), 0, stream, bsum, scanBlocks);
    hipLaunchKernelGGL(k_scan3, dim3(scanBlocks), dim3(256), 0, stream, rowptr, bsum);
    hipLaunchKernelGGL(k_reorder, dim3(eBlocks), dim3(256), 0, stream,
                       src, dst, ea, rowptr, cur, esrc, eea);
    for (int l = 0; l < 2; ++l) {
        hipLaunchKernelGGL(k_trans, dim3(transBlocks), dim3(256), 0, stream,
                           h, Wl + l * kC * kHC, bl + l * kHC,
                           Wr + l * kC * kHC, br + l * kHC, xl, xrg);
        hipLaunchKernelGGL(k_edge, dim3(edgeBlocks), dim3(256), 0, stream,
                           rowptr, deg, esrc, eea, xl, xrg,
                           We + l * kHC, att + l * kH * kC, gat_b + l * kHC, ps, pq);
        hipLaunchKernelGGL(k_statsr, dim3(1), dim3(1024), 0, stream, ps, pq, stats);
        hipLaunchKernelGGL(k_post, dim3(postBlocks), dim3(256), 0, stream,
                           xrg, gat_b + l * kHC, ln1w + l * kHC, ln1b + l * kHC,
                           linw + l * kHC * kC, linb + l * kC,
                           ln2w + l * kC, ln2b + l * kC, stats, jk,
                           h, (l == 1) ? (float*)d_out : jk);
    }
}

// Round 3
// 488.221 us; speedup vs baseline: 1.1549x; 1.1549x over previous
//
#include <hip/hip_runtime.h>
#include <hip/hip_fp16.h>

constexpr int kNodes = 50000;
constexpr int kNE    = 800000;            // edges before self loops
constexpr int kFin   = 256;
constexpr int kC     = 32;
constexpr int kH     = 4;
constexpr int kHC    = 128;               // kH * kC
constexpr int kTN    = 16;                // nodes per k_embed block
constexpr int kWP    = 258;               // padded sWt row (2-way LDS alias = free)
constexpr int kLWP   = 130;               // padded s_lwT row in k_post (float2-aligned, 2-way alias)
constexpr float kEps   = 1e-5f;
constexpr float kSlope = 0.2f;
constexpr float kL2E   = 1.44269504f;     // log2(e): fold into att so exp is 1 instr
constexpr float kShift2 = 8.0f * 1.44269504f; // softmax-invariant shift (exp2 domain)

// ---- DPP butterfly add: v += partner(v), pure VALU (no DS pipe).
template<int CTRL>
__device__ __forceinline__ float dpp_add(float v) {
    int x = __builtin_amdgcn_update_dpp(0, __float_as_int(v), CTRL, 0xF, 0xF, true);
    return v + __int_as_float(x);
}
// 16-lane sum: xor1(quad_perm 1,0,3,2), xor2(quad_perm 2,3,0,1),
// row_half_mirror (xor7: valid once quads uniform), row_mirror (xor15: valid once octets uniform).
__device__ __forceinline__ float red16(float p) {
    p = dpp_add<0xB1>(p);
    p = dpp_add<0x4E>(p);
    p = dpp_add<0x141>(p);
    p = dpp_add<0x140>(p);
    return p;
}

// ---- zero-fill
__global__ void __launch_bounds__(256) k_fill0(unsigned* __restrict__ p, int n) {
    int i = blockIdx.x * 256 + threadIdx.x;
    if (i < n) p[i] = 0u;
}

// ---- K1: h0 = relu(node_ln(x @ W_emb + b_emb)); jk = h0.
// 16 nodes/block; x staged (16KB), W staged TRANSPOSED pad-258 (33KB).  [R1 version]
__global__ void __launch_bounds__(256) k_embed(
    const float* __restrict__ x, const float* __restrict__ W, const float* __restrict__ b,
    const float* __restrict__ lnw, const float* __restrict__ lnb,
    float* __restrict__ h, float* __restrict__ jk) {
    __shared__ float sx[kTN * kFin];      // 16 KB
    __shared__ float sWt[kC * kWP];       // 33 KB
    int t = threadIdx.x;
    int n0 = blockIdx.x * kTN;            // 50000 = 3125 * 16 exact
    for (int i = t; i < kFin * kC; i += 256) {
        int k = i >> 5, c = i & 31;
        sWt[c * kWP + k] = W[i];
    }
    const float* xg = x + (long)n0 * kFin;
    for (int i = t; i < kTN * kFin; i += 256) sx[i] = xg[i];
    __syncthreads();
    int c = t & 31, n2 = t >> 5;          // n2 = 0..7
    const float* xa = sx + n2 * kFin;
    const float* xb = sx + (n2 + 8) * kFin;
    const float* wrow = sWt + c * kWP;
    float acc0 = 0.f, acc1 = 0.f;
    #pragma unroll 8
    for (int k = 0; k < kFin; k += 4) {
        float4 x0 = *(const float4*)(xa + k);
        float4 x1 = *(const float4*)(xb + k);
        float2 w0 = *(const float2*)(wrow + k);
        float2 w1 = *(const float2*)(wrow + k + 2);
        acc0 += x0.x * w0.x + x0.y * w0.y + x0.z * w1.x + x0.w * w1.y;
        acc1 += x1.x * w0.x + x1.y * w0.y + x1.z * w1.x + x1.w * w1.y;
    }
    float bc = b[c], lw = lnw[c], lb = lnb[c];
    // node n2
    {
        float y = acc0 + bc;
        float m = y;
        #pragma unroll
        for (int o = 1; o < 32; o <<= 1) m += __shfl_xor(m, o);
        m *= (1.f / kC);
        float xc = y - m, v = xc * xc;
        #pragma unroll
        for (int o = 1; o < 32; o <<= 1) v += __shfl_xor(v, o);
        v *= (1.f / kC);
        float out = fmaxf(xc * rsqrtf(v + kEps) * lw + lb, 0.f);
        int node = n0 + n2;
        h[node * kC + c] = out;
        jk[node * kC + c] = out;
    }
    // node n2 + 8
    {
        float y = acc1 + bc;
        float m = y;
        #pragma unroll
        for (int o = 1; o < 32; o <<= 1) m += __shfl_xor(m, o);
        m *= (1.f / kC);
        float xc = y - m, v = xc * xc;
        #pragma unroll
        for (int o = 1; o < 32; o <<= 1) v += __shfl_xor(v, o);
        v *= (1.f / kC);
        float out = fmaxf(xc * rsqrtf(v + kEps) * lw + lb, 0.f);
        int node = n0 + n2 + 8;
        h[node * kC + c] = out;
        jk[node * kC + c] = out;
    }
}

// ---- K2: xl = h@Wl + bl (fp16) ; xr = h@Wr + br (fp32).
__global__ void __launch_bounds__(256) k_trans(
    const float* __restrict__ h,
    const float* __restrict__ Wl, const float* __restrict__ bl,
    const float* __restrict__ Wr, const float* __restrict__ br,
    __half* __restrict__ xl, float* __restrict__ xr) {
    __shared__ float s_h[32 * kC];
    int t = threadIdx.x;
    int j = t & 127, hf = t >> 7;
    float wl[kC], wr[kC];
    #pragma unroll
    for (int k = 0; k < kC; ++k) { wl[k] = Wl[k * kHC + j]; wr[k] = Wr[k * kHC + j]; }
    float blj = bl[j], brj = br[j];
    int n0 = blockIdx.x * 32;
    int nn = min(32, kNodes - n0);
    for (int i = t; i < nn * kC; i += 256) s_h[i] = h[n0 * kC + i];
    __syncthreads();
    int nend = min(nn, hf * 16 + 16);
    for (int n = hf * 16; n < nend; ++n) {
        const float4* h4 = (const float4*)(s_h + n * kC);
        float al = blj, ar = brj;
        #pragma unroll
        for (int kq = 0; kq < 8; ++kq) {
            float4 hv = h4[kq];
            al += hv.x * wl[kq*4] + hv.y * wl[kq*4+1] + hv.z * wl[kq*4+2] + hv.w * wl[kq*4+3];
            ar += hv.x * wr[kq*4] + hv.y * wr[kq*4+1] + hv.z * wr[kq*4+2] + hv.w * wr[kq*4+3];
        }
        long g = (long)(n0 + n) * kHC + j;
        xl[g] = __float2half(al);
        xr[g] = ar;
    }
}

// ---- CSR build (dst is layer-invariant: built ONCE)
__global__ void __launch_bounds__(256) k_hist(const int* __restrict__ dst, int* __restrict__ deg) {
    int e = blockIdx.x * 256 + threadIdx.x;
    if (e < kNE) atomicAdd(&deg[dst[e]], 1);
}

__global__ void __launch_bounds__(256) k_scan1(const int* __restrict__ deg,
                                               int* __restrict__ excl, int* __restrict__ bsum) {
    __shared__ int s[256];
    int t = threadIdx.x;
    int i = blockIdx.x * 256 + t;
    int v = (i < kNodes) ? deg[i] : 0;
    s[t] = v;
    __syncthreads();
    for (int o = 1; o < 256; o <<= 1) {
        int tv = (t >= o) ? s[t - o] : 0;
        __syncthreads();
        s[t] += tv;
        __syncthreads();
    }
    if (i < kNodes) excl[i] = s[t] - v;
    if (t == 255) bsum[blockIdx.x] = s[255];
}

__global__ void __launch_bounds__(256) k_scan2(int* __restrict__ bsum, int nb) {
    __shared__ int s[256];
    int t = threadIdx.x;
    int v = (t < nb) ? bsum[t] : 0;
    s[t] = v;
    __syncthreads();
    for (int o = 1; o < 256; o <<= 1) {
        int tv = (t >= o) ? s[t - o] : 0;
        __syncthreads();
        s[t] += tv;
        __syncthreads();
    }
    if (t < nb) bsum[t] = s[t];
}

__global__ void __launch_bounds__(256) k_scan3(int* __restrict__ excl, const int* __restrict__ bsum) {
    int i = blockIdx.x * 256 + threadIdx.x;
    if (i >= kNodes) return;
    if (blockIdx.x > 0) excl[i] += bsum[blockIdx.x - 1];
}

__global__ void __launch_bounds__(256) k_reorder(
    const int* __restrict__ src, const int* __restrict__ dst, const float* __restrict__ ea,
    const int* __restrict__ rowptr, int* __restrict__ cur,
    int* __restrict__ esrc, float* __restrict__ eea) {
    int e = blockIdx.x * 256 + threadIdx.x;
    if (e >= kNE) return;
    int d = dst[e];
    int pos = rowptr[d] + atomicAdd(&cur[d], 1);
    esrc[pos] = src[e];
    eea[pos]  = ea[e];
}

// ---- K3: fused edge phase, 2 features/lane, 1 wave/node, 4 nodes/block.
// d is wave-uniform (readfirstlane) -> esrc/eea loads go to the SCALAR pipe
// (s_load), gather bases computed on SALU. Logit reduce via DPP (pure VALU).
// DS-pipe ops per edge: 0.
__global__ void __launch_bounds__(256) k_edge(
    const int* __restrict__ rowptr, const int* __restrict__ deg,
    const int* __restrict__ esrc, const float* __restrict__ eea,
    const __half* __restrict__ xl, float* __restrict__ xrg,
    const float* __restrict__ We, const float* __restrict__ att,
    const float* __restrict__ gat_b, float* __restrict__ ps, float* __restrict__ pq) {
    int t = threadIdx.x & 63;             // lane
    int w = __builtin_amdgcn_readfirstlane(threadIdx.x >> 6);   // wave 0..3 (uniform)
    int d = blockIdx.x * 4 + w;           // node (50000 = 12500 * 4 exact)
    const __half2* xl2 = (const __half2*)xl;
    long rowb = (long)d * 64;             // row offset in half2/float2 units

    float2 xrv = ((const float2*)xrg)[rowb + t];
    float2 Wev = ((const float2*)We)[t];
    float2 av  = ((const float2*)att)[t];
    av.x *= kL2E; av.y *= kL2E;           // fold ln2 into att -> single v_exp

    float2 xself = __half22float2(xl2[rowb + t]);

    // self loop (ea = 0)
    float z0 = xself.x + xrv.x, z1 = xself.y + xrv.y;
    z0 = fmaxf(z0, kSlope * z0); z1 = fmaxf(z1, kSlope * z1);
    float p = red16(z0 * av.x + z1 * av.y);
    float ee = __builtin_amdgcn_exp2f(p - kShift2);
    float l = ee, o0 = ee * xself.x, o1 = ee * xself.y;

    int base = rowptr[d], cnt = deg[d];   // uniform -> SGPR
    int e = 0;
    for (; e + 8 <= cnt; e += 8) {
        int se[8]; float ev[8];
        #pragma unroll
        for (int u = 0; u < 8; ++u) { se[u] = esrc[base + e + u]; ev[u] = eea[base + e + u]; }
        float2 xv[8]; float pv[8];
        #pragma unroll
        for (int u = 0; u < 8; ++u)
            xv[u] = __half22float2(xl2[(long)se[u] * 64 + t]);
        #pragma unroll
        for (int u = 0; u < 8; ++u) {
            float zz0 = fmaf(ev[u], Wev.x, xrv.x) + xv[u].x;
            float zz1 = fmaf(ev[u], Wev.y, xrv.y) + xv[u].y;
            zz0 = fmaxf(zz0, kSlope * zz0);
            zz1 = fmaxf(zz1, kSlope * zz1);
            pv[u] = red16(zz0 * av.x + zz1 * av.y);
        }
        #pragma unroll
        for (int u = 0; u < 8; ++u) {
            float eeu = __builtin_amdgcn_exp2f(pv[u] - kShift2);
            l += eeu;
            o0 = fmaf(eeu, xv[u].x, o0);
            o1 = fmaf(eeu, xv[u].y, o1);
        }
    }
    for (; e < cnt; ++e) {
        int s = esrc[base + e];
        float eav = eea[base + e];
        float2 xv = __half22float2(xl2[(long)s * 64 + t]);
        float zz0 = fmaf(eav, Wev.x, xrv.x) + xv.x;
        float zz1 = fmaf(eav, Wev.y, xrv.y) + xv.y;
        zz0 = fmaxf(zz0, kSlope * zz0);
        zz1 = fmaxf(zz1, kSlope * zz1);
        float pe = red16(zz0 * av.x + zz1 * av.y);
        float eeu = __builtin_amdgcn_exp2f(pe - kShift2);
        l += eeu;
        o0 = fmaf(eeu, xv.x, o0);
        o1 = fmaf(eeu, xv.y, o1);
    }
    float rl = __builtin_amdgcn_rcpf(l);
    float v0 = o0 * rl, v1 = o1 * rl;
    ((float2*)xrg)[rowb + t] = make_float2(v0, v1);   // g overwrites xr (row-private)
    float2 gb = ((const float2*)gat_b)[t];
    float vb0 = v0 + gb.x, vb1 = v1 + gb.y;
    float s = vb0 + vb1, q = vb0 * vb0 + vb1 * vb1;
    #pragma unroll
    for (int mm = 1; mm < 64; mm <<= 1) { s += __shfl_xor(s, mm); q += __shfl_xor(q, mm); }
    if (t == 0) { ps[d] = s; pq[d] = q; }
}

// ---- K4: reduce per-node partials -> stats[2].
__global__ void __launch_bounds__(1024) k_statsr(
    const float* __restrict__ ps, const float* __restrict__ pq, float* __restrict__ stats) {
    __shared__ float rs[1024], rq[1024];
    int t = threadIdx.x;
    float s = 0.f, q = 0.f;
    for (int i = t; i < kNodes; i += 1024) { s += ps[i]; q += pq[i]; }
    rs[t] = s; rq[t] = q;
    __syncthreads();
    for (int o = 512; o > 0; o >>= 1) {
        if (t < o) { rs[t] += rs[t + o]; rq[t] += rq[t + o]; }
        __syncthreads();
    }
    if (t == 0) { stats[0] = rs[0]; stats[1] = rq[0]; }
}

// ---- K5: h = relu(node_ln(relu(graph_ln(g+gat_b)) @ lin_w + lin_b)); jk_out = max(jk_in, h)
// lin_w staged TRANSPOSED pad-130 -> float4(vb, broadcast) + 2x float2(w) per 4 FMA.
__global__ void __launch_bounds__(256) k_post(
    const float* __restrict__ g, const float* __restrict__ gat_b,
    const float* __restrict__ ln1w, const float* __restrict__ ln1b,
    const float* __restrict__ linw, const float* __restrict__ linb,
    const float* __restrict__ ln2w, const float* __restrict__ ln2b,
    const float* __restrict__ stats, const float* __restrict__ jk_in,
    float* __restrict__ h, float* __restrict__ jk_out) {
    __shared__ float s_lwT[kC * kLWP];    // 16.6 KB, lin_w transposed
    __shared__ float s_vb[8 * kHC];       // 4 KB
    int t = threadIdx.x;
    int n0 = blockIdx.x * 8;
    const float inv = 1.f / ((float)kNodes * kHC);
    float mean = stats[0] * inv;
    float var  = stats[1] * inv - mean * mean;
    float rstd = rsqrtf(var + kEps);
    for (int i = t; i < kHC * kC; i += 256) {
        int k = i >> 5, c = i & 31;
        s_lwT[c * kLWP + k] = linw[i];
    }
    for (int i = t; i < 8 * kHC; i += 256) {
        int node = n0 + (i >> 7), f = i & 127;
        float a = (g[(long)node * kHC + f] + gat_b[f] - mean) * rstd * ln1w[f] + ln1b[f];
        s_vb[i] = fmaxf(a, 0.f);
    }
    __syncthreads();
    int n = t >> 5, c = t & 31;
    int node = n0 + n;
    float acc = linb[c];
    const float* vb = s_vb + n * kHC;
    const float* wr = s_lwT + c * kLWP;
    #pragma unroll 8
    for (int k = 0; k < kHC; k += 4) {
        float4 v4 = *(const float4*)(vb + k);
        float2 w0 = *(const float2*)(wr + k);
        float2 w1 = *(const float2*)(wr + k + 2);
        acc += v4.x * w0.x + v4.y * w0.y + v4.z * w1.x + v4.w * w1.y;
    }
    float m = acc;
    #pragma unroll
    for (int mm = 1; mm < 32; mm <<= 1) m += __shfl_xor(m, mm);
    m *= (1.f / kC);
    float dd = acc - m;
    float q = dd * dd;
    #pragma unroll
    for (int mm = 1; mm < 32; mm <<= 1) q += __shfl_xor(q, mm);
    q *= (1.f / kC);
    float out = dd * rsqrtf(q + kEps) * ln2w[c] + ln2b[c];
    out = fmaxf(out, 0.f);
    h[node * kC + c] = out;
    jk_out[node * kC + c] = fmaxf(jk_in[node * kC + c], out);
}

extern "C" void kernel_launch(void* const* d_in, const int* in_sizes, int n_in,
                              void* d_out, int out_size, void* d_ws, size_t ws_size,
                              hipStream_t stream) {
    (void)in_sizes; (void)n_in; (void)out_size; (void)ws_size;
    const float* x     = (const float*)d_in[0];
    const int*   ei    = (const int*)d_in[1];
    const int*   src   = ei;
    const int*   dst   = ei + kNE;
    const float* ea    = (const float*)d_in[2];
    const float* W_emb = (const float*)d_in[3];
    const float* b_emb = (const float*)d_in[4];
    const float* ln0w  = (const float*)d_in[5];
    const float* ln0b  = (const float*)d_in[6];
    const float* Wl    = (const float*)d_in[7];
    const float* bl    = (const float*)d_in[8];
    const float* Wr    = (const float*)d_in[9];
    const float* br    = (const float*)d_in[10];
    const float* We    = (const float*)d_in[11];
    const float* att   = (const float*)d_in[12];
    const float* gat_b = (const float*)d_in[13];
    const float* ln1w  = (const float*)d_in[14];
    const float* ln1b  = (const float*)d_in[15];
    const float* linw  = (const float*)d_in[16];
    const float* linb  = (const float*)d_in[17];
    const float* ln2w  = (const float*)d_in[18];
    const float* ln2b  = (const float*)d_in[19];

    char* wsb = (char*)d_ws;
    float*  h      = (float*)(wsb);                 // 6.4e6 B
    float*  jk     = (float*)(wsb +  6400000);      // 6.4e6 B
    float*  xrg    = (float*)(wsb + 12800000);      // 25.6e6 B (xr, later g)
    __half* xl     = (__half*)(wsb + 38400000);     // 12.8e6 B
    int*    esrc   = (int*)(wsb + 51200000);        // 3.2e6 B
    float*  eea    = (float*)(wsb + 54400000);      // 3.2e6 B
    int*    deg    = (int*)(wsb + 57600000);        // 0.2e6 B
    int*    cur    = (int*)(wsb + 57800000);        // 0.2e6 B
    int*    rowptr = (int*)(wsb + 58000000);        // 0.2e6 B
    int*    bsum   = (int*)(wsb + 58200000);        // 1 KB
    float*  stats  = (float*)(wsb + 58201024);      // 8 B
    float*  ps     = (float*)(wsb + 58300000);      // 0.2e6 B
    float*  pq     = (float*)(wsb + 58500000);      // 0.2e6 B

    const int scanBlocks  = (kNodes + 255) / 256;        // 196
    const int embedBlocks = kNodes / kTN;                // 3125 exact
    const int transBlocks = (kNodes + 31) / 32;          // 1563
    const int eBlocks     = (kNE + 255) / 256;
    const int edgeBlocks  = kNodes / 4;                  // 12500 exact, 4 nodes/block
    const int postBlocks  = kNodes / 8;                  // 6250 exact

    hipLaunchKernelGGL(k_embed, dim3(embedBlocks), dim3(256), 0, stream,
                       x, W_emb, b_emb, ln0w, ln0b, h, jk);
    // CSR build (once; dst is layer-invariant)
    hipLaunchKernelGGL(k_fill0, dim3((2 * kNodes + 255) / 256), dim3(256), 0, stream,
                       (unsigned*)deg, 2 * kNodes);      // deg + cur
    hipLaunchKernelGGL(k_hist, dim3(eBlocks), dim3(256), 0, stream, dst, deg);
    hipLaunchKernelGGL(k_scan1, dim3(scanBlocks), dim3(256), 0, stream, deg, rowptr, bsum);
    hipLaunchKernelGGL(k_scan2, dim3(1), dim3(256), 0, stream, bsum, scanBlocks);
    hipLaunchKernelGGL(k_scan3, dim3(scanBlocks), dim3(256), 0, stream, rowptr, bsum);
    hipLaunchKernelGGL(k_reorder, dim3(eBlocks), dim3(256), 0, stream,
                       src, dst, ea, rowptr, cur, esrc, eea);
    for (int l = 0; l < 2; ++l) {
        hipLaunchKernelGGL(k_trans, dim3(transBlocks), dim3(256), 0, stream,
                           h, Wl + l * kC * kHC, bl + l * kHC,
                           Wr + l * kC * kHC, br + l * kHC, xl, xrg);
        hipLaunchKernelGGL(k_edge, dim3(edgeBlocks), dim3(256), 0, stream,
                           rowptr, deg, esrc, eea, xl, xrg,
                           We + l * kHC, att + l * kH * kC, gat_b + l * kHC, ps, pq);
        hipLaunchKernelGGL(k_statsr, dim3(1), dim3(1024), 0, stream, ps, pq, stats);
        hipLaunchKernelGGL(k_post, dim3(postBlocks), dim3(256), 0, stream,
                           xrg, gat_b + l * kHC, ln1w + l * kHC, ln1b + l * kHC,
                           linw + l * kHC * kC, linb + l * kC,
                           ln2w + l * kC, ln2b + l * kC, stats, jk,
                           h, (l == 1) ? (float*)d_out : jk);
    }
}

// Round 4
// 482.131 us; speedup vs baseline: 1.1695x; 1.0126x over previous
//
#include <hip/hip_runtime.h>
#include <hip/hip_fp16.h>

constexpr int kNodes = 50000;
constexpr int kNE    = 800000;            // edges before self loops
constexpr int kFin   = 256;
constexpr int kC     = 32;
constexpr int kH     = 4;
constexpr int kHC    = 128;               // kH * kC
constexpr int kTN    = 16;                // nodes per k_embed block
constexpr int kWP    = 258;               // padded sWt row (2-way LDS alias = free)
constexpr int kLWP   = 130;               // padded s_lwT row in k_post (float2-aligned, 2-way alias)
constexpr float kEps   = 1e-5f;
constexpr float kSlope = 0.2f;
constexpr float kL2E   = 1.44269504f;     // log2(e): fold into att so exp is 1 instr
constexpr float kShift2 = 8.0f * 1.44269504f; // softmax-invariant shift (exp2 domain)

// ---- DPP butterfly add: v += partner(v), pure VALU (no DS pipe).
template<int CTRL>
__device__ __forceinline__ float dpp_add(float v) {
    int x = __builtin_amdgcn_update_dpp(0, __float_as_int(v), CTRL, 0xF, 0xF, true);
    return v + __int_as_float(x);
}
// 16-lane sum: xor1(quad_perm 1,0,3,2), xor2(quad_perm 2,3,0,1),
// row_half_mirror (xor7: valid once quads uniform), row_mirror (xor15: valid once octets uniform).
__device__ __forceinline__ float red16(float p) {
    p = dpp_add<0xB1>(p);
    p = dpp_add<0x4E>(p);
    p = dpp_add<0x141>(p);
    p = dpp_add<0x140>(p);
    return p;
}

// ---- zero-fill
__global__ void __launch_bounds__(256) k_fill0(unsigned* __restrict__ p, int n) {
    int i = blockIdx.x * 256 + threadIdx.x;
    if (i < n) p[i] = 0u;
}

// ---- K1: h0 = relu(node_ln(x @ W_emb + b_emb)); jk = h0.
// 16 nodes/block; x staged (16KB), W staged TRANSPOSED pad-258 (33KB).
__global__ void __launch_bounds__(256) k_embed(
    const float* __restrict__ x, const float* __restrict__ W, const float* __restrict__ b,
    const float* __restrict__ lnw, const float* __restrict__ lnb,
    float* __restrict__ h, float* __restrict__ jk) {
    __shared__ float sx[kTN * kFin];      // 16 KB
    __shared__ float sWt[kC * kWP];       // 33 KB
    int t = threadIdx.x;
    int n0 = blockIdx.x * kTN;            // 50000 = 3125 * 16 exact
    for (int i = t; i < kFin * kC; i += 256) {
        int k = i >> 5, c = i & 31;
        sWt[c * kWP + k] = W[i];
    }
    const float* xg = x + (long)n0 * kFin;
    for (int i = t; i < kTN * kFin; i += 256) sx[i] = xg[i];
    __syncthreads();
    int c = t & 31, n2 = t >> 5;          // n2 = 0..7
    const float* xa = sx + n2 * kFin;
    const float* xb = sx + (n2 + 8) * kFin;
    const float* wrow = sWt + c * kWP;
    float acc0 = 0.f, acc1 = 0.f;
    #pragma unroll 8
    for (int k = 0; k < kFin; k += 4) {
        float4 x0 = *(const float4*)(xa + k);
        float4 x1 = *(const float4*)(xb + k);
        float2 w0 = *(const float2*)(wrow + k);
        float2 w1 = *(const float2*)(wrow + k + 2);
        acc0 += x0.x * w0.x + x0.y * w0.y + x0.z * w1.x + x0.w * w1.y;
        acc1 += x1.x * w0.x + x1.y * w0.y + x1.z * w1.x + x1.w * w1.y;
    }
    float bc = b[c], lw = lnw[c], lb = lnb[c];
    // node n2
    {
        float y = acc0 + bc;
        float m = y;
        #pragma unroll
        for (int o = 1; o < 32; o <<= 1) m += __shfl_xor(m, o);
        m *= (1.f / kC);
        float xc = y - m, v = xc * xc;
        #pragma unroll
        for (int o = 1; o < 32; o <<= 1) v += __shfl_xor(v, o);
        v *= (1.f / kC);
        float out = fmaxf(xc * rsqrtf(v + kEps) * lw + lb, 0.f);
        int node = n0 + n2;
        h[node * kC + c] = out;
        jk[node * kC + c] = out;
    }
    // node n2 + 8
    {
        float y = acc1 + bc;
        float m = y;
        #pragma unroll
        for (int o = 1; o < 32; o <<= 1) m += __shfl_xor(m, o);
        m *= (1.f / kC);
        float xc = y - m, v = xc * xc;
        #pragma unroll
        for (int o = 1; o < 32; o <<= 1) v += __shfl_xor(v, o);
        v *= (1.f / kC);
        float out = fmaxf(xc * rsqrtf(v + kEps) * lw + lb, 0.f);
        int node = n0 + n2 + 8;
        h[node * kC + c] = out;
        jk[node * kC + c] = out;
    }
}

// ---- K2: xl = h@Wl + bl (fp16) ; xr = h@Wr + br (fp32).
__global__ void __launch_bounds__(256) k_trans(
    const float* __restrict__ h,
    const float* __restrict__ Wl, const float* __restrict__ bl,
    const float* __restrict__ Wr, const float* __restrict__ br,
    __half* __restrict__ xl, float* __restrict__ xr) {
    __shared__ float s_h[32 * kC];
    int t = threadIdx.x;
    int j = t & 127, hf = t >> 7;
    float wl[kC], wr[kC];
    #pragma unroll
    for (int k = 0; k < kC; ++k) { wl[k] = Wl[k * kHC + j]; wr[k] = Wr[k * kHC + j]; }
    float blj = bl[j], brj = br[j];
    int n0 = blockIdx.x * 32;
    int nn = min(32, kNodes - n0);
    for (int i = t; i < nn * kC; i += 256) s_h[i] = h[n0 * kC + i];
    __syncthreads();
    int nend = min(nn, hf * 16 + 16);
    for (int n = hf * 16; n < nend; ++n) {
        const float4* h4 = (const float4*)(s_h + n * kC);
        float al = blj, ar = brj;
        #pragma unroll
        for (int kq = 0; kq < 8; ++kq) {
            float4 hv = h4[kq];
            al += hv.x * wl[kq*4] + hv.y * wl[kq*4+1] + hv.z * wl[kq*4+2] + hv.w * wl[kq*4+3];
            ar += hv.x * wr[kq*4] + hv.y * wr[kq*4+1] + hv.z * wr[kq*4+2] + hv.w * wr[kq*4+3];
        }
        long g = (long)(n0 + n) * kHC + j;
        xl[g] = __float2half(al);
        xr[g] = ar;
    }
}

// ---- CSR build (dst is layer-invariant: built ONCE)
__global__ void __launch_bounds__(256) k_hist(const int* __restrict__ dst, int* __restrict__ deg) {
    int e = blockIdx.x * 256 + threadIdx.x;
    if (e < kNE) atomicAdd(&deg[dst[e]], 1);
}

__global__ void __launch_bounds__(256) k_scan1(const int* __restrict__ deg,
                                               int* __restrict__ excl, int* __restrict__ bsum) {
    __shared__ int s[256];
    int t = threadIdx.x;
    int i = blockIdx.x * 256 + t;
    int v = (i < kNodes) ? deg[i] : 0;
    s[t] = v;
    __syncthreads();
    for (int o = 1; o < 256; o <<= 1) {
        int tv = (t >= o) ? s[t - o] : 0;
        __syncthreads();
        s[t] += tv;
        __syncthreads();
    }
    if (i < kNodes) excl[i] = s[t] - v;
    if (t == 255) bsum[blockIdx.x] = s[255];
}

__global__ void __launch_bounds__(256) k_scan2(int* __restrict__ bsum, int nb) {
    __shared__ int s[256];
    int t = threadIdx.x;
    int v = (t < nb) ? bsum[t] : 0;
    s[t] = v;
    __syncthreads();
    for (int o = 1; o < 256; o <<= 1) {
        int tv = (t >= o) ? s[t - o] : 0;
        __syncthreads();
        s[t] += tv;
        __syncthreads();
    }
    if (t < nb) bsum[t] = s[t];
}

__global__ void __launch_bounds__(256) k_scan3(int* __restrict__ excl, const int* __restrict__ bsum) {
    int i = blockIdx.x * 256 + threadIdx.x;
    if (i >= kNodes) return;
    if (blockIdx.x > 0) excl[i] += bsum[blockIdx.x - 1];
}

// ---- packed scatter: one 8B write per edge (was 2x 4B into separate arrays
// -> 2 random line-touches; now 1). WRITE_SIZE should ~halve.
__global__ void __launch_bounds__(256) k_reorder(
    const int* __restrict__ src, const int* __restrict__ dst, const float* __restrict__ ea,
    const int* __restrict__ rowptr, int* __restrict__ cur,
    int2* __restrict__ epack) {
    int e = blockIdx.x * 256 + threadIdx.x;
    if (e >= kNE) return;
    int d = dst[e];
    int pos = rowptr[d] + atomicAdd(&cur[d], 1);
    epack[pos] = make_int2(src[e], __float_as_int(ea[e]));
}

// ---- K3: fused edge phase, 2 features/lane, 1 wave/node, 4 nodes/block.
// d wave-uniform -> epack loads on the SCALAR pipe (s_load_dwordx2/x16 bursts).
// Logit reduce via DPP (pure VALU). DS-pipe ops per edge: 0.
__global__ void __launch_bounds__(256) k_edge(
    const int* __restrict__ rowptr, const int* __restrict__ deg,
    const int2* __restrict__ epack,
    const __half* __restrict__ xl, float* __restrict__ xrg,
    const float* __restrict__ We, const float* __restrict__ att,
    const float* __restrict__ gat_b, float* __restrict__ ps, float* __restrict__ pq) {
    int t = threadIdx.x & 63;             // lane
    int w = __builtin_amdgcn_readfirstlane(threadIdx.x >> 6);   // wave 0..3 (uniform)
    int d = blockIdx.x * 4 + w;           // node (50000 = 12500 * 4 exact)
    const __half2* xl2 = (const __half2*)xl;
    long rowb = (long)d * 64;             // row offset in half2/float2 units

    float2 xrv = ((const float2*)xrg)[rowb + t];
    float2 Wev = ((const float2*)We)[t];
    float2 av  = ((const float2*)att)[t];
    av.x *= kL2E; av.y *= kL2E;           // fold ln2 into att -> single v_exp

    float2 xself = __half22float2(xl2[rowb + t]);

    // self loop (ea = 0)
    float z0 = xself.x + xrv.x, z1 = xself.y + xrv.y;
    z0 = fmaxf(z0, kSlope * z0); z1 = fmaxf(z1, kSlope * z1);
    float p = red16(z0 * av.x + z1 * av.y);
    float ee = __builtin_amdgcn_exp2f(p - kShift2);
    float l = ee, o0 = ee * xself.x, o1 = ee * xself.y;

    int base = rowptr[d], cnt = deg[d];   // uniform -> SGPR
    int e = 0;
    for (; e + 8 <= cnt; e += 8) {
        int se[8]; float ev[8];
        #pragma unroll
        for (int u = 0; u < 8; ++u) {
            int2 ep = epack[base + e + u];
            se[u] = ep.x; ev[u] = __int_as_float(ep.y);
        }
        float2 xv[8]; float pv[8];
        #pragma unroll
        for (int u = 0; u < 8; ++u)
            xv[u] = __half22float2(xl2[(long)se[u] * 64 + t]);
        #pragma unroll
        for (int u = 0; u < 8; ++u) {
            float zz0 = fmaf(ev[u], Wev.x, xrv.x) + xv[u].x;
            float zz1 = fmaf(ev[u], Wev.y, xrv.y) + xv[u].y;
            zz0 = fmaxf(zz0, kSlope * zz0);
            zz1 = fmaxf(zz1, kSlope * zz1);
            pv[u] = red16(zz0 * av.x + zz1 * av.y);
        }
        #pragma unroll
        for (int u = 0; u < 8; ++u) {
            float eeu = __builtin_amdgcn_exp2f(pv[u] - kShift2);
            l += eeu;
            o0 = fmaf(eeu, xv[u].x, o0);
            o1 = fmaf(eeu, xv[u].y, o1);
        }
    }
    for (; e < cnt; ++e) {
        int2 ep = epack[base + e];
        int s = ep.x;
        float eav = __int_as_float(ep.y);
        float2 xv = __half22float2(xl2[(long)s * 64 + t]);
        float zz0 = fmaf(eav, Wev.x, xrv.x) + xv.x;
        float zz1 = fmaf(eav, Wev.y, xrv.y) + xv.y;
        zz0 = fmaxf(zz0, kSlope * zz0);
        zz1 = fmaxf(zz1, kSlope * zz1);
        float pe = red16(zz0 * av.x + zz1 * av.y);
        float eeu = __builtin_amdgcn_exp2f(pe - kShift2);
        l += eeu;
        o0 = fmaf(eeu, xv.x, o0);
        o1 = fmaf(eeu, xv.y, o1);
    }
    float rl = __builtin_amdgcn_rcpf(l);
    float v0 = o0 * rl, v1 = o1 * rl;
    ((float2*)xrg)[rowb + t] = make_float2(v0, v1);   // g overwrites xr (row-private)
    float2 gb = ((const float2*)gat_b)[t];
    float vb0 = v0 + gb.x, vb1 = v1 + gb.y;
    float s = vb0 + vb1, q = vb0 * vb0 + vb1 * vb1;
    #pragma unroll
    for (int mm = 1; mm < 64; mm <<= 1) { s += __shfl_xor(s, mm); q += __shfl_xor(q, mm); }
    if (t == 0) { ps[d] = s; pq[d] = q; }
}

// ---- K4: reduce per-node partials -> stats[2].
__global__ void __launch_bounds__(1024) k_statsr(
    const float* __restrict__ ps, const float* __restrict__ pq, float* __restrict__ stats) {
    __shared__ float rs[1024], rq[1024];
    int t = threadIdx.x;
    float s = 0.f, q = 0.f;
    for (int i = t; i < kNodes; i += 1024) { s += ps[i]; q += pq[i]; }
    rs[t] = s; rq[t] = q;
    __syncthreads();
    for (int o = 512; o > 0; o >>= 1) {
        if (t < o) { rs[t] += rs[t + o]; rq[t] += rq[t + o]; }
        __syncthreads();
    }
    if (t == 0) { stats[0] = rs[0]; stats[1] = rq[0]; }
}

// ---- K5: h = relu(node_ln(relu(graph_ln(g+gat_b)) @ lin_w + lin_b)); jk_out = max(jk_in, h)
// lin_w staged TRANSPOSED pad-130 -> float4(vb, broadcast) + 2x float2(w) per 4 FMA.
__global__ void __launch_bounds__(256) k_post(
    const float* __restrict__ g, const float* __restrict__ gat_b,
    const float* __restrict__ ln1w, const float* __restrict__ ln1b,
    const float* __restrict__ linw, const float* __restrict__ linb,
    const float* __restrict__ ln2w, const float* __restrict__ ln2b,
    const float* __restrict__ stats, const float* __restrict__ jk_in,
    float* __restrict__ h, float* __restrict__ jk_out) {
    __shared__ float s_lwT[kC * kLWP];    // 16.6 KB, lin_w transposed
    __shared__ float s_vb[8 * kHC];       // 4 KB
    int t = threadIdx.x;
    int n0 = blockIdx.x * 8;
    const float inv = 1.f / ((float)kNodes * kHC);
    float mean = stats[0] * inv;
    float var  = stats[1] * inv - mean * mean;
    float rstd = rsqrtf(var + kEps);
    for (int i = t; i < kHC * kC; i += 256) {
        int k = i >> 5, c = i & 31;
        s_lwT[c * kLWP + k] = linw[i];
    }
    for (int i = t; i < 8 * kHC; i += 256) {
        int node = n0 + (i >> 7), f = i & 127;
        float a = (g[(long)node * kHC + f] + gat_b[f] - mean) * rstd * ln1w[f] + ln1b[f];
        s_vb[i] = fmaxf(a, 0.f);
    }
    __syncthreads();
    int n = t >> 5, c = t & 31;
    int node = n0 + n;
    float acc = linb[c];
    const float* vb = s_vb + n * kHC;
    const float* wr = s_lwT + c * kLWP;
    #pragma unroll 8
    for (int k = 0; k < kHC; k += 4) {
        float4 v4 = *(const float4*)(vb + k);
        float2 w0 = *(const float2*)(wr + k);
        float2 w1 = *(const float2*)(wr + k + 2);
        acc += v4.x * w0.x + v4.y * w0.y + v4.z * w1.x + v4.w * w1.y;
    }
    float m = acc;
    #pragma unroll
    for (int mm = 1; mm < 32; mm <<= 1) m += __shfl_xor(m, mm);
    m *= (1.f / kC);
    float dd = acc - m;
    float q = dd * dd;
    #pragma unroll
    for (int mm = 1; mm < 32; mm <<= 1) q += __shfl_xor(q, mm);
    q *= (1.f / kC);
    float out = dd * rsqrtf(q + kEps) * ln2w[c] + ln2b[c];
    out = fmaxf(out, 0.f);
    h[node * kC + c] = out;
    jk_out[node * kC + c] = fmaxf(jk_in[node * kC + c], out);
}

extern "C" void kernel_launch(void* const* d_in, const int* in_sizes, int n_in,
                              void* d_out, int out_size, void* d_ws, size_t ws_size,
                              hipStream_t stream) {
    (void)in_sizes; (void)n_in; (void)out_size; (void)ws_size;
    const float* x     = (const float*)d_in[0];
    const int*   ei    = (const int*)d_in[1];
    const int*   src   = ei;
    const int*   dst   = ei + kNE;
    const float* ea    = (const float*)d_in[2];
    const float* W_emb = (const float*)d_in[3];
    const float* b_emb = (const float*)d_in[4];
    const float* ln0w  = (const float*)d_in[5];
    const float* ln0b  = (const float*)d_in[6];
    const float* Wl    = (const float*)d_in[7];
    const float* bl    = (const float*)d_in[8];
    const float* Wr    = (const float*)d_in[9];
    const float* br    = (const float*)d_in[10];
    const float* We    = (const float*)d_in[11];
    const float* att   = (const float*)d_in[12];
    const float* gat_b = (const float*)d_in[13];
    const float* ln1w  = (const float*)d_in[14];
    const float* ln1b  = (const float*)d_in[15];
    const float* linw  = (const float*)d_in[16];
    const float* linb  = (const float*)d_in[17];
    const float* ln2w  = (const float*)d_in[18];
    const float* ln2b  = (const float*)d_in[19];

    char* wsb = (char*)d_ws;
    float*  h      = (float*)(wsb);                 // 6.4e6 B
    float*  jk     = (float*)(wsb +  6400000);      // 6.4e6 B
    float*  xrg    = (float*)(wsb + 12800000);      // 25.6e6 B (xr, later g)
    __half* xl     = (__half*)(wsb + 38400000);     // 12.8e6 B
    int2*   epack  = (int2*)(wsb + 51200000);       // 6.4e6 B (packed src+ea per edge)
    int*    deg    = (int*)(wsb + 57600000);        // 0.2e6 B
    int*    cur    = (int*)(wsb + 57800000);        // 0.2e6 B
    int*    rowptr = (int*)(wsb + 58000000);        // 0.2e6 B
    int*    bsum   = (int*)(wsb + 58200000);        // 1 KB
    float*  stats  = (float*)(wsb + 58201024);      // 8 B
    float*  ps     = (float*)(wsb + 58300000);      // 0.2e6 B
    float*  pq     = (float*)(wsb + 58500000);      // 0.2e6 B

    const int scanBlocks  = (kNodes + 255) / 256;        // 196
    const int embedBlocks = kNodes / kTN;                // 3125 exact
    const int transBlocks = (kNodes + 31) / 32;          // 1563
    const int eBlocks     = (kNE + 255) / 256;
    const int edgeBlocks  = kNodes / 4;                  // 12500 exact, 4 nodes/block
    const int postBlocks  = kNodes / 8;                  // 6250 exact

    hipLaunchKernelGGL(k_embed, dim3(embedBlocks), dim3(256), 0, stream,
                       x, W_emb, b_emb, ln0w, ln0b, h, jk);
    // CSR build (once; dst is layer-invariant)
    hipLaunchKernelGGL(k_fill0, dim3((2 * kNodes + 255) / 256), dim3(256), 0, stream,
                       (unsigned*)deg, 2 * kNodes);      // deg + cur
    hipLaunchKernelGGL(k_hist, dim3(eBlocks), dim3(256), 0, stream, dst, deg);
    hipLaunchKernelGGL(k_scan1, dim3(scanBlocks), dim3(256), 0, stream, deg, rowptr, bsum);
    hipLaunchKernelGGL(k_scan2, dim3(1), dim3(256), 0, stream, bsum, scanBlocks);
    hipLaunchKernelGGL(k_scan3, dim3(scanBlocks), dim3(256), 0, stream, rowptr, bsum);
    hipLaunchKernelGGL(k_reorder, dim3(eBlocks), dim3(256), 0, stream,
                       src, dst, ea, rowptr, cur, epack);
    for (int l = 0; l < 2; ++l) {
        hipLaunchKernelGGL(k_trans, dim3(transBlocks), dim3(256), 0, stream,
                           h, Wl + l * kC * kHC, bl + l * kHC,
                           Wr + l * kC * kHC, br + l * kHC, xl, xrg);
        hipLaunchKernelGGL(k_edge, dim3(edgeBlocks), dim3(256), 0, stream,
                           rowptr, deg, epack, xl, xrg,
                           We + l * kHC, att + l * kH * kC, gat_b + l * kHC, ps, pq);
        hipLaunchKernelGGL(k_statsr, dim3(1), dim3(1024), 0, stream, ps, pq, stats);
        hipLaunchKernelGGL(k_post, dim3(postBlocks), dim3(256), 0, stream,
                           xrg, gat_b + l * kHC, ln1w + l * kHC, ln1b + l * kHC,
                           linw + l * kHC * kC, linb + l * kC,
                           ln2w + l * kC, ln2b + l * kC, stats, jk,
                           h, (l == 1) ? (float*)d_out : jk);
    }
}

// Round 5
// 463.860 us; speedup vs baseline: 1.2155x; 1.0394x over previous
//
#include <hip/hip_runtime.h>
#include <hip/hip_fp16.h>

constexpr int kNodes = 50000;
constexpr int kNE    = 800000;            // edges before self loops
constexpr int kFin   = 256;
constexpr int kC     = 32;
constexpr int kH     = 4;
constexpr int kHC    = 128;               // kH * kC
constexpr int kTN    = 16;                // nodes per k_embed block
constexpr int kWP    = 258;               // padded sWt row (2-way LDS alias = free)
constexpr int kLWP   = 130;               // padded s_lwT row in k_post (float2-aligned, 2-way alias)
constexpr int kEmbedBlocks = kNodes / kTN;        // 3125
constexpr int kHistBlocks  = (kNE + 255) / 256;   // 3125
constexpr int kTransBlocks = (kNodes + 31) / 32;  // 1563
constexpr float kEps   = 1e-5f;
constexpr float kSlope = 0.2f;
constexpr float kL2E   = 1.44269504f;     // log2(e): fold into att so exp is 1 instr
constexpr float kShift2 = 8.0f * 1.44269504f; // softmax-invariant shift (exp2 domain)

// ---- DPP butterfly add: v += partner(v), pure VALU (no DS pipe).
template<int CTRL>
__device__ __forceinline__ float dpp_add(float v) {
    int x = __builtin_amdgcn_update_dpp(0, __float_as_int(v), CTRL, 0xF, 0xF, true);
    return v + __int_as_float(x);
}
// 16-lane sum: xor1, xor2, row_half_mirror, row_mirror.
__device__ __forceinline__ float red16(float p) {
    p = dpp_add<0xB1>(p);
    p = dpp_add<0x4E>(p);
    p = dpp_add<0x141>(p);
    p = dpp_add<0x140>(p);
    return p;
}

// ---- zero-fill
__global__ void __launch_bounds__(256) k_fill0(unsigned* __restrict__ p, int n) {
    int i = blockIdx.x * 256 + threadIdx.x;
    if (i < n) p[i] = 0u;
}

// ---- K_A: role-split fused kernel.
// blocks [0, kEmbedBlocks): h0 = relu(node_ln(x @ W_emb + b_emb)); jk = h0.
// blocks [kEmbedBlocks, +kHistBlocks): degree histogram (atomic-latency-bound,
// hides under embed's DS-bound compute).
__global__ void __launch_bounds__(256) k_embed_hist(
    const float* __restrict__ x, const float* __restrict__ W, const float* __restrict__ b,
    const float* __restrict__ lnw, const float* __restrict__ lnb,
    float* __restrict__ h, float* __restrict__ jk,
    const int* __restrict__ dst, int* __restrict__ deg) {
    __shared__ float sx[kTN * kFin];      // 16 KB
    __shared__ float sWt[kC * kWP];       // 33 KB
    int t = threadIdx.x;
    if (blockIdx.x >= kEmbedBlocks) {     // ---- hist role
        int e = (blockIdx.x - kEmbedBlocks) * 256 + t;
        if (e < kNE) atomicAdd(&deg[dst[e]], 1);
        return;
    }
    // ---- embed role
    int n0 = blockIdx.x * kTN;            // 50000 = 3125 * 16 exact
    for (int i = t; i < kFin * kC; i += 256) {
        int k = i >> 5, c = i & 31;
        sWt[c * kWP + k] = W[i];
    }
    const float* xg = x + (long)n0 * kFin;
    for (int i = t; i < kTN * kFin; i += 256) sx[i] = xg[i];
    __syncthreads();
    int c = t & 31, n2 = t >> 5;          // n2 = 0..7
    const float* xa = sx + n2 * kFin;
    const float* xb = sx + (n2 + 8) * kFin;
    const float* wrow = sWt + c * kWP;
    float acc0 = 0.f, acc1 = 0.f;
    #pragma unroll 8
    for (int k = 0; k < kFin; k += 4) {
        float4 x0 = *(const float4*)(xa + k);
        float4 x1 = *(const float4*)(xb + k);
        float2 w0 = *(const float2*)(wrow + k);
        float2 w1 = *(const float2*)(wrow + k + 2);
        acc0 += x0.x * w0.x + x0.y * w0.y + x0.z * w1.x + x0.w * w1.y;
        acc1 += x1.x * w0.x + x1.y * w0.y + x1.z * w1.x + x1.w * w1.y;
    }
    float bc = b[c], lw = lnw[c], lb = lnb[c];
    {
        float y = acc0 + bc;
        float m = y;
        #pragma unroll
        for (int o = 1; o < 32; o <<= 1) m += __shfl_xor(m, o);
        m *= (1.f / kC);
        float xc = y - m, v = xc * xc;
        #pragma unroll
        for (int o = 1; o < 32; o <<= 1) v += __shfl_xor(v, o);
        v *= (1.f / kC);
        float out = fmaxf(xc * rsqrtf(v + kEps) * lw + lb, 0.f);
        int node = n0 + n2;
        h[node * kC + c] = out;
        jk[node * kC + c] = out;
    }
    {
        float y = acc1 + bc;
        float m = y;
        #pragma unroll
        for (int o = 1; o < 32; o <<= 1) m += __shfl_xor(m, o);
        m *= (1.f / kC);
        float xc = y - m, v = xc * xc;
        #pragma unroll
        for (int o = 1; o < 32; o <<= 1) v += __shfl_xor(v, o);
        v *= (1.f / kC);
        float out = fmaxf(xc * rsqrtf(v + kEps) * lw + lb, 0.f);
        int node = n0 + n2 + 8;
        h[node * kC + c] = out;
        jk[node * kC + c] = out;
    }
}

// ---- trans body: xl = h@Wl + bl (fp16) ; xr = h@Wr + br (fp32). bid = node-tile idx.
__device__ __forceinline__ void trans_body(
    int bid, float* s_h, const float* __restrict__ h,
    const float* __restrict__ Wl, const float* __restrict__ bl,
    const float* __restrict__ Wr, const float* __restrict__ br,
    __half* __restrict__ xl, float* __restrict__ xr) {
    int t = threadIdx.x;
    int j = t & 127, hf = t >> 7;
    float wl[kC], wr[kC];
    #pragma unroll
    for (int k = 0; k < kC; ++k) { wl[k] = Wl[k * kHC + j]; wr[k] = Wr[k * kHC + j]; }
    float blj = bl[j], brj = br[j];
    int n0 = bid * 32;
    int nn = min(32, kNodes - n0);
    for (int i = t; i < nn * kC; i += 256) s_h[i] = h[n0 * kC + i];
    __syncthreads();
    int nend = min(nn, hf * 16 + 16);
    for (int n = hf * 16; n < nend; ++n) {
        const float4* h4 = (const float4*)(s_h + n * kC);
        float al = blj, ar = brj;
        #pragma unroll
        for (int kq = 0; kq < 8; ++kq) {
            float4 hv = h4[kq];
            al += hv.x * wl[kq*4] + hv.y * wl[kq*4+1] + hv.z * wl[kq*4+2] + hv.w * wl[kq*4+3];
            ar += hv.x * wr[kq*4] + hv.y * wr[kq*4+1] + hv.z * wr[kq*4+2] + hv.w * wr[kq*4+3];
        }
        long g = (long)(n0 + n) * kHC + j;
        xl[g] = __float2half(al);
        xr[g] = ar;
    }
}

// ---- K2 (standalone, layer 1): k_trans
__global__ void __launch_bounds__(256) k_trans(
    const float* __restrict__ h,
    const float* __restrict__ Wl, const float* __restrict__ bl,
    const float* __restrict__ Wr, const float* __restrict__ br,
    __half* __restrict__ xl, float* __restrict__ xr) {
    __shared__ float s_h[32 * kC];
    trans_body(blockIdx.x, s_h, h, Wl, bl, Wr, br, xl, xr);
}

// ---- K_B: role-split fused kernel (layer 0 only).
// blocks [0, kHistBlocks): reorder (packed 8B scatter; atomic-latency-bound).
// blocks [kHistBlocks, +kTransBlocks): trans layer 0 (needs only h).
__global__ void __launch_bounds__(256) k_trans_reorder(
    const float* __restrict__ h,
    const float* __restrict__ Wl, const float* __restrict__ bl,
    const float* __restrict__ Wr, const float* __restrict__ br,
    __half* __restrict__ xl, float* __restrict__ xr,
    const int* __restrict__ src, const int* __restrict__ dst, const float* __restrict__ ea,
    const int* __restrict__ rowptr, int* __restrict__ cur, int2* __restrict__ epack) {
    __shared__ float s_h[32 * kC];
    if (blockIdx.x < kHistBlocks) {       // ---- reorder role (starts first)
        int e = blockIdx.x * 256 + threadIdx.x;
        if (e < kNE) {
            int d = dst[e];
            int pos = rowptr[d] + atomicAdd(&cur[d], 1);
            epack[pos] = make_int2(src[e], __float_as_int(ea[e]));
        }
        return;
    }
    trans_body(blockIdx.x - kHistBlocks, s_h, h, Wl, bl, Wr, br, xl, xr);
}

// ---- CSR scans (dst is layer-invariant: built ONCE)
__global__ void __launch_bounds__(256) k_scan1(const int* __restrict__ deg,
                                               int* __restrict__ excl, int* __restrict__ bsum) {
    __shared__ int s[256];
    int t = threadIdx.x;
    int i = blockIdx.x * 256 + t;
    int v = (i < kNodes) ? deg[i] : 0;
    s[t] = v;
    __syncthreads();
    for (int o = 1; o < 256; o <<= 1) {
        int tv = (t >= o) ? s[t - o] : 0;
        __syncthreads();
        s[t] += tv;
        __syncthreads();
    }
    if (i < kNodes) excl[i] = s[t] - v;
    if (t == 255) bsum[blockIdx.x] = s[255];
}

__global__ void __launch_bounds__(256) k_scan2(int* __restrict__ bsum, int nb) {
    __shared__ int s[256];
    int t = threadIdx.x;
    int v = (t < nb) ? bsum[t] : 0;
    s[t] = v;
    __syncthreads();
    for (int o = 1; o < 256; o <<= 1) {
        int tv = (t >= o) ? s[t - o] : 0;
        __syncthreads();
        s[t] += tv;
        __syncthreads();
    }
    if (t < nb) bsum[t] = s[t];
}

__global__ void __launch_bounds__(256) k_scan3(int* __restrict__ excl, const int* __restrict__ bsum) {
    int i = blockIdx.x * 256 + threadIdx.x;
    if (i >= kNodes) return;
    if (blockIdx.x > 0) excl[i] += bsum[blockIdx.x - 1];
}

// ---- K3: fused edge phase, 2 features/lane, 1 wave/node, 4 nodes/block.
// d wave-uniform -> epack loads on the SCALAR pipe. DPP reduce. 0 DS ops/edge.
__global__ void __launch_bounds__(256) k_edge(
    const int* __restrict__ rowptr, const int* __restrict__ deg,
    const int2* __restrict__ epack,
    const __half* __restrict__ xl, float* __restrict__ xrg,
    const float* __restrict__ We, const float* __restrict__ att,
    const float* __restrict__ gat_b, float* __restrict__ ps, float* __restrict__ pq) {
    int t = threadIdx.x & 63;             // lane
    int w = __builtin_amdgcn_readfirstlane(threadIdx.x >> 6);   // wave 0..3 (uniform)
    int d = blockIdx.x * 4 + w;           // node (50000 = 12500 * 4 exact)
    const __half2* xl2 = (const __half2*)xl;
    long rowb = (long)d * 64;             // row offset in half2/float2 units

    float2 xrv = ((const float2*)xrg)[rowb + t];
    float2 Wev = ((const float2*)We)[t];
    float2 av  = ((const float2*)att)[t];
    av.x *= kL2E; av.y *= kL2E;           // fold ln2 into att -> single v_exp

    float2 xself = __half22float2(xl2[rowb + t]);

    // self loop (ea = 0)
    float z0 = xself.x + xrv.x, z1 = xself.y + xrv.y;
    z0 = fmaxf(z0, kSlope * z0); z1 = fmaxf(z1, kSlope * z1);
    float p = red16(z0 * av.x + z1 * av.y);
    float ee = __builtin_amdgcn_exp2f(p - kShift2);
    float l = ee, o0 = ee * xself.x, o1 = ee * xself.y;

    int base = rowptr[d], cnt = deg[d];   // uniform -> SGPR
    int e = 0;
    for (; e + 8 <= cnt; e += 8) {
        int se[8]; float ev[8];
        #pragma unroll
        for (int u = 0; u < 8; ++u) {
            int2 ep = epack[base + e + u];
            se[u] = ep.x; ev[u] = __int_as_float(ep.y);
        }
        float2 xv[8]; float pv[8];
        #pragma unroll
        for (int u = 0; u < 8; ++u)
            xv[u] = __half22float2(xl2[(long)se[u] * 64 + t]);
        #pragma unroll
        for (int u = 0; u < 8; ++u) {
            float zz0 = fmaf(ev[u], Wev.x, xrv.x) + xv[u].x;
            float zz1 = fmaf(ev[u], Wev.y, xrv.y) + xv[u].y;
            zz0 = fmaxf(zz0, kSlope * zz0);
            zz1 = fmaxf(zz1, kSlope * zz1);
            pv[u] = red16(zz0 * av.x + zz1 * av.y);
        }
        #pragma unroll
        for (int u = 0; u < 8; ++u) {
            float eeu = __builtin_amdgcn_exp2f(pv[u] - kShift2);
            l += eeu;
            o0 = fmaf(eeu, xv[u].x, o0);
            o1 = fmaf(eeu, xv[u].y, o1);
        }
    }
    for (; e < cnt; ++e) {
        int2 ep = epack[base + e];
        int s = ep.x;
        float eav = __int_as_float(ep.y);
        float2 xv = __half22float2(xl2[(long)s * 64 + t]);
        float zz0 = fmaf(eav, Wev.x, xrv.x) + xv.x;
        float zz1 = fmaf(eav, Wev.y, xrv.y) + xv.y;
        zz0 = fmaxf(zz0, kSlope * zz0);
        zz1 = fmaxf(zz1, kSlope * zz1);
        float pe = red16(zz0 * av.x + zz1 * av.y);
        float eeu = __builtin_amdgcn_exp2f(pe - kShift2);
        l += eeu;
        o0 = fmaf(eeu, xv.x, o0);
        o1 = fmaf(eeu, xv.y, o1);
    }
    float rl = __builtin_amdgcn_rcpf(l);
    float v0 = o0 * rl, v1 = o1 * rl;
    ((float2*)xrg)[rowb + t] = make_float2(v0, v1);   // g overwrites xr (row-private)
    float2 gb = ((const float2*)gat_b)[t];
    float vb0 = v0 + gb.x, vb1 = v1 + gb.y;
    float s = vb0 + vb1, q = vb0 * vb0 + vb1 * vb1;
    #pragma unroll
    for (int mm = 1; mm < 64; mm <<= 1) { s += __shfl_xor(s, mm); q += __shfl_xor(q, mm); }
    if (t == 0) { ps[d] = s; pq[d] = q; }
}

// ---- K4: reduce per-node partials -> stats[2].
__global__ void __launch_bounds__(1024) k_statsr(
    const float* __restrict__ ps, const float* __restrict__ pq, float* __restrict__ stats) {
    __shared__ float rs[1024], rq[1024];
    int t = threadIdx.x;
    float s = 0.f, q = 0.f;
    for (int i = t; i < kNodes; i += 1024) { s += ps[i]; q += pq[i]; }
    rs[t] = s; rq[t] = q;
    __syncthreads();
    for (int o = 512; o > 0; o >>= 1) {
        if (t < o) { rs[t] += rs[t + o]; rq[t] += rq[t + o]; }
        __syncthreads();
    }
    if (t == 0) { stats[0] = rs[0]; stats[1] = rq[0]; }
}

// ---- K5: h = relu(node_ln(relu(graph_ln(g+gat_b)) @ lin_w + lin_b)); jk_out = max(jk_in, h)
__global__ void __launch_bounds__(256) k_post(
    const float* __restrict__ g, const float* __restrict__ gat_b,
    const float* __restrict__ ln1w, const float* __restrict__ ln1b,
    const float* __restrict__ linw, const float* __restrict__ linb,
    const float* __restrict__ ln2w, const float* __restrict__ ln2b,
    const float* __restrict__ stats, const float* __restrict__ jk_in,
    float* __restrict__ h, float* __restrict__ jk_out) {
    __shared__ float s_lwT[kC * kLWP];    // 16.6 KB, lin_w transposed
    __shared__ float s_vb[8 * kHC];       // 4 KB
    int t = threadIdx.x;
    int n0 = blockIdx.x * 8;
    const float inv = 1.f / ((float)kNodes * kHC);
    float mean = stats[0] * inv;
    float var  = stats[1] * inv - mean * mean;
    float rstd = rsqrtf(var + kEps);
    for (int i = t; i < kHC * kC; i += 256) {
        int k = i >> 5, c = i & 31;
        s_lwT[c * kLWP + k] = linw[i];
    }
    for (int i = t; i < 8 * kHC; i += 256) {
        int node = n0 + (i >> 7), f = i & 127;
        float a = (g[(long)node * kHC + f] + gat_b[f] - mean) * rstd * ln1w[f] + ln1b[f];
        s_vb[i] = fmaxf(a, 0.f);
    }
    __syncthreads();
    int n = t >> 5, c = t & 31;
    int node = n0 + n;
    float acc = linb[c];
    const float* vb = s_vb + n * kHC;
    const float* wr = s_lwT + c * kLWP;
    #pragma unroll 8
    for (int k = 0; k < kHC; k += 4) {
        float4 v4 = *(const float4*)(vb + k);
        float2 w0 = *(const float2*)(wr + k);
        float2 w1 = *(const float2*)(wr + k + 2);
        acc += v4.x * w0.x + v4.y * w0.y + v4.z * w1.x + v4.w * w1.y;
    }
    float m = acc;
    #pragma unroll
    for (int mm = 1; mm < 32; mm <<= 1) m += __shfl_xor(m, mm);
    m *= (1.f / kC);
    float dd = acc - m;
    float q = dd * dd;
    #pragma unroll
    for (int mm = 1; mm < 32; mm <<= 1) q += __shfl_xor(q, mm);
    q *= (1.f / kC);
    float out = dd * rsqrtf(q + kEps) * ln2w[c] + ln2b[c];
    out = fmaxf(out, 0.f);
    h[node * kC + c] = out;
    jk_out[node * kC + c] = fmaxf(jk_in[node * kC + c], out);
}

extern "C" void kernel_launch(void* const* d_in, const int* in_sizes, int n_in,
                              void* d_out, int out_size, void* d_ws, size_t ws_size,
                              hipStream_t stream) {
    (void)in_sizes; (void)n_in; (void)out_size; (void)ws_size;
    const float* x     = (const float*)d_in[0];
    const int*   ei    = (const int*)d_in[1];
    const int*   src   = ei;
    const int*   dst   = ei + kNE;
    const float* ea    = (const float*)d_in[2];
    const float* W_emb = (const float*)d_in[3];
    const float* b_emb = (const float*)d_in[4];
    const float* ln0w  = (const float*)d_in[5];
    const float* ln0b  = (const float*)d_in[6];
    const float* Wl    = (const float*)d_in[7];
    const float* bl    = (const float*)d_in[8];
    const float* Wr    = (const float*)d_in[9];
    const float* br    = (const float*)d_in[10];
    const float* We    = (const float*)d_in[11];
    const float* att   = (const float*)d_in[12];
    const float* gat_b = (const float*)d_in[13];
    const float* ln1w  = (const float*)d_in[14];
    const float* ln1b  = (const float*)d_in[15];
    const float* linw  = (const float*)d_in[16];
    const float* linb  = (const float*)d_in[17];
    const float* ln2w  = (const float*)d_in[18];
    const float* ln2b  = (const float*)d_in[19];

    char* wsb = (char*)d_ws;
    float*  h      = (float*)(wsb);                 // 6.4e6 B
    float*  jk     = (float*)(wsb +  6400000);      // 6.4e6 B
    float*  xrg    = (float*)(wsb + 12800000);      // 25.6e6 B (xr, later g)
    __half* xl     = (__half*)(wsb + 38400000);     // 12.8e6 B
    int2*   epack  = (int2*)(wsb + 51200000);       // 6.4e6 B (packed src+ea per edge)
    int*    deg    = (int*)(wsb + 57600000);        // 0.2e6 B
    int*    cur    = (int*)(wsb + 57800000);        // 0.2e6 B
    int*    rowptr = (int*)(wsb + 58000000);        // 0.2e6 B
    int*    bsum   = (int*)(wsb + 58200000);        // 1 KB
    float*  stats  = (float*)(wsb + 58201024);      // 8 B
    float*  ps     = (float*)(wsb + 58300000);      // 0.2e6 B
    float*  pq     = (float*)(wsb + 58500000);      // 0.2e6 B

    const int scanBlocks = (kNodes + 255) / 256;         // 196
    const int edgeBlocks = kNodes / 4;                   // 12500 exact, 4 nodes/block
    const int postBlocks = kNodes / 8;                   // 6250 exact

    // zero deg + cur, then fused embed ∥ hist
    hipLaunchKernelGGL(k_fill0, dim3((2 * kNodes + 255) / 256), dim3(256), 0, stream,
                       (unsigned*)deg, 2 * kNodes);
    hipLaunchKernelGGL(k_embed_hist, dim3(kEmbedBlocks + kHistBlocks), dim3(256), 0, stream,
                       x, W_emb, b_emb, ln0w, ln0b, h, jk, dst, deg);
    hipLaunchKernelGGL(k_scan1, dim3(scanBlocks), dim3(256), 0, stream, deg, rowptr, bsum);
    hipLaunchKernelGGL(k_scan2, dim3(1), dim3(256), 0, stream, bsum, scanBlocks);
    hipLaunchKernelGGL(k_scan3, dim3(scanBlocks), dim3(256), 0, stream, rowptr, bsum);
    // fused reorder ∥ trans(layer 0)
    hipLaunchKernelGGL(k_trans_reorder, dim3(kHistBlocks + kTransBlocks), dim3(256), 0, stream,
                       h, Wl, bl, Wr, br, xl, xrg,
                       src, dst, ea, rowptr, cur, epack);
    for (int l = 0; l < 2; ++l) {
        if (l == 1) {
            hipLaunchKernelGGL(k_trans, dim3(kTransBlocks), dim3(256), 0, stream,
                               h, Wl + l * kC * kHC, bl + l * kHC,
                               Wr + l * kC * kHC, br + l * kHC, xl, xrg);
        }
        hipLaunchKernelGGL(k_edge, dim3(edgeBlocks), dim3(256), 0, stream,
                           rowptr, deg, epack, xl, xrg,
                           We + l * kHC, att + l * kH * kC, gat_b + l * kHC, ps, pq);
        hipLaunchKernelGGL(k_statsr, dim3(1), dim3(1024), 0, stream, ps, pq, stats);
        hipLaunchKernelGGL(k_post, dim3(postBlocks), dim3(256), 0, stream,
                           xrg, gat_b + l * kHC, ln1w + l * kHC, ln1b + l * kHC,
                           linw + l * kHC * kC, linb + l * kC,
                           ln2w + l * kC, ln2b + l * kC, stats, jk,
                           h, (l == 1) ? (float*)d_out : jk);
    }
}

// Round 6
// 462.573 us; speedup vs baseline: 1.2189x; 1.0028x over previous
//
#include <hip/hip_runtime.h>
#include <hip/hip_fp16.h>

constexpr int kNodes = 50000;
constexpr int kNE    = 800000;            // edges before self loops
constexpr int kFin   = 256;
constexpr int kC     = 32;
constexpr int kH     = 4;
constexpr int kHC    = 128;               // kH * kC
constexpr int kTN    = 16;                // nodes per k_embed block
constexpr int kWP    = 258;               // padded sWt row (2-way LDS alias = free)
constexpr int kLWP   = 130;               // padded s_lwT row in k_post (float2-aligned, 2-way alias)
constexpr int kEmbedBlocks = kNodes / kTN;        // 3125
constexpr int kHistBlocks  = (kNE + 255) / 256;   // 3125
constexpr int kTransBlocks = (kNodes + 31) / 32;  // 1563
constexpr float kEps   = 1e-5f;
constexpr float kSlope = 0.2f;
constexpr float kL2E   = 1.44269504f;     // log2(e): fold into att so exp is 1 instr
constexpr float kShift2 = 8.0f * 1.44269504f; // softmax-invariant shift (exp2 domain)

// ---- DPP butterfly add: v += partner(v), pure VALU (no DS pipe).
template<int CTRL>
__device__ __forceinline__ float dpp_add(float v) {
    int x = __builtin_amdgcn_update_dpp(0, __float_as_int(v), CTRL, 0xF, 0xF, true);
    return v + __int_as_float(x);
}
// 8-lane sum (head = 8 lanes x 4 features): xor1, xor2, then row_half_mirror
// (xor7 == xor4 once quads are uniform).
__device__ __forceinline__ float red8(float p) {
    p = dpp_add<0xB1>(p);
    p = dpp_add<0x4E>(p);
    p = dpp_add<0x141>(p);
    return p;
}

// ---- zero-fill
__global__ void __launch_bounds__(256) k_fill0(unsigned* __restrict__ p, int n) {
    int i = blockIdx.x * 256 + threadIdx.x;
    if (i < n) p[i] = 0u;
}

// ---- K_A: role-split fused kernel.
// blocks [0, kEmbedBlocks): h0 = relu(node_ln(x @ W_emb + b_emb)); jk = h0.
// blocks [kEmbedBlocks, +kHistBlocks): degree histogram.
__global__ void __launch_bounds__(256) k_embed_hist(
    const float* __restrict__ x, const float* __restrict__ W, const float* __restrict__ b,
    const float* __restrict__ lnw, const float* __restrict__ lnb,
    float* __restrict__ h, float* __restrict__ jk,
    const int* __restrict__ dst, int* __restrict__ deg) {
    __shared__ float sx[kTN * kFin];      // 16 KB
    __shared__ float sWt[kC * kWP];       // 33 KB
    int t = threadIdx.x;
    if (blockIdx.x >= kEmbedBlocks) {     // ---- hist role
        int e = (blockIdx.x - kEmbedBlocks) * 256 + t;
        if (e < kNE) atomicAdd(&deg[dst[e]], 1);
        return;
    }
    // ---- embed role
    int n0 = blockIdx.x * kTN;            // 50000 = 3125 * 16 exact
    for (int i = t; i < kFin * kC; i += 256) {
        int k = i >> 5, c = i & 31;
        sWt[c * kWP + k] = W[i];
    }
    const float* xg = x + (long)n0 * kFin;
    for (int i = t; i < kTN * kFin; i += 256) sx[i] = xg[i];
    __syncthreads();
    int c = t & 31, n2 = t >> 5;          // n2 = 0..7
    const float* xa = sx + n2 * kFin;
    const float* xb = sx + (n2 + 8) * kFin;
    const float* wrow = sWt + c * kWP;
    float acc0 = 0.f, acc1 = 0.f;
    #pragma unroll 8
    for (int k = 0; k < kFin; k += 4) {
        float4 x0 = *(const float4*)(xa + k);
        float4 x1 = *(const float4*)(xb + k);
        float2 w0 = *(const float2*)(wrow + k);
        float2 w1 = *(const float2*)(wrow + k + 2);
        acc0 += x0.x * w0.x + x0.y * w0.y + x0.z * w1.x + x0.w * w1.y;
        acc1 += x1.x * w0.x + x1.y * w0.y + x1.z * w1.x + x1.w * w1.y;
    }
    float bc = b[c], lw = lnw[c], lb = lnb[c];
    {
        float y = acc0 + bc;
        float m = y;
        #pragma unroll
        for (int o = 1; o < 32; o <<= 1) m += __shfl_xor(m, o);
        m *= (1.f / kC);
        float xc = y - m, v = xc * xc;
        #pragma unroll
        for (int o = 1; o < 32; o <<= 1) v += __shfl_xor(v, o);
        v *= (1.f / kC);
        float out = fmaxf(xc * rsqrtf(v + kEps) * lw + lb, 0.f);
        int node = n0 + n2;
        h[node * kC + c] = out;
        jk[node * kC + c] = out;
    }
    {
        float y = acc1 + bc;
        float m = y;
        #pragma unroll
        for (int o = 1; o < 32; o <<= 1) m += __shfl_xor(m, o);
        m *= (1.f / kC);
        float xc = y - m, v = xc * xc;
        #pragma unroll
        for (int o = 1; o < 32; o <<= 1) v += __shfl_xor(v, o);
        v *= (1.f / kC);
        float out = fmaxf(xc * rsqrtf(v + kEps) * lw + lb, 0.f);
        int node = n0 + n2 + 8;
        h[node * kC + c] = out;
        jk[node * kC + c] = out;
    }
}

// ---- trans body: xl = h@Wl + bl (fp16) ; xr = h@Wr + br (fp32). bid = node-tile idx.
__device__ __forceinline__ void trans_body(
    int bid, float* s_h, const float* __restrict__ h,
    const float* __restrict__ Wl, const float* __restrict__ bl,
    const float* __restrict__ Wr, const float* __restrict__ br,
    __half* __restrict__ xl, float* __restrict__ xr) {
    int t = threadIdx.x;
    int j = t & 127, hf = t >> 7;
    float wl[kC], wr[kC];
    #pragma unroll
    for (int k = 0; k < kC; ++k) { wl[k] = Wl[k * kHC + j]; wr[k] = Wr[k * kHC + j]; }
    float blj = bl[j], brj = br[j];
    int n0 = bid * 32;
    int nn = min(32, kNodes - n0);
    for (int i = t; i < nn * kC; i += 256) s_h[i] = h[n0 * kC + i];
    __syncthreads();
    int nend = min(nn, hf * 16 + 16);
    for (int n = hf * 16; n < nend; ++n) {
        const float4* h4 = (const float4*)(s_h + n * kC);
        float al = blj, ar = brj;
        #pragma unroll
        for (int kq = 0; kq < 8; ++kq) {
            float4 hv = h4[kq];
            al += hv.x * wl[kq*4] + hv.y * wl[kq*4+1] + hv.z * wl[kq*4+2] + hv.w * wl[kq*4+3];
            ar += hv.x * wr[kq*4] + hv.y * wr[kq*4+1] + hv.z * wr[kq*4+2] + hv.w * wr[kq*4+3];
        }
        long g = (long)(n0 + n) * kHC + j;
        xl[g] = __float2half(al);
        xr[g] = ar;
    }
}

// ---- K2 (standalone, layer 1): k_trans
__global__ void __launch_bounds__(256) k_trans(
    const float* __restrict__ h,
    const float* __restrict__ Wl, const float* __restrict__ bl,
    const float* __restrict__ Wr, const float* __restrict__ br,
    __half* __restrict__ xl, float* __restrict__ xr) {
    __shared__ float s_h[32 * kC];
    trans_body(blockIdx.x, s_h, h, Wl, bl, Wr, br, xl, xr);
}

// ---- K_B: role-split fused kernel (layer 0 only).
// blocks [0, kHistBlocks): reorder (packed 8B scatter; atomic-latency-bound).
// blocks [kHistBlocks, +kTransBlocks): trans layer 0 (needs only h).
__global__ void __launch_bounds__(256) k_trans_reorder(
    const float* __restrict__ h,
    const float* __restrict__ Wl, const float* __restrict__ bl,
    const float* __restrict__ Wr, const float* __restrict__ br,
    __half* __restrict__ xl, float* __restrict__ xr,
    const int* __restrict__ src, const int* __restrict__ dst, const float* __restrict__ ea,
    const int* __restrict__ rowptr, int* __restrict__ cur, int2* __restrict__ epack) {
    __shared__ float s_h[32 * kC];
    if (blockIdx.x < kHistBlocks) {       // ---- reorder role (starts first)
        int e = blockIdx.x * 256 + threadIdx.x;
        if (e < kNE) {
            int d = dst[e];
            int pos = rowptr[d] + atomicAdd(&cur[d], 1);
            epack[pos] = make_int2(src[e], __float_as_int(ea[e]));
        }
        return;
    }
    trans_body(blockIdx.x - kHistBlocks, s_h, h, Wl, bl, Wr, br, xl, xr);
}

// ---- CSR scans (dst is layer-invariant: built ONCE)
__global__ void __launch_bounds__(256) k_scan1(const int* __restrict__ deg,
                                               int* __restrict__ excl, int* __restrict__ bsum) {
    __shared__ int s[256];
    int t = threadIdx.x;
    int i = blockIdx.x * 256 + t;
    int v = (i < kNodes) ? deg[i] : 0;
    s[t] = v;
    __syncthreads();
    for (int o = 1; o < 256; o <<= 1) {
        int tv = (t >= o) ? s[t - o] : 0;
        __syncthreads();
        s[t] += tv;
        __syncthreads();
    }
    if (i < kNodes) excl[i] = s[t] - v;
    if (t == 255) bsum[blockIdx.x] = s[255];
}

__global__ void __launch_bounds__(256) k_scan2(int* __restrict__ bsum, int nb) {
    __shared__ int s[256];
    int t = threadIdx.x;
    int v = (t < nb) ? bsum[t] : 0;
    s[t] = v;
    __syncthreads();
    for (int o = 1; o < 256; o <<= 1) {
        int tv = (t >= o) ? s[t - o] : 0;
        __syncthreads();
        s[t] += tv;
        __syncthreads();
    }
    if (t < nb) bsum[t] = s[t];
}

__global__ void __launch_bounds__(256) k_scan3(int* __restrict__ excl, const int* __restrict__ bsum) {
    int i = blockIdx.x * 256 + threadIdx.x;
    if (i >= kNodes) return;
    if (blockIdx.x > 0) excl[i] += bsum[blockIdx.x - 1];
}

// ---- K3: fused edge phase, 4 features/lane, 2 edges/wave, 1 wave/node.
// Lane t: f = t&31 owns features 4f..4f+3; slot = t>>5 picks edge 0/1 of a pair.
// One dwordx2 gather serves 2 edges; head-reduce is 3 DPP stages (8-lane heads).
// epack on the SCALAR pipe (d wave-uniform). Slot merge: 5 shfl_xor(32)/node.
__global__ void __launch_bounds__(256) k_edge(
    const int* __restrict__ rowptr, const int* __restrict__ deg,
    const int2* __restrict__ epack,
    const __half* __restrict__ xl, float* __restrict__ xrg,
    const float* __restrict__ We, const float* __restrict__ att,
    const float* __restrict__ gat_b, float* __restrict__ ps, float* __restrict__ pq) {
    struct h4 { __half2 a, b; };          // 8 B = 4 halves
    int t = threadIdx.x & 63;
    int w = __builtin_amdgcn_readfirstlane(threadIdx.x >> 6);   // wave 0..3 (uniform)
    int d = blockIdx.x * 4 + w;           // node (50000 = 12500 * 4 exact)
    int f = t & 31;                       // feature quad
    bool slot0 = (t < 32);
    float em0 = slot0 ? 1.f : 0.f;

    const h4* xl4 = (const h4*)xl;        // row stride 32 h4
    long rowq = (long)d * 32;

    float4 xrv = ((const float4*)xrg)[rowq + f];
    float4 Wev = ((const float4*)We)[f];
    float4 av  = ((const float4*)att)[f];
    av.x *= kL2E; av.y *= kL2E; av.z *= kL2E; av.w *= kL2E;
    float4 gb  = ((const float4*)gat_b)[f];

    h4 xs = xl4[rowq + f];
    float2 xs01 = __half22float2(xs.a), xs23 = __half22float2(xs.b);

    // self loop (ea = 0), counted on slot 0 only
    float z0 = xs01.x + xrv.x, z1 = xs01.y + xrv.y;
    float z2 = xs23.x + xrv.z, z3 = xs23.y + xrv.w;
    z0 = fmaxf(z0, kSlope * z0); z1 = fmaxf(z1, kSlope * z1);
    z2 = fmaxf(z2, kSlope * z2); z3 = fmaxf(z3, kSlope * z3);
    float p = red8(z0 * av.x + z1 * av.y + z2 * av.z + z3 * av.w);
    float ee = __builtin_amdgcn_exp2f(p - kShift2) * em0;
    float l = ee;
    float o0 = ee * xs01.x, o1 = ee * xs01.y, o2 = ee * xs23.x, o3 = ee * xs23.y;

    int base = rowptr[d], cnt = deg[d];   // uniform -> SGPR
    int npair = cnt >> 1;
    int e = 0;
    for (; e + 4 <= npair; e += 4) {
        int2 pa[4], pb[4];
        #pragma unroll
        for (int u = 0; u < 4; ++u) {
            pa[u] = epack[base + 2 * (e + u)];
            pb[u] = epack[base + 2 * (e + u) + 1];
        }
        h4 xv[4]; float eav[4];
        #pragma unroll
        for (int u = 0; u < 4; ++u) {
            int srow = slot0 ? pa[u].x : pb[u].x;
            xv[u] = xl4[(long)srow * 32 + f];
            eav[u] = __int_as_float(slot0 ? pa[u].y : pb[u].y);
        }
        #pragma unroll
        for (int u = 0; u < 4; ++u) {
            float2 x01 = __half22float2(xv[u].a), x23 = __half22float2(xv[u].b);
            float a0 = fmaf(eav[u], Wev.x, xrv.x) + x01.x;
            float a1 = fmaf(eav[u], Wev.y, xrv.y) + x01.y;
            float a2 = fmaf(eav[u], Wev.z, xrv.z) + x23.x;
            float a3 = fmaf(eav[u], Wev.w, xrv.w) + x23.y;
            a0 = fmaxf(a0, kSlope * a0); a1 = fmaxf(a1, kSlope * a1);
            a2 = fmaxf(a2, kSlope * a2); a3 = fmaxf(a3, kSlope * a3);
            float pp = red8(a0 * av.x + a1 * av.y + a2 * av.z + a3 * av.w);
            float eu = __builtin_amdgcn_exp2f(pp - kShift2);
            l += eu;
            o0 = fmaf(eu, x01.x, o0); o1 = fmaf(eu, x01.y, o1);
            o2 = fmaf(eu, x23.x, o2); o3 = fmaf(eu, x23.y, o3);
        }
    }
    for (; e < npair; ++e) {
        int2 pa = epack[base + 2 * e];
        int2 pb = epack[base + 2 * e + 1];
        int srow = slot0 ? pa.x : pb.x;
        float eav = __int_as_float(slot0 ? pa.y : pb.y);
        h4 xv = xl4[(long)srow * 32 + f];
        float2 x01 = __half22float2(xv.a), x23 = __half22float2(xv.b);
        float a0 = fmaf(eav, Wev.x, xrv.x) + x01.x;
        float a1 = fmaf(eav, Wev.y, xrv.y) + x01.y;
        float a2 = fmaf(eav, Wev.z, xrv.z) + x23.x;
        float a3 = fmaf(eav, Wev.w, xrv.w) + x23.y;
        a0 = fmaxf(a0, kSlope * a0); a1 = fmaxf(a1, kSlope * a1);
        a2 = fmaxf(a2, kSlope * a2); a3 = fmaxf(a3, kSlope * a3);
        float pp = red8(a0 * av.x + a1 * av.y + a2 * av.z + a3 * av.w);
        float eu = __builtin_amdgcn_exp2f(pp - kShift2);
        l += eu;
        o0 = fmaf(eu, x01.x, o0); o1 = fmaf(eu, x01.y, o1);
        o2 = fmaf(eu, x23.x, o2); o3 = fmaf(eu, x23.y, o3);
    }
    if (cnt & 1) {                        // odd tail edge on slot 0 only
        int2 ep = epack[base + cnt - 1];
        int srow = ep.x;
        float eav = __int_as_float(ep.y);
        h4 xv = xl4[(long)srow * 32 + f];
        float2 x01 = __half22float2(xv.a), x23 = __half22float2(xv.b);
        float a0 = fmaf(eav, Wev.x, xrv.x) + x01.x;
        float a1 = fmaf(eav, Wev.y, xrv.y) + x01.y;
        float a2 = fmaf(eav, Wev.z, xrv.z) + x23.x;
        float a3 = fmaf(eav, Wev.w, xrv.w) + x23.y;
        a0 = fmaxf(a0, kSlope * a0); a1 = fmaxf(a1, kSlope * a1);
        a2 = fmaxf(a2, kSlope * a2); a3 = fmaxf(a3, kSlope * a3);
        float pp = red8(a0 * av.x + a1 * av.y + a2 * av.z + a3 * av.w);
        float eu = __builtin_amdgcn_exp2f(pp - kShift2) * em0;
        l += eu;
        o0 = fmaf(eu, x01.x, o0); o1 = fmaf(eu, x01.y, o1);
        o2 = fmaf(eu, x23.x, o2); o3 = fmaf(eu, x23.y, o3);
    }
    // merge the two edge slots
    l  += __shfl_xor(l, 32);
    o0 += __shfl_xor(o0, 32); o1 += __shfl_xor(o1, 32);
    o2 += __shfl_xor(o2, 32); o3 += __shfl_xor(o3, 32);
    float rl = __builtin_amdgcn_rcpf(l);
    float v0 = o0 * rl, v1 = o1 * rl, v2 = o2 * rl, v3 = o3 * rl;
    if (slot0)
        ((float4*)xrg)[rowq + f] = make_float4(v0, v1, v2, v3);  // g overwrites xr
    float vb0 = v0 + gb.x, vb1 = v1 + gb.y, vb2 = v2 + gb.z, vb3 = v3 + gb.w;
    float s = vb0 + vb1 + vb2 + vb3;
    float q = vb0 * vb0 + vb1 * vb1 + vb2 * vb2 + vb3 * vb3;
    #pragma unroll
    for (int mm = 1; mm < 32; mm <<= 1) { s += __shfl_xor(s, mm); q += __shfl_xor(q, mm); }
    if (t == 0) { ps[d] = s; pq[d] = q; }
}

// ---- K4: reduce per-node partials -> stats[2].
__global__ void __launch_bounds__(1024) k_statsr(
    const float* __restrict__ ps, const float* __restrict__ pq, float* __restrict__ stats) {
    __shared__ float rs[1024], rq[1024];
    int t = threadIdx.x;
    float s = 0.f, q = 0.f;
    for (int i = t; i < kNodes; i += 1024) { s += ps[i]; q += pq[i]; }
    rs[t] = s; rq[t] = q;
    __syncthreads();
    for (int o = 512; o > 0; o >>= 1) {
        if (t < o) { rs[t] += rs[t + o]; rq[t] += rq[t + o]; }
        __syncthreads();
    }
    if (t == 0) { stats[0] = rs[0]; stats[1] = rq[0]; }
}

// ---- K5: h = relu(node_ln(relu(graph_ln(g+gat_b)) @ lin_w + lin_b)); jk_out = max(jk_in, h)
__global__ void __launch_bounds__(256) k_post(
    const float* __restrict__ g, const float* __restrict__ gat_b,
    const float* __restrict__ ln1w, const float* __restrict__ ln1b,
    const float* __restrict__ linw, const float* __restrict__ linb,
    const float* __restrict__ ln2w, const float* __restrict__ ln2b,
    const float* __restrict__ stats, const float* __restrict__ jk_in,
    float* __restrict__ h, float* __restrict__ jk_out) {
    __shared__ float s_lwT[kC * kLWP];    // 16.6 KB, lin_w transposed
    __shared__ float s_vb[8 * kHC];       // 4 KB
    int t = threadIdx.x;
    int n0 = blockIdx.x * 8;
    const float inv = 1.f / ((float)kNodes * kHC);
    float mean = stats[0] * inv;
    float var  = stats[1] * inv - mean * mean;
    float rstd = rsqrtf(var + kEps);
    for (int i = t; i < kHC * kC; i += 256) {
        int k = i >> 5, c = i & 31;
        s_lwT[c * kLWP + k] = linw[i];
    }
    for (int i = t; i < 8 * kHC; i += 256) {
        int node = n0 + (i >> 7), f = i & 127;
        float a = (g[(long)node * kHC + f] + gat_b[f] - mean) * rstd * ln1w[f] + ln1b[f];
        s_vb[i] = fmaxf(a, 0.f);
    }
    __syncthreads();
    int n = t >> 5, c = t & 31;
    int node = n0 + n;
    float acc = linb[c];
    const float* vb = s_vb + n * kHC;
    const float* wr = s_lwT + c * kLWP;
    #pragma unroll 8
    for (int k = 0; k < kHC; k += 4) {
        float4 v4 = *(const float4*)(vb + k);
        float2 w0 = *(const float2*)(wr + k);
        float2 w1 = *(const float2*)(wr + k + 2);
        acc += v4.x * w0.x + v4.y * w0.y + v4.z * w1.x + v4.w * w1.y;
    }
    float m = acc;
    #pragma unroll
    for (int mm = 1; mm < 32; mm <<= 1) m += __shfl_xor(m, mm);
    m *= (1.f / kC);
    float dd = acc - m;
    float q = dd * dd;
    #pragma unroll
    for (int mm = 1; mm < 32; mm <<= 1) q += __shfl_xor(q, mm);
    q *= (1.f / kC);
    float out = dd * rsqrtf(q + kEps) * ln2w[c] + ln2b[c];
    out = fmaxf(out, 0.f);
    h[node * kC + c] = out;
    jk_out[node * kC + c] = fmaxf(jk_in[node * kC + c], out);
}

extern "C" void kernel_launch(void* const* d_in, const int* in_sizes, int n_in,
                              void* d_out, int out_size, void* d_ws, size_t ws_size,
                              hipStream_t stream) {
    (void)in_sizes; (void)n_in; (void)out_size; (void)ws_size;
    const float* x     = (const float*)d_in[0];
    const int*   ei    = (const int*)d_in[1];
    const int*   src   = ei;
    const int*   dst   = ei + kNE;
    const float* ea    = (const float*)d_in[2];
    const float* W_emb = (const float*)d_in[3];
    const float* b_emb = (const float*)d_in[4];
    const float* ln0w  = (const float*)d_in[5];
    const float* ln0b  = (const float*)d_in[6];
    const float* Wl    = (const float*)d_in[7];
    const float* bl    = (const float*)d_in[8];
    const float* Wr    = (const float*)d_in[9];
    const float* br    = (const float*)d_in[10];
    const float* We    = (const float*)d_in[11];
    const float* att   = (const float*)d_in[12];
    const float* gat_b = (const float*)d_in[13];
    const float* ln1w  = (const float*)d_in[14];
    const float* ln1b  = (const float*)d_in[15];
    const float* linw  = (const float*)d_in[16];
    const float* linb  = (const float*)d_in[17];
    const float* ln2w  = (const float*)d_in[18];
    const float* ln2b  = (const float*)d_in[19];

    char* wsb = (char*)d_ws;
    float*  h      = (float*)(wsb);                 // 6.4e6 B
    float*  jk     = (float*)(wsb +  6400000);      // 6.4e6 B
    float*  xrg    = (float*)(wsb + 12800000);      // 25.6e6 B (xr, later g)
    __half* xl     = (__half*)(wsb + 38400000);     // 12.8e6 B
    int2*   epack  = (int2*)(wsb + 51200000);       // 6.4e6 B (packed src+ea per edge)
    int*    deg    = (int*)(wsb + 57600000);        // 0.2e6 B
    int*    cur    = (int*)(wsb + 57800000);        // 0.2e6 B
    int*    rowptr = (int*)(wsb + 58000000);        // 0.2e6 B
    int*    bsum   = (int*)(wsb + 58200000);        // 1 KB
    float*  stats  = (float*)(wsb + 58201024);      // 8 B
    float*  ps     = (float*)(wsb + 58300000);      // 0.2e6 B
    float*  pq     = (float*)(wsb + 58500000);      // 0.2e6 B

    const int scanBlocks = (kNodes + 255) / 256;         // 196
    const int edgeBlocks = kNodes / 4;                   // 12500 exact, 4 nodes/block
    const int postBlocks = kNodes / 8;                   // 6250 exact

    // zero deg + cur, then fused embed ∥ hist
    hipLaunchKernelGGL(k_fill0, dim3((2 * kNodes + 255) / 256), dim3(256), 0, stream,
                       (unsigned*)deg, 2 * kNodes);
    hipLaunchKernelGGL(k_embed_hist, dim3(kEmbedBlocks + kHistBlocks), dim3(256), 0, stream,
                       x, W_emb, b_emb, ln0w, ln0b, h, jk, dst, deg);
    hipLaunchKernelGGL(k_scan1, dim3(scanBlocks), dim3(256), 0, stream, deg, rowptr, bsum);
    hipLaunchKernelGGL(k_scan2, dim3(1), dim3(256), 0, stream, bsum, scanBlocks);
    hipLaunchKernelGGL(k_scan3, dim3(scanBlocks), dim3(256), 0, stream, rowptr, bsum);
    // fused reorder ∥ trans(layer 0)
    hipLaunchKernelGGL(k_trans_reorder, dim3(kHistBlocks + kTransBlocks), dim3(256), 0, stream,
                       h, Wl, bl, Wr, br, xl, xrg,
                       src, dst, ea, rowptr, cur, epack);
    for (int l = 0; l < 2; ++l) {
        if (l == 1) {
            hipLaunchKernelGGL(k_trans, dim3(kTransBlocks), dim3(256), 0, stream,
                               h, Wl + l * kC * kHC, bl + l * kHC,
                               Wr + l * kC * kHC, br + l * kHC, xl, xrg);
        }
        hipLaunchKernelGGL(k_edge, dim3(edgeBlocks), dim3(256), 0, stream,
                           rowptr, deg, epack, xl, xrg,
                           We + l * kHC, att + l * kH * kC, gat_b + l * kHC, ps, pq);
        hipLaunchKernelGGL(k_statsr, dim3(1), dim3(1024), 0, stream, ps, pq, stats);
        hipLaunchKernelGGL(k_post, dim3(postBlocks), dim3(256), 0, stream,
                           xrg, gat_b + l * kHC, ln1w + l * kHC, ln1b + l * kHC,
                           linw + l * kHC * kC, linb + l * kC,
                           ln2w + l * kC, ln2b + l * kC, stats, jk,
                           h, (l == 1) ? (float*)d_out : jk);
    }
}

// Round 7
// 456.274 us; speedup vs baseline: 1.2357x; 1.0138x over previous
//
#include <hip/hip_runtime.h>
#include <hip/hip_fp16.h>

constexpr int kNodes = 50000;
constexpr int kNE    = 800000;            // edges before self loops
constexpr int kFin   = 256;
constexpr int kC     = 32;
constexpr int kH     = 4;
constexpr int kHC    = 128;               // kH * kC
constexpr int kTN    = 16;                // nodes per k_embed block
constexpr int kWPh   = 264;               // padded fp16 W row: 528 B = 33*16 (aligned), 4-way alias on w-read
constexpr int kLWP   = 130;               // padded s_lwT row in k_post (float2-aligned, 2-way alias)
constexpr int kEmbedBlocks = kNodes / kTN;        // 3125
constexpr int kHistBlocks  = (kNE + 255) / 256;   // 3125
constexpr int kTransBlocks = (kNodes + 31) / 32;  // 1563
constexpr float kEps   = 1e-5f;
constexpr float kSlope = 0.2f;
constexpr float kL2E   = 1.44269504f;     // log2(e): fold into att so exp is 1 instr
constexpr float kShift2 = 8.0f * 1.44269504f; // softmax-invariant shift (exp2 domain)

typedef _Float16 f16;
typedef _Float16 f16x2 __attribute__((ext_vector_type(2)));
struct alignas(16) h8 { f16x2 v[4]; };    // 8 halves = 16 B

__device__ __forceinline__ float fdot2_(f16x2 a, f16x2 b, float c) {
#if __has_builtin(__builtin_amdgcn_fdot2)
    return __builtin_amdgcn_fdot2(a, b, c, false);
#else
    return fmaf((float)a.x, (float)b.x, fmaf((float)a.y, (float)b.y, c));
#endif
}

// ---- DPP butterfly add: v += partner(v), pure VALU (no DS pipe).
template<int CTRL>
__device__ __forceinline__ float dpp_add(float v) {
    int x = __builtin_amdgcn_update_dpp(0, __float_as_int(v), CTRL, 0xF, 0xF, true);
    return v + __int_as_float(x);
}
// 8-lane sum (head = 8 lanes x 4 features): xor1, xor2, then row_half_mirror.
__device__ __forceinline__ float red8(float p) {
    p = dpp_add<0xB1>(p);
    p = dpp_add<0x4E>(p);
    p = dpp_add<0x141>(p);
    return p;
}

// ---- zero-fill
__global__ void __launch_bounds__(256) k_fill0(unsigned* __restrict__ p, int n) {
    int i = blockIdx.x * 256 + threadIdx.x;
    if (i < n) p[i] = 0u;
}

// ---- K_A: role-split fused kernel, fp16 operands + v_dot2_f32_f16.
// blocks [0, kHistBlocks): degree histogram (placed FIRST: atomics start early).
// blocks [kHistBlocks, +kEmbedBlocks): h0 = relu(node_ln(x @ W_emb + b_emb)); jk = h0.
// LDS 24.5 KB -> 6 blocks/CU (vs 49.7 KB / 3 before); inner loop 3 DS + 8 dot2
// per 16 MACs (vs 8 DS + 16 FMA).
__global__ void __launch_bounds__(256) k_embed_hist(
    const float* __restrict__ x, const float* __restrict__ W, const float* __restrict__ b,
    const float* __restrict__ lnw, const float* __restrict__ lnb,
    float* __restrict__ h, float* __restrict__ jk,
    const int* __restrict__ dst, int* __restrict__ deg) {
    __shared__ f16 sxh[kTN * kFin];       // 8 KB
    __shared__ f16 sWh[kC * kWPh];        // 16.5 KB
    int t = threadIdx.x;
    if (blockIdx.x < kHistBlocks) {       // ---- hist role
        int e = blockIdx.x * 256 + t;
        if (e < kNE) atomicAdd(&deg[dst[e]], 1);
        return;
    }
    // ---- embed role
    int n0 = (blockIdx.x - kHistBlocks) * kTN;   // 50000 = 3125 * 16 exact
    for (int i = t; i < kFin * kC; i += 256) {
        int k = i >> 5, c = i & 31;
        sWh[c * kWPh + k] = (f16)W[i];
    }
    const float2* xg2 = (const float2*)(x + (long)n0 * kFin);
    f16x2* sx2 = (f16x2*)sxh;
    for (int i = t; i < kTN * kFin / 2; i += 256) {
        float2 v = xg2[i];
        f16x2 hv; hv.x = (f16)v.x; hv.y = (f16)v.y;
        sx2[i] = hv;
    }
    __syncthreads();
    int c = t & 31, n2 = t >> 5;          // n2 = 0..7
    const h8* xa = (const h8*)(sxh + n2 * kFin);
    const h8* xb = (const h8*)(sxh + (n2 + 8) * kFin);
    const h8* wr = (const h8*)(sWh + c * kWPh);
    float a0 = 0.f, a0b = 0.f, a1 = 0.f, a1b = 0.f;
    #pragma unroll 8
    for (int i8 = 0; i8 < kFin / 8; ++i8) {
        h8 xv0 = xa[i8];
        h8 xv1 = xb[i8];
        h8 wv  = wr[i8];
        a0  = fdot2_(xv0.v[0], wv.v[0], a0);
        a0b = fdot2_(xv0.v[1], wv.v[1], a0b);
        a0  = fdot2_(xv0.v[2], wv.v[2], a0);
        a0b = fdot2_(xv0.v[3], wv.v[3], a0b);
        a1  = fdot2_(xv1.v[0], wv.v[0], a1);
        a1b = fdot2_(xv1.v[1], wv.v[1], a1b);
        a1  = fdot2_(xv1.v[2], wv.v[2], a1);
        a1b = fdot2_(xv1.v[3], wv.v[3], a1b);
    }
    float acc0 = a0 + a0b, acc1 = a1 + a1b;
    float bc = b[c], lw = lnw[c], lb = lnb[c];
    {
        float y = acc0 + bc;
        float m = y;
        #pragma unroll
        for (int o = 1; o < 32; o <<= 1) m += __shfl_xor(m, o);
        m *= (1.f / kC);
        float xc = y - m, v = xc * xc;
        #pragma unroll
        for (int o = 1; o < 32; o <<= 1) v += __shfl_xor(v, o);
        v *= (1.f / kC);
        float out = fmaxf(xc * rsqrtf(v + kEps) * lw + lb, 0.f);
        int node = n0 + n2;
        h[node * kC + c] = out;
        jk[node * kC + c] = out;
    }
    {
        float y = acc1 + bc;
        float m = y;
        #pragma unroll
        for (int o = 1; o < 32; o <<= 1) m += __shfl_xor(m, o);
        m *= (1.f / kC);
        float xc = y - m, v = xc * xc;
        #pragma unroll
        for (int o = 1; o < 32; o <<= 1) v += __shfl_xor(v, o);
        v *= (1.f / kC);
        float out = fmaxf(xc * rsqrtf(v + kEps) * lw + lb, 0.f);
        int node = n0 + n2 + 8;
        h[node * kC + c] = out;
        jk[node * kC + c] = out;
    }
}

// ---- trans body: xl = h@Wl + bl (fp16) ; xr = h@Wr + br (fp32). bid = node-tile idx.
__device__ __forceinline__ void trans_body(
    int bid, float* s_h, const float* __restrict__ h,
    const float* __restrict__ Wl, const float* __restrict__ bl,
    const float* __restrict__ Wr, const float* __restrict__ br,
    __half* __restrict__ xl, float* __restrict__ xr) {
    int t = threadIdx.x;
    int j = t & 127, hf = t >> 7;
    float wl[kC], wr[kC];
    #pragma unroll
    for (int k = 0; k < kC; ++k) { wl[k] = Wl[k * kHC + j]; wr[k] = Wr[k * kHC + j]; }
    float blj = bl[j], brj = br[j];
    int n0 = bid * 32;
    int nn = min(32, kNodes - n0);
    for (int i = t; i < nn * kC; i += 256) s_h[i] = h[n0 * kC + i];
    __syncthreads();
    int nend = min(nn, hf * 16 + 16);
    for (int n = hf * 16; n < nend; ++n) {
        const float4* h4 = (const float4*)(s_h + n * kC);
        float al = blj, ar = brj;
        #pragma unroll
        for (int kq = 0; kq < 8; ++kq) {
            float4 hv = h4[kq];
            al += hv.x * wl[kq*4] + hv.y * wl[kq*4+1] + hv.z * wl[kq*4+2] + hv.w * wl[kq*4+3];
            ar += hv.x * wr[kq*4] + hv.y * wr[kq*4+1] + hv.z * wr[kq*4+2] + hv.w * wr[kq*4+3];
        }
        long g = (long)(n0 + n) * kHC + j;
        xl[g] = __float2half(al);
        xr[g] = ar;
    }
}

// ---- K2 (standalone, layer 1): k_trans
__global__ void __launch_bounds__(256) k_trans(
    const float* __restrict__ h,
    const float* __restrict__ Wl, const float* __restrict__ bl,
    const float* __restrict__ Wr, const float* __restrict__ br,
    __half* __restrict__ xl, float* __restrict__ xr) {
    __shared__ float s_h[32 * kC];
    trans_body(blockIdx.x, s_h, h, Wl, bl, Wr, br, xl, xr);
}

// ---- K_B: role-split fused kernel (layer 0 only).
// blocks [0, kHistBlocks): reorder (packed 8B scatter; atomic-latency-bound).
// blocks [kHistBlocks, +kTransBlocks): trans layer 0 (needs only h).
__global__ void __launch_bounds__(256) k_trans_reorder(
    const float* __restrict__ h,
    const float* __restrict__ Wl, const float* __restrict__ bl,
    const float* __restrict__ Wr, const float* __restrict__ br,
    __half* __restrict__ xl, float* __restrict__ xr,
    const int* __restrict__ src, const int* __restrict__ dst, const float* __restrict__ ea,
    const int* __restrict__ rowptr, int* __restrict__ cur, int2* __restrict__ epack) {
    __shared__ float s_h[32 * kC];
    if (blockIdx.x < kHistBlocks) {       // ---- reorder role (starts first)
        int e = blockIdx.x * 256 + threadIdx.x;
        if (e < kNE) {
            int d = dst[e];
            int pos = rowptr[d] + atomicAdd(&cur[d], 1);
            epack[pos] = make_int2(src[e], __float_as_int(ea[e]));
        }
        return;
    }
    trans_body(blockIdx.x - kHistBlocks, s_h, h, Wl, bl, Wr, br, xl, xr);
}

// ---- CSR scans (dst is layer-invariant: built ONCE)
__global__ void __launch_bounds__(256) k_scan1(const int* __restrict__ deg,
                                               int* __restrict__ excl, int* __restrict__ bsum) {
    __shared__ int s[256];
    int t = threadIdx.x;
    int i = blockIdx.x * 256 + t;
    int v = (i < kNodes) ? deg[i] : 0;
    s[t] = v;
    __syncthreads();
    for (int o = 1; o < 256; o <<= 1) {
        int tv = (t >= o) ? s[t - o] : 0;
        __syncthreads();
        s[t] += tv;
        __syncthreads();
    }
    if (i < kNodes) excl[i] = s[t] - v;
    if (t == 255) bsum[blockIdx.x] = s[255];
}

__global__ void __launch_bounds__(256) k_scan2(int* __restrict__ bsum, int nb) {
    __shared__ int s[256];
    int t = threadIdx.x;
    int v = (t < nb) ? bsum[t] : 0;
    s[t] = v;
    __syncthreads();
    for (int o = 1; o < 256; o <<= 1) {
        int tv = (t >= o) ? s[t - o] : 0;
        __syncthreads();
        s[t] += tv;
        __syncthreads();
    }
    if (t < nb) bsum[t] = s[t];
}

__global__ void __launch_bounds__(256) k_scan3(int* __restrict__ excl, const int* __restrict__ bsum) {
    int i = blockIdx.x * 256 + threadIdx.x;
    if (i >= kNodes) return;
    if (blockIdx.x > 0) excl[i] += bsum[blockIdx.x - 1];
}

// ---- K3: fused edge phase, 4 features/lane, 2 edges/wave, 1 wave/node.
__global__ void __launch_bounds__(256) k_edge(
    const int* __restrict__ rowptr, const int* __restrict__ deg,
    const int2* __restrict__ epack,
    const __half* __restrict__ xl, float* __restrict__ xrg,
    const float* __restrict__ We, const float* __restrict__ att,
    const float* __restrict__ gat_b, float* __restrict__ ps, float* __restrict__ pq) {
    struct h4 { __half2 a, b; };          // 8 B = 4 halves
    int t = threadIdx.x & 63;
    int w = __builtin_amdgcn_readfirstlane(threadIdx.x >> 6);   // wave 0..3 (uniform)
    int d = blockIdx.x * 4 + w;           // node (50000 = 12500 * 4 exact)
    int f = t & 31;                       // feature quad
    bool slot0 = (t < 32);
    float em0 = slot0 ? 1.f : 0.f;

    const h4* xl4 = (const h4*)xl;        // row stride 32 h4
    long rowq = (long)d * 32;

    float4 xrv = ((const float4*)xrg)[rowq + f];
    float4 Wev = ((const float4*)We)[f];
    float4 av  = ((const float4*)att)[f];
    av.x *= kL2E; av.y *= kL2E; av.z *= kL2E; av.w *= kL2E;
    float4 gb  = ((const float4*)gat_b)[f];

    h4 xs = xl4[rowq + f];
    float2 xs01 = __half22float2(xs.a), xs23 = __half22float2(xs.b);

    // self loop (ea = 0), counted on slot 0 only
    float z0 = xs01.x + xrv.x, z1 = xs01.y + xrv.y;
    float z2 = xs23.x + xrv.z, z3 = xs23.y + xrv.w;
    z0 = fmaxf(z0, kSlope * z0); z1 = fmaxf(z1, kSlope * z1);
    z2 = fmaxf(z2, kSlope * z2); z3 = fmaxf(z3, kSlope * z3);
    float p = red8(z0 * av.x + z1 * av.y + z2 * av.z + z3 * av.w);
    float ee = __builtin_amdgcn_exp2f(p - kShift2) * em0;
    float l = ee;
    float o0 = ee * xs01.x, o1 = ee * xs01.y, o2 = ee * xs23.x, o3 = ee * xs23.y;

    int base = rowptr[d], cnt = deg[d];   // uniform -> SGPR
    int npair = cnt >> 1;
    int e = 0;
    for (; e + 4 <= npair; e += 4) {
        int2 pa[4], pb[4];
        #pragma unroll
        for (int u = 0; u < 4; ++u) {
            pa[u] = epack[base + 2 * (e + u)];
            pb[u] = epack[base + 2 * (e + u) + 1];
        }
        h4 xv[4]; float eav[4];
        #pragma unroll
        for (int u = 0; u < 4; ++u) {
            int srow = slot0 ? pa[u].x : pb[u].x;
            xv[u] = xl4[(long)srow * 32 + f];
            eav[u] = __int_as_float(slot0 ? pa[u].y : pb[u].y);
        }
        #pragma unroll
        for (int u = 0; u < 4; ++u) {
            float2 x01 = __half22float2(xv[u].a), x23 = __half22float2(xv[u].b);
            float a0 = fmaf(eav[u], Wev.x, xrv.x) + x01.x;
            float a1 = fmaf(eav[u], Wev.y, xrv.y) + x01.y;
            float a2 = fmaf(eav[u], Wev.z, xrv.z) + x23.x;
            float a3 = fmaf(eav[u], Wev.w, xrv.w) + x23.y;
            a0 = fmaxf(a0, kSlope * a0); a1 = fmaxf(a1, kSlope * a1);
            a2 = fmaxf(a2, kSlope * a2); a3 = fmaxf(a3, kSlope * a3);
            float pp = red8(a0 * av.x + a1 * av.y + a2 * av.z + a3 * av.w);
            float eu = __builtin_amdgcn_exp2f(pp - kShift2);
            l += eu;
            o0 = fmaf(eu, x01.x, o0); o1 = fmaf(eu, x01.y, o1);
            o2 = fmaf(eu, x23.x, o2); o3 = fmaf(eu, x23.y, o3);
        }
    }
    for (; e < npair; ++e) {
        int2 pa = epack[base + 2 * e];
        int2 pb = epack[base + 2 * e + 1];
        int srow = slot0 ? pa.x : pb.x;
        float eav = __int_as_float(slot0 ? pa.y : pb.y);
        h4 xv = xl4[(long)srow * 32 + f];
        float2 x01 = __half22float2(xv.a), x23 = __half22float2(xv.b);
        float a0 = fmaf(eav, Wev.x, xrv.x) + x01.x;
        float a1 = fmaf(eav, Wev.y, xrv.y) + x01.y;
        float a2 = fmaf(eav, Wev.z, xrv.z) + x23.x;
        float a3 = fmaf(eav, Wev.w, xrv.w) + x23.y;
        a0 = fmaxf(a0, kSlope * a0); a1 = fmaxf(a1, kSlope * a1);
        a2 = fmaxf(a2, kSlope * a2); a3 = fmaxf(a3, kSlope * a3);
        float pp = red8(a0 * av.x + a1 * av.y + a2 * av.z + a3 * av.w);
        float eu = __builtin_amdgcn_exp2f(pp - kShift2);
        l += eu;
        o0 = fmaf(eu, x01.x, o0); o1 = fmaf(eu, x01.y, o1);
        o2 = fmaf(eu, x23.x, o2); o3 = fmaf(eu, x23.y, o3);
    }
    if (cnt & 1) {                        // odd tail edge on slot 0 only
        int2 ep = epack[base + cnt - 1];
        int srow = ep.x;
        float eav = __int_as_float(ep.y);
        h4 xv = xl4[(long)srow * 32 + f];
        float2 x01 = __half22float2(xv.a), x23 = __half22float2(xv.b);
        float a0 = fmaf(eav, Wev.x, xrv.x) + x01.x;
        float a1 = fmaf(eav, Wev.y, xrv.y) + x01.y;
        float a2 = fmaf(eav, Wev.z, xrv.z) + x23.x;
        float a3 = fmaf(eav, Wev.w, xrv.w) + x23.y;
        a0 = fmaxf(a0, kSlope * a0); a1 = fmaxf(a1, kSlope * a1);
        a2 = fmaxf(a2, kSlope * a2); a3 = fmaxf(a3, kSlope * a3);
        float pp = red8(a0 * av.x + a1 * av.y + a2 * av.z + a3 * av.w);
        float eu = __builtin_amdgcn_exp2f(pp - kShift2) * em0;
        l += eu;
        o0 = fmaf(eu, x01.x, o0); o1 = fmaf(eu, x01.y, o1);
        o2 = fmaf(eu, x23.x, o2); o3 = fmaf(eu, x23.y, o3);
    }
    // merge the two edge slots
    l  += __shfl_xor(l, 32);
    o0 += __shfl_xor(o0, 32); o1 += __shfl_xor(o1, 32);
    o2 += __shfl_xor(o2, 32); o3 += __shfl_xor(o3, 32);
    float rl = __builtin_amdgcn_rcpf(l);
    float v0 = o0 * rl, v1 = o1 * rl, v2 = o2 * rl, v3 = o3 * rl;
    if (slot0)
        ((float4*)xrg)[rowq + f] = make_float4(v0, v1, v2, v3);  // g overwrites xr
    float vb0 = v0 + gb.x, vb1 = v1 + gb.y, vb2 = v2 + gb.z, vb3 = v3 + gb.w;
    float s = vb0 + vb1 + vb2 + vb3;
    float q = vb0 * vb0 + vb1 * vb1 + vb2 * vb2 + vb3 * vb3;
    #pragma unroll
    for (int mm = 1; mm < 32; mm <<= 1) { s += __shfl_xor(s, mm); q += __shfl_xor(q, mm); }
    if (t == 0) { ps[d] = s; pq[d] = q; }
}

// ---- K4: reduce per-node partials -> stats[2].
__global__ void __launch_bounds__(1024) k_statsr(
    const float* __restrict__ ps, const float* __restrict__ pq, float* __restrict__ stats) {
    __shared__ float rs[1024], rq[1024];
    int t = threadIdx.x;
    float s = 0.f, q = 0.f;
    for (int i = t; i < kNodes; i += 1024) { s += ps[i]; q += pq[i]; }
    rs[t] = s; rq[t] = q;
    __syncthreads();
    for (int o = 512; o > 0; o >>= 1) {
        if (t < o) { rs[t] += rs[t + o]; rq[t] += rq[t + o]; }
        __syncthreads();
    }
    if (t == 0) { stats[0] = rs[0]; stats[1] = rq[0]; }
}

// ---- K5: h = relu(node_ln(relu(graph_ln(g+gat_b)) @ lin_w + lin_b)); jk_out = max(jk_in, h)
__global__ void __launch_bounds__(256) k_post(
    const float* __restrict__ g, const float* __restrict__ gat_b,
    const float* __restrict__ ln1w, const float* __restrict__ ln1b,
    const float* __restrict__ linw, const float* __restrict__ linb,
    const float* __restrict__ ln2w, const float* __restrict__ ln2b,
    const float* __restrict__ stats, const float* __restrict__ jk_in,
    float* __restrict__ h, float* __restrict__ jk_out) {
    __shared__ float s_lwT[kC * kLWP];    // 16.6 KB, lin_w transposed
    __shared__ float s_vb[8 * kHC];       // 4 KB
    int t = threadIdx.x;
    int n0 = blockIdx.x * 8;
    const float inv = 1.f / ((float)kNodes * kHC);
    float mean = stats[0] * inv;
    float var  = stats[1] * inv - mean * mean;
    float rstd = rsqrtf(var + kEps);
    for (int i = t; i < kHC * kC; i += 256) {
        int k = i >> 5, c = i & 31;
        s_lwT[c * kLWP + k] = linw[i];
    }
    for (int i = t; i < 8 * kHC; i += 256) {
        int node = n0 + (i >> 7), f = i & 127;
        float a = (g[(long)node * kHC + f] + gat_b[f] - mean) * rstd * ln1w[f] + ln1b[f];
        s_vb[i] = fmaxf(a, 0.f);
    }
    __syncthreads();
    int n = t >> 5, c = t & 31;
    int node = n0 + n;
    float acc = linb[c];
    const float* vb = s_vb + n * kHC;
    const float* wr = s_lwT + c * kLWP;
    #pragma unroll 8
    for (int k = 0; k < kHC; k += 4) {
        float4 v4 = *(const float4*)(vb + k);
        float2 w0 = *(const float2*)(wr + k);
        float2 w1 = *(const float2*)(wr + k + 2);
        acc += v4.x * w0.x + v4.y * w0.y + v4.z * w1.x + v4.w * w1.y;
    }
    float m = acc;
    #pragma unroll
    for (int mm = 1; mm < 32; mm <<= 1) m += __shfl_xor(m, mm);
    m *= (1.f / kC);
    float dd = acc - m;
    float q = dd * dd;
    #pragma unroll
    for (int mm = 1; mm < 32; mm <<= 1) q += __shfl_xor(q, mm);
    q *= (1.f / kC);
    float out = dd * rsqrtf(q + kEps) * ln2w[c] + ln2b[c];
    out = fmaxf(out, 0.f);
    h[node * kC + c] = out;
    jk_out[node * kC + c] = fmaxf(jk_in[node * kC + c], out);
}

extern "C" void kernel_launch(void* const* d_in, const int* in_sizes, int n_in,
                              void* d_out, int out_size, void* d_ws, size_t ws_size,
                              hipStream_t stream) {
    (void)in_sizes; (void)n_in; (void)out_size; (void)ws_size;
    const float* x     = (const float*)d_in[0];
    const int*   ei    = (const int*)d_in[1];
    const int*   src   = ei;
    const int*   dst   = ei + kNE;
    const float* ea    = (const float*)d_in[2];
    const float* W_emb = (const float*)d_in[3];
    const float* b_emb = (const float*)d_in[4];
    const float* ln0w  = (const float*)d_in[5];
    const float* ln0b  = (const float*)d_in[6];
    const float* Wl    = (const float*)d_in[7];
    const float* bl    = (const float*)d_in[8];
    const float* Wr    = (const float*)d_in[9];
    const float* br    = (const float*)d_in[10];
    const float* We    = (const float*)d_in[11];
    const float* att   = (const float*)d_in[12];
    const float* gat_b = (const float*)d_in[13];
    const float* ln1w  = (const float*)d_in[14];
    const float* ln1b  = (const float*)d_in[15];
    const float* linw  = (const float*)d_in[16];
    const float* linb  = (const float*)d_in[17];
    const float* ln2w  = (const float*)d_in[18];
    const float* ln2b  = (const float*)d_in[19];

    char* wsb = (char*)d_ws;
    float*  h      = (float*)(wsb);                 // 6.4e6 B
    float*  jk     = (float*)(wsb +  6400000);      // 6.4e6 B
    float*  xrg    = (float*)(wsb + 12800000);      // 25.6e6 B (xr, later g)
    __half* xl     = (__half*)(wsb + 38400000);     // 12.8e6 B
    int2*   epack  = (int2*)(wsb + 51200000);       // 6.4e6 B (packed src+ea per edge)
    int*    deg    = (int*)(wsb + 57600000);        // 0.2e6 B
    int*    cur    = (int*)(wsb + 57800000);        // 0.2e6 B
    int*    rowptr = (int*)(wsb + 58000000);        // 0.2e6 B
    int*    bsum   = (int*)(wsb + 58200000);        // 1 KB
    float*  stats  = (float*)(wsb + 58201024);      // 8 B
    float*  ps     = (float*)(wsb + 58300000);      // 0.2e6 B
    float*  pq     = (float*)(wsb + 58500000);      // 0.2e6 B

    const int scanBlocks = (kNodes + 255) / 256;         // 196
    const int edgeBlocks = kNodes / 4;                   // 12500 exact, 4 nodes/block
    const int postBlocks = kNodes / 8;                   // 6250 exact

    // zero deg + cur, then fused hist ∥ embed (hist first: atomics start early)
    hipLaunchKernelGGL(k_fill0, dim3((2 * kNodes + 255) / 256), dim3(256), 0, stream,
                       (unsigned*)deg, 2 * kNodes);
    hipLaunchKernelGGL(k_embed_hist, dim3(kHistBlocks + kEmbedBlocks), dim3(256), 0, stream,
                       x, W_emb, b_emb, ln0w, ln0b, h, jk, dst, deg);
    hipLaunchKernelGGL(k_scan1, dim3(scanBlocks), dim3(256), 0, stream, deg, rowptr, bsum);
    hipLaunchKernelGGL(k_scan2, dim3(1), dim3(256), 0, stream, bsum, scanBlocks);
    hipLaunchKernelGGL(k_scan3, dim3(scanBlocks), dim3(256), 0, stream, rowptr, bsum);
    // fused reorder ∥ trans(layer 0)
    hipLaunchKernelGGL(k_trans_reorder, dim3(kHistBlocks + kTransBlocks), dim3(256), 0, stream,
                       h, Wl, bl, Wr, br, xl, xrg,
                       src, dst, ea, rowptr, cur, epack);
    for (int l = 0; l < 2; ++l) {
        if (l == 1) {
            hipLaunchKernelGGL(k_trans, dim3(kTransBlocks), dim3(256), 0, stream,
                               h, Wl + l * kC * kHC, bl + l * kHC,
                               Wr + l * kC * kHC, br + l * kHC, xl, xrg);
        }
        hipLaunchKernelGGL(k_edge, dim3(edgeBlocks), dim3(256), 0, stream,
                           rowptr, deg, epack, xl, xrg,
                           We + l * kHC, att + l * kH * kC, gat_b + l * kHC, ps, pq);
        hipLaunchKernelGGL(k_statsr, dim3(1), dim3(1024), 0, stream, ps, pq, stats);
        hipLaunchKernelGGL(k_post, dim3(postBlocks), dim3(256), 0, stream,
                           xrg, gat_b + l * kHC, ln1w + l * kHC, ln1b + l * kHC,
                           linw + l * kHC * kC, linb + l * kC,
                           ln2w + l * kC, ln2b + l * kC, stats, jk,
                           h, (l == 1) ? (float*)d_out : jk);
    }
}

// Round 8
// 421.585 us; speedup vs baseline: 1.3374x; 1.0823x over previous
//
#include <hip/hip_runtime.h>
#include <hip/hip_fp16.h>

constexpr int kNodes = 50000;
constexpr int kNE    = 800000;            // edges before self loops
constexpr int kFin   = 256;
constexpr int kC     = 32;
constexpr int kH     = 4;
constexpr int kHC    = 128;               // kH * kC
constexpr int kTN    = 16;                // nodes per k_embed block
constexpr int kWPh   = 264;               // padded fp16 W row: 528 B = 33*16 (aligned)
constexpr int kLWP   = 130;               // padded s_lwT row in k_post (float2-aligned, 2-way alias)
constexpr int kEmbedBlocks = kNodes / kTN;        // 3125
constexpr int kHistBlocks  = (kNE + 255) / 256;   // 3125
constexpr int kTransBlocks = (kNodes + 31) / 32;  // 1563
constexpr float kEps   = 1e-5f;
constexpr float kSlope = 0.2f;
constexpr float kL2E   = 1.44269504f;     // log2(e): fold into att so exp is 1 instr
constexpr float kShift2 = 8.0f * 1.44269504f; // softmax-invariant shift (exp2 domain)

typedef _Float16 f16;
typedef _Float16 f16x2 __attribute__((ext_vector_type(2)));
struct alignas(16) h8 { f16x2 v[4]; };    // 8 halves = 16 B

__device__ __forceinline__ float fdot2_(f16x2 a, f16x2 b, float c) {
#if __has_builtin(__builtin_amdgcn_fdot2)
    return __builtin_amdgcn_fdot2(a, b, c, false);
#else
    return fmaf((float)a.x, (float)b.x, fmaf((float)a.y, (float)b.y, c));
#endif
}

// ---- DPP butterfly add: v += partner(v), pure VALU (no DS pipe).
template<int CTRL>
__device__ __forceinline__ float dpp_add(float v) {
    int x = __builtin_amdgcn_update_dpp(0, __float_as_int(v), CTRL, 0xF, 0xF, true);
    return v + __int_as_float(x);
}
// 8-lane sum (head = 8 lanes x 4 features): xor1, xor2, then row_half_mirror.
__device__ __forceinline__ float red8(float p) {
    p = dpp_add<0xB1>(p);
    p = dpp_add<0x4E>(p);
    p = dpp_add<0x141>(p);
    return p;
}

// ---- zero-fill
__global__ void __launch_bounds__(256) k_fill0(unsigned* __restrict__ p, int n) {
    int i = blockIdx.x * 256 + threadIdx.x;
    if (i < n) p[i] = 0u;
}

// ---- K_A: role-split fused kernel, fp16 operands + v_dot2_f32_f16.
// blocks [0, kHistBlocks): degree histogram; the atomicAdd RETURN VALUE is the
// edge's rank within its dst row -> stored to rank[e] (kills reorder's atomic).
// blocks [kHistBlocks, +kEmbedBlocks): h0 = relu(node_ln(x @ W_emb + b_emb)); jk = h0.
__global__ void __launch_bounds__(256) k_embed_hist(
    const float* __restrict__ x, const float* __restrict__ W, const float* __restrict__ b,
    const float* __restrict__ lnw, const float* __restrict__ lnb,
    float* __restrict__ h, float* __restrict__ jk,
    const int* __restrict__ dst, int* __restrict__ deg, unsigned short* __restrict__ rank) {
    __shared__ f16 sxh[kTN * kFin];       // 8 KB
    __shared__ f16 sWh[kC * kWPh];        // 16.5 KB
    int t = threadIdx.x;
    if (blockIdx.x < kHistBlocks) {       // ---- hist role
        int e = blockIdx.x * 256 + t;
        if (e < kNE) {
            int r = atomicAdd(&deg[dst[e]], 1);
            rank[e] = (unsigned short)r;  // max degree ~50 << 65536
        }
        return;
    }
    // ---- embed role
    int n0 = (blockIdx.x - kHistBlocks) * kTN;   // 50000 = 3125 * 16 exact
    for (int i = t; i < kFin * kC; i += 256) {
        int k = i >> 5, c = i & 31;
        sWh[c * kWPh + k] = (f16)W[i];
    }
    const float2* xg2 = (const float2*)(x + (long)n0 * kFin);
    f16x2* sx2 = (f16x2*)sxh;
    for (int i = t; i < kTN * kFin / 2; i += 256) {
        float2 v = xg2[i];
        f16x2 hv; hv.x = (f16)v.x; hv.y = (f16)v.y;
        sx2[i] = hv;
    }
    __syncthreads();
    int c = t & 31, n2 = t >> 5;          // n2 = 0..7
    const h8* xa = (const h8*)(sxh + n2 * kFin);
    const h8* xb = (const h8*)(sxh + (n2 + 8) * kFin);
    const h8* wr = (const h8*)(sWh + c * kWPh);
    float a0 = 0.f, a0b = 0.f, a1 = 0.f, a1b = 0.f;
    #pragma unroll 8
    for (int i8 = 0; i8 < kFin / 8; ++i8) {
        h8 xv0 = xa[i8];
        h8 xv1 = xb[i8];
        h8 wv  = wr[i8];
        a0  = fdot2_(xv0.v[0], wv.v[0], a0);
        a0b = fdot2_(xv0.v[1], wv.v[1], a0b);
        a0  = fdot2_(xv0.v[2], wv.v[2], a0);
        a0b = fdot2_(xv0.v[3], wv.v[3], a0b);
        a1  = fdot2_(xv1.v[0], wv.v[0], a1);
        a1b = fdot2_(xv1.v[1], wv.v[1], a1b);
        a1  = fdot2_(xv1.v[2], wv.v[2], a1);
        a1b = fdot2_(xv1.v[3], wv.v[3], a1b);
    }
    float acc0 = a0 + a0b, acc1 = a1 + a1b;
    float bc = b[c], lw = lnw[c], lb = lnb[c];
    {
        float y = acc0 + bc;
        float m = y;
        #pragma unroll
        for (int o = 1; o < 32; o <<= 1) m += __shfl_xor(m, o);
        m *= (1.f / kC);
        float xc = y - m, v = xc * xc;
        #pragma unroll
        for (int o = 1; o < 32; o <<= 1) v += __shfl_xor(v, o);
        v *= (1.f / kC);
        float out = fmaxf(xc * rsqrtf(v + kEps) * lw + lb, 0.f);
        int node = n0 + n2;
        h[node * kC + c] = out;
        jk[node * kC + c] = out;
    }
    {
        float y = acc1 + bc;
        float m = y;
        #pragma unroll
        for (int o = 1; o < 32; o <<= 1) m += __shfl_xor(m, o);
        m *= (1.f / kC);
        float xc = y - m, v = xc * xc;
        #pragma unroll
        for (int o = 1; o < 32; o <<= 1) v += __shfl_xor(v, o);
        v *= (1.f / kC);
        float out = fmaxf(xc * rsqrtf(v + kEps) * lw + lb, 0.f);
        int node = n0 + n2 + 8;
        h[node * kC + c] = out;
        jk[node * kC + c] = out;
    }
}

// ---- trans body: xl = h@Wl + bl (fp16) ; xr = h@Wr + br (fp32). bid = node-tile idx.
__device__ __forceinline__ void trans_body(
    int bid, float* s_h, const float* __restrict__ h,
    const float* __restrict__ Wl, const float* __restrict__ bl,
    const float* __restrict__ Wr, const float* __restrict__ br,
    __half* __restrict__ xl, float* __restrict__ xr) {
    int t = threadIdx.x;
    int j = t & 127, hf = t >> 7;
    float wl[kC], wr[kC];
    #pragma unroll
    for (int k = 0; k < kC; ++k) { wl[k] = Wl[k * kHC + j]; wr[k] = Wr[k * kHC + j]; }
    float blj = bl[j], brj = br[j];
    int n0 = bid * 32;
    int nn = min(32, kNodes - n0);
    for (int i = t; i < nn * kC; i += 256) s_h[i] = h[n0 * kC + i];
    __syncthreads();
    int nend = min(nn, hf * 16 + 16);
    for (int n = hf * 16; n < nend; ++n) {
        const float4* h4 = (const float4*)(s_h + n * kC);
        float al = blj, ar = brj;
        #pragma unroll
        for (int kq = 0; kq < 8; ++kq) {
            float4 hv = h4[kq];
            al += hv.x * wl[kq*4] + hv.y * wl[kq*4+1] + hv.z * wl[kq*4+2] + hv.w * wl[kq*4+3];
            ar += hv.x * wr[kq*4] + hv.y * wr[kq*4+1] + hv.z * wr[kq*4+2] + hv.w * wr[kq*4+3];
        }
        long g = (long)(n0 + n) * kHC + j;
        xl[g] = __float2half(al);
        xr[g] = ar;
    }
}

// ---- K2 (standalone, layer 1): k_trans
__global__ void __launch_bounds__(256) k_trans(
    const float* __restrict__ h,
    const float* __restrict__ Wl, const float* __restrict__ bl,
    const float* __restrict__ Wr, const float* __restrict__ br,
    __half* __restrict__ xl, float* __restrict__ xr) {
    __shared__ float s_h[32 * kC];
    trans_body(blockIdx.x, s_h, h, Wl, bl, Wr, br, xl, xr);
}

// ---- K_B: role-split fused kernel (layer 0 only).
// blocks [0, kHistBlocks): reorder, now ATOMIC-FREE: pos = rowptr[dst] + rank[e].
// blocks [kHistBlocks, +kTransBlocks): trans layer 0 (needs only h).
__global__ void __launch_bounds__(256) k_trans_reorder(
    const float* __restrict__ h,
    const float* __restrict__ Wl, const float* __restrict__ bl,
    const float* __restrict__ Wr, const float* __restrict__ br,
    __half* __restrict__ xl, float* __restrict__ xr,
    const int* __restrict__ src, const int* __restrict__ dst, const float* __restrict__ ea,
    const int* __restrict__ rowptr, const unsigned short* __restrict__ rank,
    int2* __restrict__ epack) {
    __shared__ float s_h[32 * kC];
    if (blockIdx.x < kHistBlocks) {       // ---- reorder role (starts first)
        int e = blockIdx.x * 256 + threadIdx.x;
        if (e < kNE) {
            int d = dst[e];
            int pos = rowptr[d] + (int)rank[e];
            epack[pos] = make_int2(src[e], __float_as_int(ea[e]));
        }
        return;
    }
    trans_body(blockIdx.x - kHistBlocks, s_h, h, Wl, bl, Wr, br, xl, xr);
}

// ---- CSR scans (dst is layer-invariant: built ONCE)
__global__ void __launch_bounds__(256) k_scan1(const int* __restrict__ deg,
                                               int* __restrict__ excl, int* __restrict__ bsum) {
    __shared__ int s[256];
    int t = threadIdx.x;
    int i = blockIdx.x * 256 + t;
    int v = (i < kNodes) ? deg[i] : 0;
    s[t] = v;
    __syncthreads();
    for (int o = 1; o < 256; o <<= 1) {
        int tv = (t >= o) ? s[t - o] : 0;
        __syncthreads();
        s[t] += tv;
        __syncthreads();
    }
    if (i < kNodes) excl[i] = s[t] - v;
    if (t == 255) bsum[blockIdx.x] = s[255];
}

__global__ void __launch_bounds__(256) k_scan2(int* __restrict__ bsum, int nb) {
    __shared__ int s[256];
    int t = threadIdx.x;
    int v = (t < nb) ? bsum[t] : 0;
    s[t] = v;
    __syncthreads();
    for (int o = 1; o < 256; o <<= 1) {
        int tv = (t >= o) ? s[t - o] : 0;
        __syncthreads();
        s[t] += tv;
        __syncthreads();
    }
    if (t < nb) bsum[t] = s[t];
}

__global__ void __launch_bounds__(256) k_scan3(int* __restrict__ excl, const int* __restrict__ bsum) {
    int i = blockIdx.x * 256 + threadIdx.x;
    if (i >= kNodes) return;
    if (blockIdx.x > 0) excl[i] += bsum[blockIdx.x - 1];
}

// ---- K3: fused edge phase, 4 features/lane, 2 edges/wave, 1 wave/node.
__global__ void __launch_bounds__(256) k_edge(
    const int* __restrict__ rowptr, const int* __restrict__ deg,
    const int2* __restrict__ epack,
    const __half* __restrict__ xl, float* __restrict__ xrg,
    const float* __restrict__ We, const float* __restrict__ att,
    const float* __restrict__ gat_b, float* __restrict__ ps, float* __restrict__ pq) {
    struct h4 { __half2 a, b; };          // 8 B = 4 halves
    int t = threadIdx.x & 63;
    int w = __builtin_amdgcn_readfirstlane(threadIdx.x >> 6);   // wave 0..3 (uniform)
    int d = blockIdx.x * 4 + w;           // node (50000 = 12500 * 4 exact)
    int f = t & 31;                       // feature quad
    bool slot0 = (t < 32);
    float em0 = slot0 ? 1.f : 0.f;

    const h4* xl4 = (const h4*)xl;        // row stride 32 h4
    long rowq = (long)d * 32;

    float4 xrv = ((const float4*)xrg)[rowq + f];
    float4 Wev = ((const float4*)We)[f];
    float4 av  = ((const float4*)att)[f];
    av.x *= kL2E; av.y *= kL2E; av.z *= kL2E; av.w *= kL2E;
    float4 gb  = ((const float4*)gat_b)[f];

    h4 xs = xl4[rowq + f];
    float2 xs01 = __half22float2(xs.a), xs23 = __half22float2(xs.b);

    // self loop (ea = 0), counted on slot 0 only
    float z0 = xs01.x + xrv.x, z1 = xs01.y + xrv.y;
    float z2 = xs23.x + xrv.z, z3 = xs23.y + xrv.w;
    z0 = fmaxf(z0, kSlope * z0); z1 = fmaxf(z1, kSlope * z1);
    z2 = fmaxf(z2, kSlope * z2); z3 = fmaxf(z3, kSlope * z3);
    float p = red8(z0 * av.x + z1 * av.y + z2 * av.z + z3 * av.w);
    float ee = __builtin_amdgcn_exp2f(p - kShift2) * em0;
    float l = ee;
    float o0 = ee * xs01.x, o1 = ee * xs01.y, o2 = ee * xs23.x, o3 = ee * xs23.y;

    int base = rowptr[d], cnt = deg[d];   // uniform -> SGPR
    int npair = cnt >> 1;
    int e = 0;
    for (; e + 4 <= npair; e += 4) {
        int2 pa[4], pb[4];
        #pragma unroll
        for (int u = 0; u < 4; ++u) {
            pa[u] = epack[base + 2 * (e + u)];
            pb[u] = epack[base + 2 * (e + u) + 1];
        }
        h4 xv[4]; float eav[4];
        #pragma unroll
        for (int u = 0; u < 4; ++u) {
            int srow = slot0 ? pa[u].x : pb[u].x;
            xv[u] = xl4[(long)srow * 32 + f];
            eav[u] = __int_as_float(slot0 ? pa[u].y : pb[u].y);
        }
        #pragma unroll
        for (int u = 0; u < 4; ++u) {
            float2 x01 = __half22float2(xv[u].a), x23 = __half22float2(xv[u].b);
            float a0 = fmaf(eav[u], Wev.x, xrv.x) + x01.x;
            float a1 = fmaf(eav[u], Wev.y, xrv.y) + x01.y;
            float a2 = fmaf(eav[u], Wev.z, xrv.z) + x23.x;
            float a3 = fmaf(eav[u], Wev.w, xrv.w) + x23.y;
            a0 = fmaxf(a0, kSlope * a0); a1 = fmaxf(a1, kSlope * a1);
            a2 = fmaxf(a2, kSlope * a2); a3 = fmaxf(a3, kSlope * a3);
            float pp = red8(a0 * av.x + a1 * av.y + a2 * av.z + a3 * av.w);
            float eu = __builtin_amdgcn_exp2f(pp - kShift2);
            l += eu;
            o0 = fmaf(eu, x01.x, o0); o1 = fmaf(eu, x01.y, o1);
            o2 = fmaf(eu, x23.x, o2); o3 = fmaf(eu, x23.y, o3);
        }
    }
    for (; e < npair; ++e) {
        int2 pa = epack[base + 2 * e];
        int2 pb = epack[base + 2 * e + 1];
        int srow = slot0 ? pa.x : pb.x;
        float eav = __int_as_float(slot0 ? pa.y : pb.y);
        h4 xv = xl4[(long)srow * 32 + f];
        float2 x01 = __half22float2(xv.a), x23 = __half22float2(xv.b);
        float a0 = fmaf(eav, Wev.x, xrv.x) + x01.x;
        float a1 = fmaf(eav, Wev.y, xrv.y) + x01.y;
        float a2 = fmaf(eav, Wev.z, xrv.z) + x23.x;
        float a3 = fmaf(eav, Wev.w, xrv.w) + x23.y;
        a0 = fmaxf(a0, kSlope * a0); a1 = fmaxf(a1, kSlope * a1);
        a2 = fmaxf(a2, kSlope * a2); a3 = fmaxf(a3, kSlope * a3);
        float pp = red8(a0 * av.x + a1 * av.y + a2 * av.z + a3 * av.w);
        float eu = __builtin_amdgcn_exp2f(pp - kShift2);
        l += eu;
        o0 = fmaf(eu, x01.x, o0); o1 = fmaf(eu, x01.y, o1);
        o2 = fmaf(eu, x23.x, o2); o3 = fmaf(eu, x23.y, o3);
    }
    if (cnt & 1) {                        // odd tail edge on slot 0 only
        int2 ep = epack[base + cnt - 1];
        int srow = ep.x;
        float eav = __int_as_float(ep.y);
        h4 xv = xl4[(long)srow * 32 + f];
        float2 x01 = __half22float2(xv.a), x23 = __half22float2(xv.b);
        float a0 = fmaf(eav, Wev.x, xrv.x) + x01.x;
        float a1 = fmaf(eav, Wev.y, xrv.y) + x01.y;
        float a2 = fmaf(eav, Wev.z, xrv.z) + x23.x;
        float a3 = fmaf(eav, Wev.w, xrv.w) + x23.y;
        a0 = fmaxf(a0, kSlope * a0); a1 = fmaxf(a1, kSlope * a1);
        a2 = fmaxf(a2, kSlope * a2); a3 = fmaxf(a3, kSlope * a3);
        float pp = red8(a0 * av.x + a1 * av.y + a2 * av.z + a3 * av.w);
        float eu = __builtin_amdgcn_exp2f(pp - kShift2) * em0;
        l += eu;
        o0 = fmaf(eu, x01.x, o0); o1 = fmaf(eu, x01.y, o1);
        o2 = fmaf(eu, x23.x, o2); o3 = fmaf(eu, x23.y, o3);
    }
    // merge the two edge slots
    l  += __shfl_xor(l, 32);
    o0 += __shfl_xor(o0, 32); o1 += __shfl_xor(o1, 32);
    o2 += __shfl_xor(o2, 32); o3 += __shfl_xor(o3, 32);
    float rl = __builtin_amdgcn_rcpf(l);
    float v0 = o0 * rl, v1 = o1 * rl, v2 = o2 * rl, v3 = o3 * rl;
    if (slot0)
        ((float4*)xrg)[rowq + f] = make_float4(v0, v1, v2, v3);  // g overwrites xr
    float vb0 = v0 + gb.x, vb1 = v1 + gb.y, vb2 = v2 + gb.z, vb3 = v3 + gb.w;
    float s = vb0 + vb1 + vb2 + vb3;
    float q = vb0 * vb0 + vb1 * vb1 + vb2 * vb2 + vb3 * vb3;
    #pragma unroll
    for (int mm = 1; mm < 32; mm <<= 1) { s += __shfl_xor(s, mm); q += __shfl_xor(q, mm); }
    if (t == 0) { ps[d] = s; pq[d] = q; }
}

// ---- K4: reduce per-node partials -> stats[2].
__global__ void __launch_bounds__(1024) k_statsr(
    const float* __restrict__ ps, const float* __restrict__ pq, float* __restrict__ stats) {
    __shared__ float rs[1024], rq[1024];
    int t = threadIdx.x;
    float s = 0.f, q = 0.f;
    for (int i = t; i < kNodes; i += 1024) { s += ps[i]; q += pq[i]; }
    rs[t] = s; rq[t] = q;
    __syncthreads();
    for (int o = 512; o > 0; o >>= 1) {
        if (t < o) { rs[t] += rs[t + o]; rq[t] += rq[t + o]; }
        __syncthreads();
    }
    if (t == 0) { stats[0] = rs[0]; stats[1] = rq[0]; }
}

// ---- K5: h = relu(node_ln(relu(graph_ln(g+gat_b)) @ lin_w + lin_b)); jk_out = max(jk_in, h)
__global__ void __launch_bounds__(256) k_post(
    const float* __restrict__ g, const float* __restrict__ gat_b,
    const float* __restrict__ ln1w, const float* __restrict__ ln1b,
    const float* __restrict__ linw, const float* __restrict__ linb,
    const float* __restrict__ ln2w, const float* __restrict__ ln2b,
    const float* __restrict__ stats, const float* __restrict__ jk_in,
    float* __restrict__ h, float* __restrict__ jk_out) {
    __shared__ float s_lwT[kC * kLWP];    // 16.6 KB, lin_w transposed
    __shared__ float s_vb[8 * kHC];       // 4 KB
    int t = threadIdx.x;
    int n0 = blockIdx.x * 8;
    const float inv = 1.f / ((float)kNodes * kHC);
    float mean = stats[0] * inv;
    float var  = stats[1] * inv - mean * mean;
    float rstd = rsqrtf(var + kEps);
    for (int i = t; i < kHC * kC; i += 256) {
        int k = i >> 5, c = i & 31;
        s_lwT[c * kLWP + k] = linw[i];
    }
    for (int i = t; i < 8 * kHC; i += 256) {
        int node = n0 + (i >> 7), f = i & 127;
        float a = (g[(long)node * kHC + f] + gat_b[f] - mean) * rstd * ln1w[f] + ln1b[f];
        s_vb[i] = fmaxf(a, 0.f);
    }
    __syncthreads();
    int n = t >> 5, c = t & 31;
    int node = n0 + n;
    float acc = linb[c];
    const float* vb = s_vb + n * kHC;
    const float* wr = s_lwT + c * kLWP;
    #pragma unroll 8
    for (int k = 0; k < kHC; k += 4) {
        float4 v4 = *(const float4*)(vb + k);
        float2 w0 = *(const float2*)(wr + k);
        float2 w1 = *(const float2*)(wr + k + 2);
        acc += v4.x * w0.x + v4.y * w0.y + v4.z * w1.x + v4.w * w1.y;
    }
    float m = acc;
    #pragma unroll
    for (int mm = 1; mm < 32; mm <<= 1) m += __shfl_xor(m, mm);
    m *= (1.f / kC);
    float dd = acc - m;
    float q = dd * dd;
    #pragma unroll
    for (int mm = 1; mm < 32; mm <<= 1) q += __shfl_xor(q, mm);
    q *= (1.f / kC);
    float out = dd * rsqrtf(q + kEps) * ln2w[c] + ln2b[c];
    out = fmaxf(out, 0.f);
    h[node * kC + c] = out;
    jk_out[node * kC + c] = fmaxf(jk_in[node * kC + c], out);
}

extern "C" void kernel_launch(void* const* d_in, const int* in_sizes, int n_in,
                              void* d_out, int out_size, void* d_ws, size_t ws_size,
                              hipStream_t stream) {
    (void)in_sizes; (void)n_in; (void)out_size; (void)ws_size;
    const float* x     = (const float*)d_in[0];
    const int*   ei    = (const int*)d_in[1];
    const int*   src   = ei;
    const int*   dst   = ei + kNE;
    const float* ea    = (const float*)d_in[2];
    const float* W_emb = (const float*)d_in[3];
    const float* b_emb = (const float*)d_in[4];
    const float* ln0w  = (const float*)d_in[5];
    const float* ln0b  = (const float*)d_in[6];
    const float* Wl    = (const float*)d_in[7];
    const float* bl    = (const float*)d_in[8];
    const float* Wr    = (const float*)d_in[9];
    const float* br    = (const float*)d_in[10];
    const float* We    = (const float*)d_in[11];
    const float* att   = (const float*)d_in[12];
    const float* gat_b = (const float*)d_in[13];
    const float* ln1w  = (const float*)d_in[14];
    const float* ln1b  = (const float*)d_in[15];
    const float* linw  = (const float*)d_in[16];
    const float* linb  = (const float*)d_in[17];
    const float* ln2w  = (const float*)d_in[18];
    const float* ln2b  = (const float*)d_in[19];

    char* wsb = (char*)d_ws;
    float*  h      = (float*)(wsb);                 // 6.4e6 B
    float*  jk     = (float*)(wsb +  6400000);      // 6.4e6 B
    float*  xrg    = (float*)(wsb + 12800000);      // 25.6e6 B (xr, later g)
    __half* xl     = (__half*)(wsb + 38400000);     // 12.8e6 B
    int2*   epack  = (int2*)(wsb + 51200000);       // 6.4e6 B (packed src+ea per edge)
    int*    deg    = (int*)(wsb + 57600000);        // 0.2e6 B
    int*    rowptr = (int*)(wsb + 58000000);        // 0.2e6 B
    int*    bsum   = (int*)(wsb + 58200000);        // 1 KB
    float*  stats  = (float*)(wsb + 58201024);      // 8 B
    float*  ps     = (float*)(wsb + 58300000);      // 0.2e6 B
    float*  pq     = (float*)(wsb + 58500000);      // 0.2e6 B
    unsigned short* rank = (unsigned short*)(wsb + 58700000);  // 1.6e6 B

    const int scanBlocks = (kNodes + 255) / 256;         // 196
    const int edgeBlocks = kNodes / 4;                   // 12500 exact, 4 nodes/block
    const int postBlocks = kNodes / 8;                   // 6250 exact

    // zero deg, then fused hist ∥ embed (hist first: atomics start early)
    hipLaunchKernelGGL(k_fill0, dim3((kNodes + 255) / 256), dim3(256), 0, stream,
                       (unsigned*)deg, kNodes);
    hipLaunchKernelGGL(k_embed_hist, dim3(kHistBlocks + kEmbedBlocks), dim3(256), 0, stream,
                       x, W_emb, b_emb, ln0w, ln0b, h, jk, dst, deg, rank);
    hipLaunchKernelGGL(k_scan1, dim3(scanBlocks), dim3(256), 0, stream, deg, rowptr, bsum);
    hipLaunchKernelGGL(k_scan2, dim3(1), dim3(256), 0, stream, bsum, scanBlocks);
    hipLaunchKernelGGL(k_scan3, dim3(scanBlocks), dim3(256), 0, stream, rowptr, bsum);
    // fused reorder ∥ trans(layer 0) — reorder is atomic-free now
    hipLaunchKernelGGL(k_trans_reorder, dim3(kHistBlocks + kTransBlocks), dim3(256), 0, stream,
                       h, Wl, bl, Wr, br, xl, xrg,
                       src, dst, ea, rowptr, rank, epack);
    for (int l = 0; l < 2; ++l) {
        if (l == 1) {
            hipLaunchKernelGGL(k_trans, dim3(kTransBlocks), dim3(256), 0, stream,
                               h, Wl + l * kC * kHC, bl + l * kHC,
                               Wr + l * kC * kHC, br + l * kHC, xl, xrg);
        }
        hipLaunchKernelGGL(k_edge, dim3(edgeBlocks), dim3(256), 0, stream,
                           rowptr, deg, epack, xl, xrg,
                           We + l * kHC, att + l * kH * kC, gat_b + l * kHC, ps, pq);
        hipLaunchKernelGGL(k_statsr, dim3(1), dim3(1024), 0, stream, ps, pq, stats);
        hipLaunchKernelGGL(k_post, dim3(postBlocks), dim3(256), 0, stream,
                           xrg, gat_b + l * kHC, ln1w + l * kHC, ln1b + l * kHC,
                           linw + l * kHC * kC, linb + l * kC,
                           ln2w + l * kC, ln2b + l * kC, stats, jk,
                           h, (l == 1) ? (float*)d_out : jk);
    }
}

// Round 9
// 419.253 us; speedup vs baseline: 1.3449x; 1.0056x over previous
//
#include <hip/hip_runtime.h>
#include <hip/hip_fp16.h>

constexpr int kNodes = 50000;
constexpr int kNE    = 800000;            // edges before self loops
constexpr int kFin   = 256;
constexpr int kC     = 32;
constexpr int kH     = 4;
constexpr int kHC    = 128;               // kH * kC
constexpr int kTN    = 16;                // nodes per k_embed block
constexpr int kLWP   = 130;               // padded s_lwT row in k_post (float2-aligned, 2-way alias)
constexpr int kEmbedBlocks = kNodes / kTN;        // 3125
constexpr int kTransBlocks = (kNodes + 31) / 32;  // 1563
constexpr int kHistGS = 256;              // grid-stride hist blocks (4-deep atomic MLP)
constexpr int kReoGS  = 256;              // grid-stride reorder blocks
constexpr float kEps   = 1e-5f;
constexpr float kSlope = 0.2f;
constexpr float kL2E   = 1.44269504f;     // log2(e): fold into att so exp is 1 instr
constexpr float kShift2 = 8.0f * 1.44269504f; // softmax-invariant shift (exp2 domain)

typedef _Float16 f16;
typedef _Float16 f16x2 __attribute__((ext_vector_type(2)));
struct alignas(16) h8 { f16x2 v[4]; };    // 8 halves = 16 B

__device__ __forceinline__ float fdot2_(f16x2 a, f16x2 b, float c) {
#if __has_builtin(__builtin_amdgcn_fdot2)
    return __builtin_amdgcn_fdot2(a, b, c, false);
#else
    return fmaf((float)a.x, (float)b.x, fmaf((float)a.y, (float)b.y, c));
#endif
}

// ---- DPP butterfly add: v += partner(v), pure VALU (no DS pipe).
template<int CTRL>
__device__ __forceinline__ float dpp_add(float v) {
    int x = __builtin_amdgcn_update_dpp(0, __float_as_int(v), CTRL, 0xF, 0xF, true);
    return v + __int_as_float(x);
}
// 8-lane sum (head = 8 lanes x 4 features): xor1, xor2, then row_half_mirror.
__device__ __forceinline__ float red8(float p) {
    p = dpp_add<0xB1>(p);
    p = dpp_add<0x4E>(p);
    p = dpp_add<0x141>(p);
    return p;
}

// ---- zero-fill
__global__ void __launch_bounds__(256) k_fill0(unsigned* __restrict__ p, int n) {
    int i = blockIdx.x * 256 + threadIdx.x;
    if (i < n) p[i] = 0u;
}

// ---- K_A: role-split fused kernel, fp16 operands + v_dot2_f32_f16.
// blocks [0, kHistGS): grid-stride degree histogram, 4-deep batches; the
// atomicAdd RETURN VALUE is the edge's rank within its dst row -> rank[e].
// blocks [kHistGS, +kEmbedBlocks): h0 = relu(node_ln(x @ W_emb + b_emb)); jk = h0.
// W tile stored [i8][c] as h8 -> lanes read consecutive 16B: conflict-free.
__global__ void __launch_bounds__(256) k_embed_hist(
    const float* __restrict__ x, const float* __restrict__ W, const float* __restrict__ b,
    const float* __restrict__ lnw, const float* __restrict__ lnb,
    float* __restrict__ h, float* __restrict__ jk,
    const int* __restrict__ dst, int* __restrict__ deg, unsigned short* __restrict__ rank) {
    __shared__ f16 sxh[kTN * kFin];       // 8 KB
    __shared__ f16 sWh[kFin / 8 * kC * 8];// 16 KB, [i8][c] blocks of 8 halves
    int t = threadIdx.x;
    if (blockIdx.x < kHistGS) {           // ---- hist role (grid-stride, 4-deep)
        const int stride = kHistGS * 256;
        int e = blockIdx.x * 256 + t;
        for (; e + 3 * stride < kNE; e += 4 * stride) {
            int d0 = dst[e], d1 = dst[e + stride], d2 = dst[e + 2 * stride], d3 = dst[e + 3 * stride];
            int r0 = atomicAdd(&deg[d0], 1);
            int r1 = atomicAdd(&deg[d1], 1);
            int r2 = atomicAdd(&deg[d2], 1);
            int r3 = atomicAdd(&deg[d3], 1);
            rank[e] = (unsigned short)r0;
            rank[e + stride] = (unsigned short)r1;
            rank[e + 2 * stride] = (unsigned short)r2;
            rank[e + 3 * stride] = (unsigned short)r3;
        }
        for (; e < kNE; e += stride) {
            int d = dst[e];
            rank[e] = (unsigned short)atomicAdd(&deg[d], 1);
        }
        return;
    }
    // ---- embed role
    int n0 = (blockIdx.x - kHistGS) * kTN;       // 50000 = 3125 * 16 exact
    for (int i = t; i < kFin * kC; i += 256) {
        int k = i >> 5, c = i & 31;
        sWh[((k >> 3) * kC + c) * 8 + (k & 7)] = (f16)W[i];
    }
    const float2* xg2 = (const float2*)(x + (long)n0 * kFin);
    f16x2* sx2 = (f16x2*)sxh;
    for (int i = t; i < kTN * kFin / 2; i += 256) {
        float2 v = xg2[i];
        f16x2 hv; hv.x = (f16)v.x; hv.y = (f16)v.y;
        sx2[i] = hv;
    }
    __syncthreads();
    int c = t & 31, n2 = t >> 5;          // n2 = 0..7
    const h8* xa = (const h8*)(sxh + n2 * kFin);
    const h8* xb = (const h8*)(sxh + (n2 + 8) * kFin);
    const h8* wr = (const h8*)sWh;        // [i8*kC + c]
    float a0 = 0.f, a0b = 0.f, a1 = 0.f, a1b = 0.f;
    #pragma unroll 8
    for (int i8 = 0; i8 < kFin / 8; ++i8) {
        h8 xv0 = xa[i8];
        h8 xv1 = xb[i8];
        h8 wv  = wr[i8 * kC + c];
        a0  = fdot2_(xv0.v[0], wv.v[0], a0);
        a0b = fdot2_(xv0.v[1], wv.v[1], a0b);
        a0  = fdot2_(xv0.v[2], wv.v[2], a0);
        a0b = fdot2_(xv0.v[3], wv.v[3], a0b);
        a1  = fdot2_(xv1.v[0], wv.v[0], a1);
        a1b = fdot2_(xv1.v[1], wv.v[1], a1b);
        a1  = fdot2_(xv1.v[2], wv.v[2], a1);
        a1b = fdot2_(xv1.v[3], wv.v[3], a1b);
    }
    float acc0 = a0 + a0b, acc1 = a1 + a1b;
    float bc = b[c], lw = lnw[c], lb = lnb[c];
    {
        float y = acc0 + bc;
        float m = y;
        #pragma unroll
        for (int o = 1; o < 32; o <<= 1) m += __shfl_xor(m, o);
        m *= (1.f / kC);
        float xc = y - m, v = xc * xc;
        #pragma unroll
        for (int o = 1; o < 32; o <<= 1) v += __shfl_xor(v, o);
        v *= (1.f / kC);
        float out = fmaxf(xc * rsqrtf(v + kEps) * lw + lb, 0.f);
        int node = n0 + n2;
        h[node * kC + c] = out;
        jk[node * kC + c] = out;
    }
    {
        float y = acc1 + bc;
        float m = y;
        #pragma unroll
        for (int o = 1; o < 32; o <<= 1) m += __shfl_xor(m, o);
        m *= (1.f / kC);
        float xc = y - m, v = xc * xc;
        #pragma unroll
        for (int o = 1; o < 32; o <<= 1) v += __shfl_xor(v, o);
        v *= (1.f / kC);
        float out = fmaxf(xc * rsqrtf(v + kEps) * lw + lb, 0.f);
        int node = n0 + n2 + 8;
        h[node * kC + c] = out;
        jk[node * kC + c] = out;
    }
}

// ---- trans body: xl = h@Wl + bl (fp16) ; xr = h@Wr + br (fp32). bid = node-tile idx.
__device__ __forceinline__ void trans_body(
    int bid, float* s_h, const float* __restrict__ h,
    const float* __restrict__ Wl, const float* __restrict__ bl,
    const float* __restrict__ Wr, const float* __restrict__ br,
    __half* __restrict__ xl, float* __restrict__ xr) {
    int t = threadIdx.x;
    int j = t & 127, hf = t >> 7;
    float wl[kC], wr[kC];
    #pragma unroll
    for (int k = 0; k < kC; ++k) { wl[k] = Wl[k * kHC + j]; wr[k] = Wr[k * kHC + j]; }
    float blj = bl[j], brj = br[j];
    int n0 = bid * 32;
    int nn = min(32, kNodes - n0);
    for (int i = t; i < nn * kC; i += 256) s_h[i] = h[n0 * kC + i];
    __syncthreads();
    int nend = min(nn, hf * 16 + 16);
    for (int n = hf * 16; n < nend; ++n) {
        const float4* h4 = (const float4*)(s_h + n * kC);
        float al = blj, ar = brj;
        #pragma unroll
        for (int kq = 0; kq < 8; ++kq) {
            float4 hv = h4[kq];
            al += hv.x * wl[kq*4] + hv.y * wl[kq*4+1] + hv.z * wl[kq*4+2] + hv.w * wl[kq*4+3];
            ar += hv.x * wr[kq*4] + hv.y * wr[kq*4+1] + hv.z * wr[kq*4+2] + hv.w * wr[kq*4+3];
        }
        long g = (long)(n0 + n) * kHC + j;
        xl[g] = __float2half(al);
        xr[g] = ar;
    }
}

// ---- K2 (standalone, layer 1): k_trans
__global__ void __launch_bounds__(256) k_trans(
    const float* __restrict__ h,
    const float* __restrict__ Wl, const float* __restrict__ bl,
    const float* __restrict__ Wr, const float* __restrict__ br,
    __half* __restrict__ xl, float* __restrict__ xr) {
    __shared__ float s_h[32 * kC];
    trans_body(blockIdx.x, s_h, h, Wl, bl, Wr, br, xl, xr);
}

// ---- K_B: role-split fused kernel (layer 0 only).
// blocks [0, kReoGS): reorder, atomic-free, grid-stride 4-deep:
// pos = rowptr[dst] + rank[e]; 4 chains in flight per thread.
// blocks [kReoGS, +kTransBlocks): trans layer 0 (needs only h).
__global__ void __launch_bounds__(256) k_trans_reorder(
    const float* __restrict__ h,
    const float* __restrict__ Wl, const float* __restrict__ bl,
    const float* __restrict__ Wr, const float* __restrict__ br,
    __half* __restrict__ xl, float* __restrict__ xr,
    const int* __restrict__ src, const int* __restrict__ dst, const float* __restrict__ ea,
    const int* __restrict__ rowptr, const unsigned short* __restrict__ rank,
    int2* __restrict__ epack) {
    __shared__ float s_h[32 * kC];
    if (blockIdx.x < kReoGS) {            // ---- reorder role (starts first)
        const int stride = kReoGS * 256;
        int e = blockIdx.x * 256 + threadIdx.x;
        for (; e + 3 * stride < kNE; e += 4 * stride) {
            int e1 = e + stride, e2 = e + 2 * stride, e3 = e + 3 * stride;
            int d0 = dst[e], d1 = dst[e1], d2 = dst[e2], d3 = dst[e3];
            int r0 = rank[e], r1 = rank[e1], r2 = rank[e2], r3 = rank[e3];
            int p0 = rowptr[d0] + r0, p1 = rowptr[d1] + r1;
            int p2 = rowptr[d2] + r2, p3 = rowptr[d3] + r3;
            epack[p0] = make_int2(src[e],  __float_as_int(ea[e]));
            epack[p1] = make_int2(src[e1], __float_as_int(ea[e1]));
            epack[p2] = make_int2(src[e2], __float_as_int(ea[e2]));
            epack[p3] = make_int2(src[e3], __float_as_int(ea[e3]));
        }
        for (; e < kNE; e += stride) {
            int d = dst[e];
            int pos = rowptr[d] + (int)rank[e];
            epack[pos] = make_int2(src[e], __float_as_int(ea[e]));
        }
        return;
    }
    trans_body(blockIdx.x - kReoGS, s_h, h, Wl, bl, Wr, br, xl, xr);
}

// ---- CSR scans (dst is layer-invariant: built ONCE)
__global__ void __launch_bounds__(256) k_scan1(const int* __restrict__ deg,
                                               int* __restrict__ excl, int* __restrict__ bsum) {
    __shared__ int s[256];
    int t = threadIdx.x;
    int i = blockIdx.x * 256 + t;
    int v = (i < kNodes) ? deg[i] : 0;
    s[t] = v;
    __syncthreads();
    for (int o = 1; o < 256; o <<= 1) {
        int tv = (t >= o) ? s[t - o] : 0;
        __syncthreads();
        s[t] += tv;
        __syncthreads();
    }
    if (i < kNodes) excl[i] = s[t] - v;
    if (t == 255) bsum[blockIdx.x] = s[255];
}

__global__ void __launch_bounds__(256) k_scan2(int* __restrict__ bsum, int nb) {
    __shared__ int s[256];
    int t = threadIdx.x;
    int v = (t < nb) ? bsum[t] : 0;
    s[t] = v;
    __syncthreads();
    for (int o = 1; o < 256; o <<= 1) {
        int tv = (t >= o) ? s[t - o] : 0;
        __syncthreads();
        s[t] += tv;
        __syncthreads();
    }
    if (t < nb) bsum[t] = s[t];
}

__global__ void __launch_bounds__(256) k_scan3(int* __restrict__ excl, const int* __restrict__ bsum) {
    int i = blockIdx.x * 256 + threadIdx.x;
    if (i >= kNodes) return;
    if (blockIdx.x > 0) excl[i] += bsum[blockIdx.x - 1];
}

// ---- K3: fused edge phase, 4 features/lane, 2 edges/wave, 1 wave/node.
__global__ void __launch_bounds__(256) k_edge(
    const int* __restrict__ rowptr, const int* __restrict__ deg,
    const int2* __restrict__ epack,
    const __half* __restrict__ xl, float* __restrict__ xrg,
    const float* __restrict__ We, const float* __restrict__ att,
    const float* __restrict__ gat_b, float* __restrict__ ps, float* __restrict__ pq) {
    struct h4 { __half2 a, b; };          // 8 B = 4 halves
    int t = threadIdx.x & 63;
    int w = __builtin_amdgcn_readfirstlane(threadIdx.x >> 6);   // wave 0..3 (uniform)
    int d = blockIdx.x * 4 + w;           // node (50000 = 12500 * 4 exact)
    int f = t & 31;                       // feature quad
    bool slot0 = (t < 32);
    float em0 = slot0 ? 1.f : 0.f;

    const h4* xl4 = (const h4*)xl;        // row stride 32 h4
    long rowq = (long)d * 32;

    float4 xrv = ((const float4*)xrg)[rowq + f];
    float4 Wev = ((const float4*)We)[f];
    float4 av  = ((const float4*)att)[f];
    av.x *= kL2E; av.y *= kL2E; av.z *= kL2E; av.w *= kL2E;
    float4 gb  = ((const float4*)gat_b)[f];

    h4 xs = xl4[rowq + f];
    float2 xs01 = __half22float2(xs.a), xs23 = __half22float2(xs.b);

    // self loop (ea = 0), counted on slot 0 only
    float z0 = xs01.x + xrv.x, z1 = xs01.y + xrv.y;
    float z2 = xs23.x + xrv.z, z3 = xs23.y + xrv.w;
    z0 = fmaxf(z0, kSlope * z0); z1 = fmaxf(z1, kSlope * z1);
    z2 = fmaxf(z2, kSlope * z2); z3 = fmaxf(z3, kSlope * z3);
    float p = red8(z0 * av.x + z1 * av.y + z2 * av.z + z3 * av.w);
    float ee = __builtin_amdgcn_exp2f(p - kShift2) * em0;
    float l = ee;
    float o0 = ee * xs01.x, o1 = ee * xs01.y, o2 = ee * xs23.x, o3 = ee * xs23.y;

    int base = rowptr[d], cnt = deg[d];   // uniform -> SGPR
    int npair = cnt >> 1;
    int e = 0;
    for (; e + 4 <= npair; e += 4) {
        int2 pa[4], pb[4];
        #pragma unroll
        for (int u = 0; u < 4; ++u) {
            pa[u] = epack[base + 2 * (e + u)];
            pb[u] = epack[base + 2 * (e + u) + 1];
        }
        h4 xv[4]; float eav[4];
        #pragma unroll
        for (int u = 0; u < 4; ++u) {
            int srow = slot0 ? pa[u].x : pb[u].x;
            xv[u] = xl4[(long)srow * 32 + f];
            eav[u] = __int_as_float(slot0 ? pa[u].y : pb[u].y);
        }
        #pragma unroll
        for (int u = 0; u < 4; ++u) {
            float2 x01 = __half22float2(xv[u].a), x23 = __half22float2(xv[u].b);
            float a0 = fmaf(eav[u], Wev.x, xrv.x) + x01.x;
            float a1 = fmaf(eav[u], Wev.y, xrv.y) + x01.y;
            float a2 = fmaf(eav[u], Wev.z, xrv.z) + x23.x;
            float a3 = fmaf(eav[u], Wev.w, xrv.w) + x23.y;
            a0 = fmaxf(a0, kSlope * a0); a1 = fmaxf(a1, kSlope * a1);
            a2 = fmaxf(a2, kSlope * a2); a3 = fmaxf(a3, kSlope * a3);
            float pp = red8(a0 * av.x + a1 * av.y + a2 * av.z + a3 * av.w);
            float eu = __builtin_amdgcn_exp2f(pp - kShift2);
            l += eu;
            o0 = fmaf(eu, x01.x, o0); o1 = fmaf(eu, x01.y, o1);
            o2 = fmaf(eu, x23.x, o2); o3 = fmaf(eu, x23.y, o3);
        }
    }
    for (; e < npair; ++e) {
        int2 pa = epack[base + 2 * e];
        int2 pb = epack[base + 2 * e + 1];
        int srow = slot0 ? pa.x : pb.x;
        float eav = __int_as_float(slot0 ? pa.y : pb.y);
        h4 xv = xl4[(long)srow * 32 + f];
        float2 x01 = __half22float2(xv.a), x23 = __half22float2(xv.b);
        float a0 = fmaf(eav, Wev.x, xrv.x) + x01.x;
        float a1 = fmaf(eav, Wev.y, xrv.y) + x01.y;
        float a2 = fmaf(eav, Wev.z, xrv.z) + x23.x;
        float a3 = fmaf(eav, Wev.w, xrv.w) + x23.y;
        a0 = fmaxf(a0, kSlope * a0); a1 = fmaxf(a1, kSlope * a1);
        a2 = fmaxf(a2, kSlope * a2); a3 = fmaxf(a3, kSlope * a3);
        float pp = red8(a0 * av.x + a1 * av.y + a2 * av.z + a3 * av.w);
        float eu = __builtin_amdgcn_exp2f(pp - kShift2);
        l += eu;
        o0 = fmaf(eu, x01.x, o0); o1 = fmaf(eu, x01.y, o1);
        o2 = fmaf(eu, x23.x, o2); o3 = fmaf(eu, x23.y, o3);
    }
    if (cnt & 1) {                        // odd tail edge on slot 0 only
        int2 ep = epack[base + cnt - 1];
        int srow = ep.x;
        float eav = __int_as_float(ep.y);
        h4 xv = xl4[(long)srow * 32 + f];
        float2 x01 = __half22float2(xv.a), x23 = __half22float2(xv.b);
        float a0 = fmaf(eav, Wev.x, xrv.x) + x01.x;
        float a1 = fmaf(eav, Wev.y, xrv.y) + x01.y;
        float a2 = fmaf(eav, Wev.z, xrv.z) + x23.x;
        float a3 = fmaf(eav, Wev.w, xrv.w) + x23.y;
        a0 = fmaxf(a0, kSlope * a0); a1 = fmaxf(a1, kSlope * a1);
        a2 = fmaxf(a2, kSlope * a2); a3 = fmaxf(a3, kSlope * a3);
        float pp = red8(a0 * av.x + a1 * av.y + a2 * av.z + a3 * av.w);
        float eu = __builtin_amdgcn_exp2f(pp - kShift2) * em0;
        l += eu;
        o0 = fmaf(eu, x01.x, o0); o1 = fmaf(eu, x01.y, o1);
        o2 = fmaf(eu, x23.x, o2); o3 = fmaf(eu, x23.y, o3);
    }
    // merge the two edge slots
    l  += __shfl_xor(l, 32);
    o0 += __shfl_xor(o0, 32); o1 += __shfl_xor(o1, 32);
    o2 += __shfl_xor(o2, 32); o3 += __shfl_xor(o3, 32);
    float rl = __builtin_amdgcn_rcpf(l);
    float v0 = o0 * rl, v1 = o1 * rl, v2 = o2 * rl, v3 = o3 * rl;
    if (slot0)
        ((float4*)xrg)[rowq + f] = make_float4(v0, v1, v2, v3);  // g overwrites xr
    float vb0 = v0 + gb.x, vb1 = v1 + gb.y, vb2 = v2 + gb.z, vb3 = v3 + gb.w;
    float s = vb0 + vb1 + vb2 + vb3;
    float q = vb0 * vb0 + vb1 * vb1 + vb2 * vb2 + vb3 * vb3;
    #pragma unroll
    for (int mm = 1; mm < 32; mm <<= 1) { s += __shfl_xor(s, mm); q += __shfl_xor(q, mm); }
    if (t == 0) { ps[d] = s; pq[d] = q; }
}

// ---- K4: reduce per-node partials -> stats[2].
__global__ void __launch_bounds__(1024) k_statsr(
    const float* __restrict__ ps, const float* __restrict__ pq, float* __restrict__ stats) {
    __shared__ float rs[1024], rq[1024];
    int t = threadIdx.x;
    float s = 0.f, q = 0.f;
    for (int i = t; i < kNodes; i += 1024) { s += ps[i]; q += pq[i]; }
    rs[t] = s; rq[t] = q;
    __syncthreads();
    for (int o = 512; o > 0; o >>= 1) {
        if (t < o) { rs[t] += rs[t + o]; rq[t] += rq[t + o]; }
        __syncthreads();
    }
    if (t == 0) { stats[0] = rs[0]; stats[1] = rq[0]; }
}

// ---- K5: h = relu(node_ln(relu(graph_ln(g+gat_b)) @ lin_w + lin_b)); jk_out = max(jk_in, h)
__global__ void __launch_bounds__(256) k_post(
    const float* __restrict__ g, const float* __restrict__ gat_b,
    const float* __restrict__ ln1w, const float* __restrict__ ln1b,
    const float* __restrict__ linw, const float* __restrict__ linb,
    const float* __restrict__ ln2w, const float* __restrict__ ln2b,
    const float* __restrict__ stats, const float* __restrict__ jk_in,
    float* __restrict__ h, float* __restrict__ jk_out) {
    __shared__ float s_lwT[kC * kLWP];    // 16.6 KB, lin_w transposed
    __shared__ float s_vb[8 * kHC];       // 4 KB
    int t = threadIdx.x;
    int n0 = blockIdx.x * 8;
    const float inv = 1.f / ((float)kNodes * kHC);
    float mean = stats[0] * inv;
    float var  = stats[1] * inv - mean * mean;
    float rstd = rsqrtf(var + kEps);
    for (int i = t; i < kHC * kC; i += 256) {
        int k = i >> 5, c = i & 31;
        s_lwT[c * kLWP + k] = linw[i];
    }
    for (int i = t; i < 8 * kHC; i += 256) {
        int node = n0 + (i >> 7), f = i & 127;
        float a = (g[(long)node * kHC + f] + gat_b[f] - mean) * rstd * ln1w[f] + ln1b[f];
        s_vb[i] = fmaxf(a, 0.f);
    }
    __syncthreads();
    int n = t >> 5, c = t & 31;
    int node = n0 + n;
    float acc = linb[c];
    const float* vb = s_vb + n * kHC;
    const float* wr = s_lwT + c * kLWP;
    #pragma unroll 8
    for (int k = 0; k < kHC; k += 4) {
        float4 v4 = *(const float4*)(vb + k);
        float2 w0 = *(const float2*)(wr + k);
        float2 w1 = *(const float2*)(wr + k + 2);
        acc += v4.x * w0.x + v4.y * w0.y + v4.z * w1.x + v4.w * w1.y;
    }
    float m = acc;
    #pragma unroll
    for (int mm = 1; mm < 32; mm <<= 1) m += __shfl_xor(m, mm);
    m *= (1.f / kC);
    float dd = acc - m;
    float q = dd * dd;
    #pragma unroll
    for (int mm = 1; mm < 32; mm <<= 1) q += __shfl_xor(q, mm);
    q *= (1.f / kC);
    float out = dd * rsqrtf(q + kEps) * ln2w[c] + ln2b[c];
    out = fmaxf(out, 0.f);
    h[node * kC + c] = out;
    jk_out[node * kC + c] = fmaxf(jk_in[node * kC + c], out);
}

extern "C" void kernel_launch(void* const* d_in, const int* in_sizes, int n_in,
                              void* d_out, int out_size, void* d_ws, size_t ws_size,
                              hipStream_t stream) {
    (void)in_sizes; (void)n_in; (void)out_size; (void)ws_size;
    const float* x     = (const float*)d_in[0];
    const int*   ei    = (const int*)d_in[1];
    const int*   src   = ei;
    const int*   dst   = ei + kNE;
    const float* ea    = (const float*)d_in[2];
    const float* W_emb = (const float*)d_in[3];
    const float* b_emb = (const float*)d_in[4];
    const float* ln0w  = (const float*)d_in[5];
    const float* ln0b  = (const float*)d_in[6];
    const float* Wl    = (const float*)d_in[7];
    const float* bl    = (const float*)d_in[8];
    const float* Wr    = (const float*)d_in[9];
    const float* br    = (const float*)d_in[10];
    const float* We    = (const float*)d_in[11];
    const float* att   = (const float*)d_in[12];
    const float* gat_b = (const float*)d_in[13];
    const float* ln1w  = (const float*)d_in[14];
    const float* ln1b  = (const float*)d_in[15];
    const float* linw  = (const float*)d_in[16];
    const float* linb  = (const float*)d_in[17];
    const float* ln2w  = (const float*)d_in[18];
    const float* ln2b  = (const float*)d_in[19];

    char* wsb = (char*)d_ws;
    float*  h      = (float*)(wsb);                 // 6.4e6 B
    float*  jk     = (float*)(wsb +  6400000);      // 6.4e6 B
    float*  xrg    = (float*)(wsb + 12800000);      // 25.6e6 B (xr, later g)
    __half* xl     = (__half*)(wsb + 38400000);     // 12.8e6 B
    int2*   epack  = (int2*)(wsb + 51200000);       // 6.4e6 B (packed src+ea per edge)
    int*    deg    = (int*)(wsb + 57600000);        // 0.2e6 B
    int*    rowptr = (int*)(wsb + 58000000);        // 0.2e6 B
    int*    bsum   = (int*)(wsb + 58200000);        // 1 KB
    float*  stats  = (float*)(wsb + 58201024);      // 8 B
    float*  ps     = (float*)(wsb + 58300000);      // 0.2e6 B
    float*  pq     = (float*)(wsb + 58500000);      // 0.2e6 B
    unsigned short* rank = (unsigned short*)(wsb + 58700000);  // 1.6e6 B

    const int scanBlocks = (kNodes + 255) / 256;         // 196
    const int edgeBlocks = kNodes / 4;                   // 12500 exact, 4 nodes/block
    const int postBlocks = kNodes / 8;                   // 6250 exact

    // zero deg, then fused hist ∥ embed (hist first: atomics start early)
    hipLaunchKernelGGL(k_fill0, dim3((kNodes + 255) / 256), dim3(256), 0, stream,
                       (unsigned*)deg, kNodes);
    hipLaunchKernelGGL(k_embed_hist, dim3(kHistGS + kEmbedBlocks), dim3(256), 0, stream,
                       x, W_emb, b_emb, ln0w, ln0b, h, jk, dst, deg, rank);
    hipLaunchKernelGGL(k_scan1, dim3(scanBlocks), dim3(256), 0, stream, deg, rowptr, bsum);
    hipLaunchKernelGGL(k_scan2, dim3(1), dim3(256), 0, stream, bsum, scanBlocks);
    hipLaunchKernelGGL(k_scan3, dim3(scanBlocks), dim3(256), 0, stream, rowptr, bsum);
    // fused reorder ∥ trans(layer 0) — reorder atomic-free, 4-deep grid-stride
    hipLaunchKernelGGL(k_trans_reorder, dim3(kReoGS + kTransBlocks), dim3(256), 0, stream,
                       h, Wl, bl, Wr, br, xl, xrg,
                       src, dst, ea, rowptr, rank, epack);
    for (int l = 0; l < 2; ++l) {
        if (l == 1) {
            hipLaunchKernelGGL(k_trans, dim3(kTransBlocks), dim3(256), 0, stream,
                               h, Wl + l * kC * kHC, bl + l * kHC,
                               Wr + l * kC * kHC, br + l * kHC, xl, xrg);
        }
        hipLaunchKernelGGL(k_edge, dim3(edgeBlocks), dim3(256), 0, stream,
                           rowptr, deg, epack, xl, xrg,
                           We + l * kHC, att + l * kH * kC, gat_b + l * kHC, ps, pq);
        hipLaunchKernelGGL(k_statsr, dim3(1), dim3(1024), 0, stream, ps, pq, stats);
        hipLaunchKernelGGL(k_post, dim3(postBlocks), dim3(256), 0, stream,
                           xrg, gat_b + l * kHC, ln1w + l * kHC, ln1b + l * kHC,
                           linw + l * kHC * kC, linb + l * kC,
                           ln2w + l * kC, ln2b + l * kC, stats, jk,
                           h, (l == 1) ? (float*)d_out : jk);
    }
}

// Round 10
// 418.887 us; speedup vs baseline: 1.3460x; 1.0009x over previous
//
#include <hip/hip_runtime.h>
#include <hip/hip_fp16.h>

constexpr int kNodes = 50000;
constexpr int kNE    = 800000;            // edges before self loops
constexpr int kFin   = 256;
constexpr int kC     = 32;
constexpr int kH     = 4;
constexpr int kHC    = 128;               // kH * kC
constexpr int kTN    = 16;                // nodes per k_embed block
constexpr int kLWP   = 130;               // padded s_lwT row in k_post (float2-aligned, 2-way alias)
constexpr int kEmbedBlocks = kNodes / kTN;        // 3125
constexpr int kTransBlocks = (kNodes + 31) / 32;  // 1563
constexpr int kHistGS = 256;              // grid-stride hist blocks (4-deep atomic MLP)
constexpr int kReoGS  = 256;              // grid-stride reorder blocks
constexpr int kDegBlocks = (kNodes + 255) / 256;  // 196 (k_prep deg-zero role)
constexpr float kEps   = 1e-5f;
constexpr float kSlope = 0.2f;
constexpr float kL2E   = 1.44269504f;     // log2(e): fold into att so exp is 1 instr
constexpr float kShift2 = 8.0f * 1.44269504f; // softmax-invariant shift (exp2 domain)

typedef _Float16 f16;
typedef _Float16 f16x2 __attribute__((ext_vector_type(2)));
struct alignas(16) h8 { f16x2 v[4]; };    // 8 halves = 16 B

__device__ __forceinline__ float fdot2_(f16x2 a, f16x2 b, float c) {
#if __has_builtin(__builtin_amdgcn_fdot2)
    return __builtin_amdgcn_fdot2(a, b, c, false);
#else
    return fmaf((float)a.x, (float)b.x, fmaf((float)a.y, (float)b.y, c));
#endif
}

// ---- DPP butterfly add: v += partner(v), pure VALU (no DS pipe).
template<int CTRL>
__device__ __forceinline__ float dpp_add(float v) {
    int x = __builtin_amdgcn_update_dpp(0, __float_as_int(v), CTRL, 0xF, 0xF, true);
    return v + __int_as_float(x);
}
// 8-lane sum (head = 8 lanes x 4 features): xor1, xor2, then row_half_mirror.
__device__ __forceinline__ float red8(float p) {
    p = dpp_add<0xB1>(p);
    p = dpp_add<0x4E>(p);
    p = dpp_add<0x141>(p);
    return p;
}

// ---- K0: prep — zero deg (196 blocks) + convert W to fp16 PRE-SWIZZLED
// [i8][c][8] (32 blocks), so embed staging is a straight 16B copy.
__global__ void __launch_bounds__(256) k_prep(
    unsigned* __restrict__ deg, const float* __restrict__ W, f16* __restrict__ Wh) {
    int t = threadIdx.x;
    if (blockIdx.x < kDegBlocks) {
        int i = blockIdx.x * 256 + t;
        if (i < kNodes) deg[i] = 0u;
        return;
    }
    int i = (blockIdx.x - kDegBlocks) * 256 + t;   // 32 blocks x 256 = 8192 = kFin*kC
    int k = i >> 5, c = i & 31;
    Wh[((k >> 3) * kC + c) * 8 + (k & 7)] = (f16)W[i];
}

// ---- K_A: role-split fused kernel, fp16 operands + v_dot2_f32_f16.
// blocks [0, kHistGS): grid-stride degree histogram, 4-deep batches; the
// atomicAdd RETURN VALUE is the edge's rank within its dst row -> rank[e].
// blocks [kHistGS, +kEmbedBlocks): h0 = relu(node_ln(x @ W_emb + b_emb)); jk = h0.
// W staged from pre-swizzled fp16 Wh: 4x16B loads + 4x ds_write_b128/thread.
__global__ void __launch_bounds__(256) k_embed_hist(
    const float* __restrict__ x, const f16* __restrict__ Wh, const float* __restrict__ b,
    const float* __restrict__ lnw, const float* __restrict__ lnb,
    float* __restrict__ h, float* __restrict__ jk,
    const int* __restrict__ dst, int* __restrict__ deg, unsigned short* __restrict__ rank) {
    __shared__ f16 sxh[kTN * kFin];       // 8 KB
    __shared__ f16 sWh[kFin / 8 * kC * 8];// 16 KB, [i8][c] blocks of 8 halves
    int t = threadIdx.x;
    if (blockIdx.x < kHistGS) {           // ---- hist role (grid-stride, 4-deep)
        const int stride = kHistGS * 256;
        int e = blockIdx.x * 256 + t;
        for (; e + 3 * stride < kNE; e += 4 * stride) {
            int d0 = dst[e], d1 = dst[e + stride], d2 = dst[e + 2 * stride], d3 = dst[e + 3 * stride];
            int r0 = atomicAdd(&deg[d0], 1);
            int r1 = atomicAdd(&deg[d1], 1);
            int r2 = atomicAdd(&deg[d2], 1);
            int r3 = atomicAdd(&deg[d3], 1);
            rank[e] = (unsigned short)r0;
            rank[e + stride] = (unsigned short)r1;
            rank[e + 2 * stride] = (unsigned short)r2;
            rank[e + 3 * stride] = (unsigned short)r3;
        }
        for (; e < kNE; e += stride) {
            int d = dst[e];
            rank[e] = (unsigned short)atomicAdd(&deg[d], 1);
        }
        return;
    }
    // ---- embed role
    int n0 = (blockIdx.x - kHistGS) * kTN;       // 50000 = 3125 * 16 exact
    {
        const h8* Wg = (const h8*)Wh;
        h8* sW8 = (h8*)sWh;
        for (int i = t; i < kFin * kC / 8; i += 256) sW8[i] = Wg[i];
    }
    const float2* xg2 = (const float2*)(x + (long)n0 * kFin);
    f16x2* sx2 = (f16x2*)sxh;
    for (int i = t; i < kTN * kFin / 2; i += 256) {
        float2 v = xg2[i];
        f16x2 hv; hv.x = (f16)v.x; hv.y = (f16)v.y;
        sx2[i] = hv;
    }
    __syncthreads();
    int c = t & 31, n2 = t >> 5;          // n2 = 0..7
    const h8* xa = (const h8*)(sxh + n2 * kFin);
    const h8* xb = (const h8*)(sxh + (n2 + 8) * kFin);
    const h8* wr = (const h8*)sWh;        // [i8*kC + c]
    float a0 = 0.f, a0b = 0.f, a1 = 0.f, a1b = 0.f;
    #pragma unroll 8
    for (int i8 = 0; i8 < kFin / 8; ++i8) {
        h8 xv0 = xa[i8];
        h8 xv1 = xb[i8];
        h8 wv  = wr[i8 * kC + c];
        a0  = fdot2_(xv0.v[0], wv.v[0], a0);
        a0b = fdot2_(xv0.v[1], wv.v[1], a0b);
        a0  = fdot2_(xv0.v[2], wv.v[2], a0);
        a0b = fdot2_(xv0.v[3], wv.v[3], a0b);
        a1  = fdot2_(xv1.v[0], wv.v[0], a1);
        a1b = fdot2_(xv1.v[1], wv.v[1], a1b);
        a1  = fdot2_(xv1.v[2], wv.v[2], a1);
        a1b = fdot2_(xv1.v[3], wv.v[3], a1b);
    }
    float acc0 = a0 + a0b, acc1 = a1 + a1b;
    float bc = b[c], lw = lnw[c], lb = lnb[c];
    {
        float y = acc0 + bc;
        float m = y;
        #pragma unroll
        for (int o = 1; o < 32; o <<= 1) m += __shfl_xor(m, o);
        m *= (1.f / kC);
        float xc = y - m, v = xc * xc;
        #pragma unroll
        for (int o = 1; o < 32; o <<= 1) v += __shfl_xor(v, o);
        v *= (1.f / kC);
        float out = fmaxf(xc * rsqrtf(v + kEps) * lw + lb, 0.f);
        int node = n0 + n2;
        h[node * kC + c] = out;
        jk[node * kC + c] = out;
    }
    {
        float y = acc1 + bc;
        float m = y;
        #pragma unroll
        for (int o = 1; o < 32; o <<= 1) m += __shfl_xor(m, o);
        m *= (1.f / kC);
        float xc = y - m, v = xc * xc;
        #pragma unroll
        for (int o = 1; o < 32; o <<= 1) v += __shfl_xor(v, o);
        v *= (1.f / kC);
        float out = fmaxf(xc * rsqrtf(v + kEps) * lw + lb, 0.f);
        int node = n0 + n2 + 8;
        h[node * kC + c] = out;
        jk[node * kC + c] = out;
    }
}

// ---- trans body: xl = h@Wl + bl (fp16) ; xr = h@Wr + br (fp32). bid = node-tile idx.
__device__ __forceinline__ void trans_body(
    int bid, float* s_h, const float* __restrict__ h,
    const float* __restrict__ Wl, const float* __restrict__ bl,
    const float* __restrict__ Wr, const float* __restrict__ br,
    __half* __restrict__ xl, float* __restrict__ xr) {
    int t = threadIdx.x;
    int j = t & 127, hf = t >> 7;
    float wl[kC], wr[kC];
    #pragma unroll
    for (int k = 0; k < kC; ++k) { wl[k] = Wl[k * kHC + j]; wr[k] = Wr[k * kHC + j]; }
    float blj = bl[j], brj = br[j];
    int n0 = bid * 32;
    int nn = min(32, kNodes - n0);
    for (int i = t; i < nn * kC; i += 256) s_h[i] = h[n0 * kC + i];
    __syncthreads();
    int nend = min(nn, hf * 16 + 16);
    for (int n = hf * 16; n < nend; ++n) {
        const float4* h4 = (const float4*)(s_h + n * kC);
        float al = blj, ar = brj;
        #pragma unroll
        for (int kq = 0; kq < 8; ++kq) {
            float4 hv = h4[kq];
            al += hv.x * wl[kq*4] + hv.y * wl[kq*4+1] + hv.z * wl[kq*4+2] + hv.w * wl[kq*4+3];
            ar += hv.x * wr[kq*4] + hv.y * wr[kq*4+1] + hv.z * wr[kq*4+2] + hv.w * wr[kq*4+3];
        }
        long g = (long)(n0 + n) * kHC + j;
        xl[g] = __float2half(al);
        xr[g] = ar;
    }
}

// ---- K2 (standalone, layer 1): k_trans (+ zeroes stats for this layer's statsr)
__global__ void __launch_bounds__(256) k_trans(
    const float* __restrict__ h,
    const float* __restrict__ Wl, const float* __restrict__ bl,
    const float* __restrict__ Wr, const float* __restrict__ br,
    __half* __restrict__ xl, float* __restrict__ xr, float* __restrict__ stats) {
    __shared__ float s_h[32 * kC];
    if (blockIdx.x == 0 && threadIdx.x == 0) { stats[0] = 0.f; stats[1] = 0.f; }
    trans_body(blockIdx.x, s_h, h, Wl, bl, Wr, br, xl, xr);
}

// ---- K_B: role-split fused kernel (layer 0 only).
// blocks [0, kReoGS): reorder, atomic-free, grid-stride 4-deep.
// blocks [kReoGS, +kTransBlocks): trans layer 0 (needs only h). First trans
// block also zeroes stats for layer 0's statsr.
__global__ void __launch_bounds__(256) k_trans_reorder(
    const float* __restrict__ h,
    const float* __restrict__ Wl, const float* __restrict__ bl,
    const float* __restrict__ Wr, const float* __restrict__ br,
    __half* __restrict__ xl, float* __restrict__ xr,
    const int* __restrict__ src, const int* __restrict__ dst, const float* __restrict__ ea,
    const int* __restrict__ rowptr, const unsigned short* __restrict__ rank,
    int2* __restrict__ epack, float* __restrict__ stats) {
    __shared__ float s_h[32 * kC];
    if (blockIdx.x < kReoGS) {            // ---- reorder role (starts first)
        const int stride = kReoGS * 256;
        int e = blockIdx.x * 256 + threadIdx.x;
        for (; e + 3 * stride < kNE; e += 4 * stride) {
            int e1 = e + stride, e2 = e + 2 * stride, e3 = e + 3 * stride;
            int d0 = dst[e], d1 = dst[e1], d2 = dst[e2], d3 = dst[e3];
            int r0 = rank[e], r1 = rank[e1], r2 = rank[e2], r3 = rank[e3];
            int p0 = rowptr[d0] + r0, p1 = rowptr[d1] + r1;
            int p2 = rowptr[d2] + r2, p3 = rowptr[d3] + r3;
            epack[p0] = make_int2(src[e],  __float_as_int(ea[e]));
            epack[p1] = make_int2(src[e1], __float_as_int(ea[e1]));
            epack[p2] = make_int2(src[e2], __float_as_int(ea[e2]));
            epack[p3] = make_int2(src[e3], __float_as_int(ea[e3]));
        }
        for (; e < kNE; e += stride) {
            int d = dst[e];
            int pos = rowptr[d] + (int)rank[e];
            epack[pos] = make_int2(src[e], __float_as_int(ea[e]));
        }
        return;
    }
    if (blockIdx.x == kReoGS && threadIdx.x == 0) { stats[0] = 0.f; stats[1] = 0.f; }
    trans_body(blockIdx.x - kReoGS, s_h, h, Wl, bl, Wr, br, xl, xr);
}

// ---- CSR scans (dst is layer-invariant: built ONCE)
__global__ void __launch_bounds__(256) k_scan1(const int* __restrict__ deg,
                                               int* __restrict__ excl, int* __restrict__ bsum) {
    __shared__ int s[256];
    int t = threadIdx.x;
    int i = blockIdx.x * 256 + t;
    int v = (i < kNodes) ? deg[i] : 0;
    s[t] = v;
    __syncthreads();
    for (int o = 1; o < 256; o <<= 1) {
        int tv = (t >= o) ? s[t - o] : 0;
        __syncthreads();
        s[t] += tv;
        __syncthreads();
    }
    if (i < kNodes) excl[i] = s[t] - v;
    if (t == 255) bsum[blockIdx.x] = s[255];
}

__global__ void __launch_bounds__(256) k_scan2(int* __restrict__ bsum, int nb) {
    __shared__ int s[256];
    int t = threadIdx.x;
    int v = (t < nb) ? bsum[t] : 0;
    s[t] = v;
    __syncthreads();
    for (int o = 1; o < 256; o <<= 1) {
        int tv = (t >= o) ? s[t - o] : 0;
        __syncthreads();
        s[t] += tv;
        __syncthreads();
    }
    if (t < nb) bsum[t] = s[t];
}

__global__ void __launch_bounds__(256) k_scan3(int* __restrict__ excl, const int* __restrict__ bsum) {
    int i = blockIdx.x * 256 + threadIdx.x;
    if (i >= kNodes) return;
    if (blockIdx.x > 0) excl[i] += bsum[blockIdx.x - 1];
}

// ---- batched edge processing: U pairs (2U edges), loads issued before use.
struct h4 { __half2 a, b; };              // 8 B = 4 halves
template<int U>
__device__ __forceinline__ void gat_batch(
    const int2* __restrict__ epack, int base2, bool slot0, int f,
    const h4* __restrict__ xl4, float4 Wev, float4 xrv, float4 av,
    float& l, float& o0, float& o1, float& o2, float& o3) {
    int2 pa[U], pb[U];
    #pragma unroll
    for (int u = 0; u < U; ++u) {
        pa[u] = epack[base2 + 2 * u];
        pb[u] = epack[base2 + 2 * u + 1];
    }
    h4 xv[U]; float eav[U];
    #pragma unroll
    for (int u = 0; u < U; ++u) {
        int srow = slot0 ? pa[u].x : pb[u].x;
        xv[u] = xl4[(long)srow * 32 + f];
        eav[u] = __int_as_float(slot0 ? pa[u].y : pb[u].y);
    }
    #pragma unroll
    for (int u = 0; u < U; ++u) {
        float2 x01 = __half22float2(xv[u].a), x23 = __half22float2(xv[u].b);
        float a0 = fmaf(eav[u], Wev.x, xrv.x) + x01.x;
        float a1 = fmaf(eav[u], Wev.y, xrv.y) + x01.y;
        float a2 = fmaf(eav[u], Wev.z, xrv.z) + x23.x;
        float a3 = fmaf(eav[u], Wev.w, xrv.w) + x23.y;
        a0 = fmaxf(a0, kSlope * a0); a1 = fmaxf(a1, kSlope * a1);
        a2 = fmaxf(a2, kSlope * a2); a3 = fmaxf(a3, kSlope * a3);
        float pp = red8(a0 * av.x + a1 * av.y + a2 * av.z + a3 * av.w);
        float eu = __builtin_amdgcn_exp2f(pp - kShift2);
        l += eu;
        o0 = fmaf(eu, x01.x, o0); o1 = fmaf(eu, x01.y, o1);
        o2 = fmaf(eu, x23.x, o2); o3 = fmaf(eu, x23.y, o3);
    }
}

// ---- K3: fused edge phase, 4 features/lane, 2 edges/wave, 1 wave/node.
// Deep pipeline: 8-pair (16-edge) batches -> 8 gathers in flight per slot.
__global__ void __launch_bounds__(256) k_edge(
    const int* __restrict__ rowptr, const int* __restrict__ deg,
    const int2* __restrict__ epack,
    const __half* __restrict__ xl, float* __restrict__ xrg,
    const float* __restrict__ We, const float* __restrict__ att,
    const float* __restrict__ gat_b, float* __restrict__ ps, float* __restrict__ pq) {
    int t = threadIdx.x & 63;
    int w = __builtin_amdgcn_readfirstlane(threadIdx.x >> 6);   // wave 0..3 (uniform)
    int d = blockIdx.x * 4 + w;           // node (50000 = 12500 * 4 exact)
    int f = t & 31;                       // feature quad
    bool slot0 = (t < 32);
    float em0 = slot0 ? 1.f : 0.f;

    const h4* xl4 = (const h4*)xl;        // row stride 32 h4
    long rowq = (long)d * 32;

    float4 xrv = ((const float4*)xrg)[rowq + f];
    float4 Wev = ((const float4*)We)[f];
    float4 av  = ((const float4*)att)[f];
    av.x *= kL2E; av.y *= kL2E; av.z *= kL2E; av.w *= kL2E;
    float4 gb  = ((const float4*)gat_b)[f];

    h4 xs = xl4[rowq + f];
    float2 xs01 = __half22float2(xs.a), xs23 = __half22float2(xs.b);

    // self loop (ea = 0), counted on slot 0 only
    float z0 = xs01.x + xrv.x, z1 = xs01.y + xrv.y;
    float z2 = xs23.x + xrv.z, z3 = xs23.y + xrv.w;
    z0 = fmaxf(z0, kSlope * z0); z1 = fmaxf(z1, kSlope * z1);
    z2 = fmaxf(z2, kSlope * z2); z3 = fmaxf(z3, kSlope * z3);
    float p = red8(z0 * av.x + z1 * av.y + z2 * av.z + z3 * av.w);
    float ee = __builtin_amdgcn_exp2f(p - kShift2) * em0;
    float l = ee;
    float o0 = ee * xs01.x, o1 = ee * xs01.y, o2 = ee * xs23.x, o3 = ee * xs23.y;

    int base = rowptr[d], cnt = deg[d];   // uniform -> SGPR
    int npair = cnt >> 1;
    int e = 0;
    for (; e + 8 <= npair; e += 8)
        gat_batch<8>(epack, base + 2 * e, slot0, f, xl4, Wev, xrv, av, l, o0, o1, o2, o3);
    if (e + 4 <= npair) {
        gat_batch<4>(epack, base + 2 * e, slot0, f, xl4, Wev, xrv, av, l, o0, o1, o2, o3);
        e += 4;
    }
    for (; e < npair; ++e)
        gat_batch<1>(epack, base + 2 * e, slot0, f, xl4, Wev, xrv, av, l, o0, o1, o2, o3);
    if (cnt & 1) {                        // odd tail edge on slot 0 only
        int2 ep = epack[base + cnt - 1];
        int srow = ep.x;
        float eav = __int_as_float(ep.y);
        h4 xv = xl4[(long)srow * 32 + f];
        float2 x01 = __half22float2(xv.a), x23 = __half22float2(xv.b);
        float a0 = fmaf(eav, Wev.x, xrv.x) + x01.x;
        float a1 = fmaf(eav, Wev.y, xrv.y) + x01.y;
        float a2 = fmaf(eav, Wev.z, xrv.z) + x23.x;
        float a3 = fmaf(eav, Wev.w, xrv.w) + x23.y;
        a0 = fmaxf(a0, kSlope * a0); a1 = fmaxf(a1, kSlope * a1);
        a2 = fmaxf(a2, kSlope * a2); a3 = fmaxf(a3, kSlope * a3);
        float pp = red8(a0 * av.x + a1 * av.y + a2 * av.z + a3 * av.w);
        float eu = __builtin_amdgcn_exp2f(pp - kShift2) * em0;
        l += eu;
        o0 = fmaf(eu, x01.x, o0); o1 = fmaf(eu, x01.y, o1);
        o2 = fmaf(eu, x23.x, o2); o3 = fmaf(eu, x23.y, o3);
    }
    // merge the two edge slots
    l  += __shfl_xor(l, 32);
    o0 += __shfl_xor(o0, 32); o1 += __shfl_xor(o1, 32);
    o2 += __shfl_xor(o2, 32); o3 += __shfl_xor(o3, 32);
    float rl = __builtin_amdgcn_rcpf(l);
    float v0 = o0 * rl, v1 = o1 * rl, v2 = o2 * rl, v3 = o3 * rl;
    if (slot0)
        ((float4*)xrg)[rowq + f] = make_float4(v0, v1, v2, v3);  // g overwrites xr
    float vb0 = v0 + gb.x, vb1 = v1 + gb.y, vb2 = v2 + gb.z, vb3 = v3 + gb.w;
    float s = vb0 + vb1 + vb2 + vb3;
    float q = vb0 * vb0 + vb1 * vb1 + vb2 * vb2 + vb3 * vb3;
    #pragma unroll
    for (int mm = 1; mm < 32; mm <<= 1) { s += __shfl_xor(s, mm); q += __shfl_xor(q, mm); }
    if (t == 0) { ps[d] = s; pq[d] = q; }
}

// ---- K4: reduce per-node partials -> stats[2]. 8 blocks + atomic finish
// (stats zeroed by the preceding trans kernel).
__global__ void __launch_bounds__(1024) k_statsr(
    const float* __restrict__ ps, const float* __restrict__ pq, float* __restrict__ stats) {
    __shared__ float rs[1024], rq[1024];
    int t = threadIdx.x;
    float s = 0.f, q = 0.f;
    for (int i = blockIdx.x * 1024 + t; i < kNodes; i += 8 * 1024) { s += ps[i]; q += pq[i]; }
    rs[t] = s; rq[t] = q;
    __syncthreads();
    for (int o = 512; o > 0; o >>= 1) {
        if (t < o) { rs[t] += rs[t + o]; rq[t] += rq[t + o]; }
        __syncthreads();
    }
    if (t == 0) { atomicAdd(&stats[0], rs[0]); atomicAdd(&stats[1], rq[0]); }
}

// ---- K5: h = relu(node_ln(relu(graph_ln(g+gat_b)) @ lin_w + lin_b)); jk_out = max(jk_in, h)
__global__ void __launch_bounds__(256) k_post(
    const float* __restrict__ g, const float* __restrict__ gat_b,
    const float* __restrict__ ln1w, const float* __restrict__ ln1b,
    const float* __restrict__ linw, const float* __restrict__ linb,
    const float* __restrict__ ln2w, const float* __restrict__ ln2b,
    const float* __restrict__ stats, const float* __restrict__ jk_in,
    float* __restrict__ h, float* __restrict__ jk_out) {
    __shared__ float s_lwT[kC * kLWP];    // 16.6 KB, lin_w transposed
    __shared__ float s_vb[8 * kHC];       // 4 KB
    int t = threadIdx.x;
    int n0 = blockIdx.x * 8;
    const float inv = 1.f / ((float)kNodes * kHC);
    float mean = stats[0] * inv;
    float var  = stats[1] * inv - mean * mean;
    float rstd = rsqrtf(var + kEps);
    for (int i = t; i < kHC * kC; i += 256) {
        int k = i >> 5, c = i & 31;
        s_lwT[c * kLWP + k] = linw[i];
    }
    for (int i = t; i < 8 * kHC; i += 256) {
        int node = n0 + (i >> 7), f = i & 127;
        float a = (g[(long)node * kHC + f] + gat_b[f] - mean) * rstd * ln1w[f] + ln1b[f];
        s_vb[i] = fmaxf(a, 0.f);
    }
    __syncthreads();
    int n = t >> 5, c = t & 31;
    int node = n0 + n;
    float acc = linb[c];
    const float* vb = s_vb + n * kHC;
    const float* wr = s_lwT + c * kLWP;
    #pragma unroll 8
    for (int k = 0; k < kHC; k += 4) {
        float4 v4 = *(const float4*)(vb + k);
        float2 w0 = *(const float2*)(wr + k);
        float2 w1 = *(const float2*)(wr + k + 2);
        acc += v4.x * w0.x + v4.y * w0.y + v4.z * w1.x + v4.w * w1.y;
    }
    float m = acc;
    #pragma unroll
    for (int mm = 1; mm < 32; mm <<= 1) m += __shfl_xor(m, mm);
    m *= (1.f / kC);
    float dd = acc - m;
    float q = dd * dd;
    #pragma unroll
    for (int mm = 1; mm < 32; mm <<= 1) q += __shfl_xor(q, mm);
    q *= (1.f / kC);
    float out = dd * rsqrtf(q + kEps) * ln2w[c] + ln2b[c];
    out = fmaxf(out, 0.f);
    h[node * kC + c] = out;
    jk_out[node * kC + c] = fmaxf(jk_in[node * kC + c], out);
}

extern "C" void kernel_launch(void* const* d_in, const int* in_sizes, int n_in,
                              void* d_out, int out_size, void* d_ws, size_t ws_size,
                              hipStream_t stream) {
    (void)in_sizes; (void)n_in; (void)out_size; (void)ws_size;
    const float* x     = (const float*)d_in[0];
    const int*   ei    = (const int*)d_in[1];
    const int*   src   = ei;
    const int*   dst   = ei + kNE;
    const float* ea    = (const float*)d_in[2];
    const float* W_emb = (const float*)d_in[3];
    const float* b_emb = (const float*)d_in[4];
    const float* ln0w  = (const float*)d_in[5];
    const float* ln0b  = (const float*)d_in[6];
    const float* Wl    = (const float*)d_in[7];
    const float* bl    = (const float*)d_in[8];
    const float* Wr    = (const float*)d_in[9];
    const float* br    = (const float*)d_in[10];
    const float* We    = (const float*)d_in[11];
    const float* att   = (const float*)d_in[12];
    const float* gat_b = (const float*)d_in[13];
    const float* ln1w  = (const float*)d_in[14];
    const float* ln1b  = (const float*)d_in[15];
    const float* linw  = (const float*)d_in[16];
    const float* linb  = (const float*)d_in[17];
    const float* ln2w  = (const float*)d_in[18];
    const float* ln2b  = (const float*)d_in[19];

    char* wsb = (char*)d_ws;
    float*  h      = (float*)(wsb);                 // 6.4e6 B
    float*  jk     = (float*)(wsb +  6400000);      // 6.4e6 B
    float*  xrg    = (float*)(wsb + 12800000);      // 25.6e6 B (xr, later g)
    __half* xl     = (__half*)(wsb + 38400000);     // 12.8e6 B
    int2*   epack  = (int2*)(wsb + 51200000);       // 6.4e6 B (packed src+ea per edge)
    int*    deg    = (int*)(wsb + 57600000);        // 0.2e6 B
    int*    rowptr = (int*)(wsb + 58000000);        // 0.2e6 B
    int*    bsum   = (int*)(wsb + 58200000);        // 1 KB
    float*  stats  = (float*)(wsb + 58201024);      // 8 B
    float*  ps     = (float*)(wsb + 58300000);      // 0.2e6 B
    float*  pq     = (float*)(wsb + 58500000);      // 0.2e6 B
    unsigned short* rank = (unsigned short*)(wsb + 58700000);  // 1.6e6 B
    f16*    Wh     = (f16*)(wsb + 60400000);        // 16 KB (pre-swizzled fp16 W_emb)

    const int scanBlocks = (kNodes + 255) / 256;         // 196
    const int edgeBlocks = kNodes / 4;                   // 12500 exact, 4 nodes/block
    const int postBlocks = kNodes / 8;                   // 6250 exact

    // prep: zero deg + convert/swizzle W_emb -> fp16
    hipLaunchKernelGGL(k_prep, dim3(kDegBlocks + 32), dim3(256), 0, stream,
                       (unsigned*)deg, W_emb, Wh);
    hipLaunchKernelGGL(k_embed_hist, dim3(kHistGS + kEmbedBlocks), dim3(256), 0, stream,
                       x, Wh, b_emb, ln0w, ln0b, h, jk, dst, deg, rank);
    hipLaunchKernelGGL(k_scan1, dim3(scanBlocks), dim3(256), 0, stream, deg, rowptr, bsum);
    hipLaunchKernelGGL(k_scan2, dim3(1), dim3(256), 0, stream, bsum, scanBlocks);
    hipLaunchKernelGGL(k_scan3, dim3(scanBlocks), dim3(256), 0, stream, rowptr, bsum);
    // fused reorder ∥ trans(layer 0) — reorder atomic-free, 4-deep grid-stride
    hipLaunchKernelGGL(k_trans_reorder, dim3(kReoGS + kTransBlocks), dim3(256), 0, stream,
                       h, Wl, bl, Wr, br, xl, xrg,
                       src, dst, ea, rowptr, rank, epack, stats);
    for (int l = 0; l < 2; ++l) {
        if (l == 1) {
            hipLaunchKernelGGL(k_trans, dim3(kTransBlocks), dim3(256), 0, stream,
                               h, Wl + l * kC * kHC, bl + l * kHC,
                               Wr + l * kC * kHC, br + l * kHC, xl, xrg, stats);
        }
        hipLaunchKernelGGL(k_edge, dim3(edgeBlocks), dim3(256), 0, stream,
                           rowptr, deg, epack, xl, xrg,
                           We + l * kHC, att + l * kH * kC, gat_b + l * kHC, ps, pq);
        hipLaunchKernelGGL(k_statsr, dim3(8), dim3(1024), 0, stream, ps, pq, stats);
        hipLaunchKernelGGL(k_post, dim3(postBlocks), dim3(256), 0, stream,
                           xrg, gat_b + l * kHC, ln1w + l * kHC, ln1b + l * kHC,
                           linw + l * kHC * kC, linb + l * kC,
                           ln2w + l * kC, ln2b + l * kC, stats, jk,
                           h, (l == 1) ? (float*)d_out : jk);
    }
}